// Round 10
// baseline (2844.088 us; speedup 1.0000x reference)
//
#include <hip/hip_runtime.h>
#include <math.h>

#define NN 1024           // N (logical)
#define LD 1040           // padded leading dimension
#define NB 64             // panel width
#define TB 128            // tail handled by tailsyrk+finish
#define CROSS (NN - TB)   // 896: panel loop covers p < CROSS
#define NSAMP 64          // n_mc

#define CCONST  (-0.91893853320467274f)   // -0.5*log(2*pi)
#define LOG2PI  (1.8378770664093453f)

__device__ __forceinline__ float bcastf(float v, int lane) {
    return __int_as_float(__builtin_amdgcn_readlane(__float_as_int(v), lane));
}
__device__ __forceinline__ float softplus_d(float v) {
    return (v > 20.f ? v : log1pf(expf(v))) + 1e-7f;
}
__device__ __forceinline__ float log_normal_f(float v, float mean, float s, float eps) {
    float d = v - mean;
    return -d * d / (2.f * s * s + eps) - logf(s) + CCONST;
}
__device__ __forceinline__ float log_lognormal_f(float v, float mean, float s) {
    float lv = logf(v);
    float d = lv - mean;
    return -d * d / (2.f * s * s + 1e-6f) - lv - logf(s) + CCONST;
}
__device__ __forceinline__ void fma4(float4& c, float a, const float4& b) {
    c.x = fmaf(a, b.x, c.x); c.y = fmaf(a, b.y, c.y);
    c.z = fmaf(a, b.z, c.z); c.w = fmaf(a, b.w, c.w);
}

// ---------------- per-sample scalars ----------------
__global__ void scal_kernel(const float* __restrict__ z,
    const float* qbm, const float* qbs, const float* qsm, const float* qss,
    const float* qem, const float* qes, const float* qzm, const float* qzs,
    const float* qnm, const float* qns, float* __restrict__ scal)
{
    int m = threadIdx.x;
    if (m >= NSAMP) return;
    float z0 = z[m*5+0], z1 = z[m*5+1], z2 = z[m*5+2], z3 = z[m*5+3], z4 = z[m*5+4];
    float spb = softplus_d(qbs[0]);
    float sps = softplus_d(qss[0]);
    float spe = softplus_d(qes[0]);
    float spz = softplus_d(qzs[0]);
    float spn = softplus_d(qns[0]);
    float sigma2 = expf(z0 * sps + qsm[0]);
    float beta   = z1 * spb + qbm[0];
    float eta    = expf(z2 * spe + qem[0]);
    float lsZ    = expf(z3 * spz + qzm[0]);
    float lsN    = expf(z4 * spn + qnm[0]);
    float s0 = softplus_d(sqrtf(logf(2.f)));
    float lp = log_normal_f(beta, 0.f, 1.f, 1e-5f)
             + log_lognormal_f(sigma2, 1.f, s0)
             + log_lognormal_f(eta,    1.f, s0)
             + log_lognormal_f(lsZ,    1.f, s0)
             + log_lognormal_f(lsN,    1.f, s0);
    float lq = log_normal_f(beta, qbm[0], spb, 1e-5f)
             + log_lognormal_f(sigma2, qsm[0], sps)
             + log_lognormal_f(eta,    qem[0], spe)
             + log_lognormal_f(lsZ,    qzm[0], spz)
             + log_lognormal_f(lsN,    qnm[0], spn);
    scal[m]           = sigma2;
    scal[NSAMP + m]   = eta;
    scal[2*NSAMP + m] = 1.f / lsZ;
    scal[3*NSAMP + m] = 1.f / lsN;
    scal[4*NSAMP + m] = beta;
    scal[5*NSAMP + m] = lp - lq;
}

// ---------------- tail-square covariance + bvec/stats init ----------------
// r21: the cols 0..63 stripe is gone — panel q=0 computes it via the fused
// epilogue (acc=0). Only the 128x128 tail square (read by finish), bvec and
// stats init remain. Expressions identical to before.
__global__ __launch_bounds__(256)
void covslim_kernel(float* __restrict__ cov, const float* __restrict__ scal,
                    const float* __restrict__ x, const float* __restrict__ y,
                    float* __restrict__ bvec, float* __restrict__ stats, int mbase)
{
    int ml = blockIdx.y;
    int m  = mbase + ml;
    float sigma2 = scal[m];
    float eta    = scal[NSAMP + m];
    float ilZ    = scal[2*NSAMP + m];
    float ilN    = scal[3*NSAMP + m];
    float* C = cov + (size_t)ml * NN * LD;
    int tid = threadIdx.x;
    int bx  = blockIdx.x;                      // 0..15

    if (bx == 0 && tid == 0) { stats[2*m] = 0.f; stats[2*m+1] = 0.f; }
    if (tid < 64) {
        int i = bx * 64 + tid;                 // 16*64 = 1024 rows
        bvec[(size_t)m * NN + i] = y[i] - scal[4*NSAMP + m];
    }

    // tail: 8 rows x 128 cols per block, full square (upper is harmless)
    int i   = CROSS + bx * 8 + (tid >> 5);     // 896..1023
    int j0  = CROSS + (tid & 31) * 4;          // 896..1020
    float xi0 = x[2*i]   * ilZ;
    float xi1 = x[2*i+1] * ilN;
    float4 xa = *(const float4*)(x + 2*j0);
    float4 xb = *(const float4*)(x + 2*j0 + 4);
    float v[4]; float d0, d1;
    d0 = xa.x*ilZ - xi0; d1 = xa.y*ilN - xi1; v[0] = eta*__expf(-0.5f*(d0*d0+d1*d1));
    d0 = xa.z*ilZ - xi0; d1 = xa.w*ilN - xi1; v[1] = eta*__expf(-0.5f*(d0*d0+d1*d1));
    d0 = xb.x*ilZ - xi0; d1 = xb.y*ilN - xi1; v[2] = eta*__expf(-0.5f*(d0*d0+d1*d1));
    d0 = xb.z*ilZ - xi0; d1 = xb.w*ilN - xi1; v[3] = eta*__expf(-0.5f*(d0*d0+d1*d1));
    #pragma unroll
    for (int q = 0; q < 4; ++q) if (j0 + q == i) v[q] += sigma2;
    float4 o; o.x = v[0]; o.y = v[1]; o.z = v[2]; o.w = v[3];
    *(float4*)(C + (size_t)i * LD + j0) = o;
}

// ---------------- fused panel: GEMM update + diag factor + TRSM ----------------
// r21: one kernel per panel (was update + trsm). Each block:
//  1. GEMM-updates its 128x64 tile AND the 64x64 diag tile (redundant per
//     block, zero extra loads: diag rows ARE the staged Bs rows; same
//     k-ascending fmaf chains as the old update -> identical values).
//  2. RBF epilogue in-register; updated values go to LDS, never to HBM.
//  3. Wave 0 factors the diag (old diag_kernel arithmetic; block 0 -> stats).
//  4. Threads 0..127 solve their rows from LDS; only SOLVED rows hit C.
// Deletes 14 trsm dispatches + the write-then-reread of every panel.
__global__ __launch_bounds__(256)
void panel_kernel(float* __restrict__ covb, const float* __restrict__ scal,
                  const float* __restrict__ x, float* __restrict__ bvec,
                  float* __restrict__ stats, int mbase, int p)
{
    int ml = blockIdx.y;
    int m  = mbase + ml;
    float* C = covb + (size_t)ml * NN * LD;
    int rowbase = p + blockIdx.x * 128;

    // LDS arena: loop phase As[32][132]+Bs[32][68]; post phase Dl[64][68]+Rw[128][68]
    __shared__ __align__(16) float smem[13184];
    float* As = smem;            // 4224
    float* Bs = smem + 4224;     // 2176
    float* Dl = smem;            // 4352 (aliases As — used after final sync)
    float* Rw = smem + 4352;     // 8704
    float* rs_s  = smem + 13056; // 64
    float* sol_s = smem + 13120; // 64

    int tid = threadIdx.x;
    int tx = tid & 7,  ty = tid >> 3;
    int c0 = tx * 8,   r0 = ty * 4;
    int dr0 = ty * 2;                 // this thread's 2 diag rows

    float4 acc[4][2], dacc[2][2];
    #pragma unroll
    for (int r = 0; r < 4; ++r) { acc[r][0] = make_float4(0,0,0,0); acc[r][1] = make_float4(0,0,0,0); }
    #pragma unroll
    for (int r = 0; r < 2; ++r) { dacc[r][0] = make_float4(0,0,0,0); dacc[r][1] = make_float4(0,0,0,0); }

    for (int ks = 0; ks < p; ks += 32) {
        for (int idx = tid; idx < 128 * 8; idx += 256) {
            int ii = idx >> 3;
            int c4 = (idx & 7) << 2;
            int gr = rowbase + ii;
            float4 v = make_float4(0,0,0,0);
            if (gr < NN) v = *(const float4*)(C + (size_t)gr * LD + ks + c4);
            As[(c4+0)*132+ii] = v.x; As[(c4+1)*132+ii] = v.y;
            As[(c4+2)*132+ii] = v.z; As[(c4+3)*132+ii] = v.w;
        }
        for (int idx = tid; idx < 64 * 8; idx += 256) {
            int ii = idx >> 3;
            int c4 = (idx & 7) << 2;
            float4 v = *(const float4*)(C + (size_t)(p + ii) * LD + ks + c4);
            Bs[(c4+0)*68+ii] = v.x; Bs[(c4+1)*68+ii] = v.y;
            Bs[(c4+2)*68+ii] = v.z; Bs[(c4+3)*68+ii] = v.w;
        }
        __syncthreads();
        #pragma unroll
        for (int k = 0; k < 32; ++k) {
            float4 b0 = *(const float4*)&Bs[k*68 + c0];
            float4 b1 = *(const float4*)&Bs[k*68 + c0 + 4];
            float4 a0 = *(const float4*)&As[k*132 + r0];
            float ar[4] = {a0.x, a0.y, a0.z, a0.w};
            #pragma unroll
            for (int r = 0; r < 4; ++r) {
                fma4(acc[r][0], ar[r], b0);
                fma4(acc[r][1], ar[r], b1);
            }
            float dv0 = Bs[k*68 + dr0];
            float dv1 = Bs[k*68 + dr0 + 1];
            fma4(dacc[0][0], dv0, b0); fma4(dacc[0][1], dv0, b1);
            fma4(dacc[1][0], dv1, b0); fma4(dacc[1][1], dv1, b1);
        }
        __syncthreads();
    }

    int jcol = p + c0;
    float sigma2 = scal[m];
    float eta    = scal[NSAMP + m];
    float ilZ    = scal[2*NSAMP + m];
    float ilN    = scal[3*NSAMP + m];
    float4 xa0 = *(const float4*)(x + 2*jcol);
    float4 xb0 = *(const float4*)(x + 2*jcol + 4);
    float4 xa1 = *(const float4*)(x + 2*jcol + 8);
    float4 xb1 = *(const float4*)(x + 2*jcol + 12);

    // main tile: u = RBF - acc -> Rw (LDS)
    #pragma unroll
    for (int r = 0; r < 4; ++r) {
        int g = rowbase + r0 + r;
        if (g < NN) {
            float xi0 = x[2*g]   * ilZ;
            float xi1 = x[2*g+1] * ilN;
            float v[8]; float d0, d1;
            d0 = xa0.x*ilZ - xi0; d1 = xa0.y*ilN - xi1; v[0] = eta*__expf(-0.5f*(d0*d0+d1*d1));
            d0 = xa0.z*ilZ - xi0; d1 = xa0.w*ilN - xi1; v[1] = eta*__expf(-0.5f*(d0*d0+d1*d1));
            d0 = xb0.x*ilZ - xi0; d1 = xb0.y*ilN - xi1; v[2] = eta*__expf(-0.5f*(d0*d0+d1*d1));
            d0 = xb0.z*ilZ - xi0; d1 = xb0.w*ilN - xi1; v[3] = eta*__expf(-0.5f*(d0*d0+d1*d1));
            d0 = xa1.x*ilZ - xi0; d1 = xa1.y*ilN - xi1; v[4] = eta*__expf(-0.5f*(d0*d0+d1*d1));
            d0 = xa1.z*ilZ - xi0; d1 = xa1.w*ilN - xi1; v[5] = eta*__expf(-0.5f*(d0*d0+d1*d1));
            d0 = xb1.x*ilZ - xi0; d1 = xb1.y*ilN - xi1; v[6] = eta*__expf(-0.5f*(d0*d0+d1*d1));
            d0 = xb1.z*ilZ - xi0; d1 = xb1.w*ilN - xi1; v[7] = eta*__expf(-0.5f*(d0*d0+d1*d1));
            #pragma unroll
            for (int qq = 0; qq < 8; ++qq) if (jcol + qq == g) v[qq] += sigma2;
            float4 u0, u1;
            u0.x = v[0] - acc[r][0].x; u0.y = v[1] - acc[r][0].y;
            u0.z = v[2] - acc[r][0].z; u0.w = v[3] - acc[r][0].w;
            u1.x = v[4] - acc[r][1].x; u1.y = v[5] - acc[r][1].y;
            u1.z = v[6] - acc[r][1].z; u1.w = v[7] - acc[r][1].w;
            *(float4*)&Rw[(r0+r)*68 + c0]     = u0;
            *(float4*)&Rw[(r0+r)*68 + c0 + 4] = u1;
        }
    }
    // diag tile: du = RBF - dacc -> Dl (LDS)
    #pragma unroll
    for (int r = 0; r < 2; ++r) {
        int g = p + dr0 + r;
        float xi0 = x[2*g]   * ilZ;
        float xi1 = x[2*g+1] * ilN;
        float v[8]; float d0, d1;
        d0 = xa0.x*ilZ - xi0; d1 = xa0.y*ilN - xi1; v[0] = eta*__expf(-0.5f*(d0*d0+d1*d1));
        d0 = xa0.z*ilZ - xi0; d1 = xa0.w*ilN - xi1; v[1] = eta*__expf(-0.5f*(d0*d0+d1*d1));
        d0 = xb0.x*ilZ - xi0; d1 = xb0.y*ilN - xi1; v[2] = eta*__expf(-0.5f*(d0*d0+d1*d1));
        d0 = xb0.z*ilZ - xi0; d1 = xb0.w*ilN - xi1; v[3] = eta*__expf(-0.5f*(d0*d0+d1*d1));
        d0 = xa1.x*ilZ - xi0; d1 = xa1.y*ilN - xi1; v[4] = eta*__expf(-0.5f*(d0*d0+d1*d1));
        d0 = xa1.z*ilZ - xi0; d1 = xa1.w*ilN - xi1; v[5] = eta*__expf(-0.5f*(d0*d0+d1*d1));
        d0 = xb1.x*ilZ - xi0; d1 = xb1.y*ilN - xi1; v[6] = eta*__expf(-0.5f*(d0*d0+d1*d1));
        d0 = xb1.z*ilZ - xi0; d1 = xb1.w*ilN - xi1; v[7] = eta*__expf(-0.5f*(d0*d0+d1*d1));
        #pragma unroll
        for (int qq = 0; qq < 8; ++qq) if (jcol + qq == g) v[qq] += sigma2;
        float4 u0, u1;
        u0.x = v[0] - dacc[r][0].x; u0.y = v[1] - dacc[r][0].y;
        u0.z = v[2] - dacc[r][0].z; u0.w = v[3] - dacc[r][0].w;
        u1.x = v[4] - dacc[r][1].x; u1.y = v[5] - dacc[r][1].y;
        u1.z = v[6] - dacc[r][1].z; u1.w = v[7] - dacc[r][1].w;
        *(float4*)&Dl[(dr0+r)*68 + c0]     = u0;
        *(float4*)&Dl[(dr0+r)*68 + c0 + 4] = u1;
    }
    __syncthreads();

    // ---- diag factor (wave 0) from Dl; old diag_kernel arithmetic ----
    if (tid < 64) {
        int r = tid;
        float row[NB];
        #pragma unroll
        for (int q = 0; q < NB/4; ++q) {
            float4 v = *(const float4*)&Dl[r*68 + 4*q];
            row[4*q+0] = v.x; row[4*q+1] = v.y; row[4*q+2] = v.z; row[4*q+3] = v.w;
        }
        float b = bvec[(size_t)m * NN + p + r];
        float quad_add = 0.f, my_d = 1.f, my_rs = 0.f, my_sol = 0.f;
        #pragma unroll
        for (int j = 0; j < NB; ++j) {
            float dj = fmaxf(bcastf(row[j], j), 1e-30f);
            float rs = rsqrtf(dj);
            if (r == j) my_d = dj;
            row[j] *= rs;                       // row[j] = L[r][j] for r>=j
            float sj = bcastf(b, j) * rs;
            quad_add = fmaf(sj, sj, quad_add);
            b = fmaf(-row[j], sj, b);
            if (r == j) { my_rs = rs; my_sol = sj; }
            #pragma unroll
            for (int c = j + 1; c < NB; ++c) {
                float s = bcastf(row[j], c);    // = L[c][j]
                row[c] = fmaf(-row[j], s, row[c]);
            }
        }
        #pragma unroll
        for (int q = 0; q < NB/4; ++q) {
            float4 v; v.x = row[4*q]; v.y = row[4*q+1]; v.z = row[4*q+2]; v.w = row[4*q+3];
            *(float4*)&Dl[r*68 + 4*q] = v;      // Tl scaled rows
        }
        rs_s[r]  = my_rs;
        sol_s[r] = my_sol;
        if (blockIdx.x == 0) {
            float ldv = logf(my_d);
            #pragma unroll
            for (int off = 32; off > 0; off >>= 1) ldv += __shfl_down(ldv, off);
            if (r == 0) {
                stats[2*m]   += quad_add;
                stats[2*m+1] += ldv;
            }
        }
    }
    __syncthreads();

    // ---- solve: thread tid<128 owns tile row tid; only rows >= p+64 ----
    if (tid >= 128) return;
    int g = rowbase + tid;
    if (g >= NN || g < p + NB) return;
    float l[NB];
    #pragma unroll
    for (int q = 0; q < NB/4; ++q) {
        float4 v = *(const float4*)&Rw[tid*68 + 4*q];
        l[4*q] = v.x; l[4*q+1] = v.y; l[4*q+2] = v.z; l[4*q+3] = v.w;
    }
    #pragma unroll
    for (int j = 0; j < NB; ++j) {
        float s0 = l[j], s1 = 0.f, s2 = 0.f, s3 = 0.f;
        int c = 0;
        #pragma unroll
        for (; c + 4 <= j; c += 4) {
            float4 t = *(const float4*)&Dl[j*68 + c];
            s0 = fmaf(-l[c],   t.x, s0);
            s1 = fmaf(-l[c+1], t.y, s1);
            s2 = fmaf(-l[c+2], t.z, s2);
            s3 = fmaf(-l[c+3], t.w, s3);
        }
        #pragma unroll
        for (; c < j; ++c) s0 = fmaf(-l[c], Dl[j*68 + c], s0);
        l[j] = ((s0 + s1) + (s2 + s3)) * rs_s[j];
    }
    float* rowp = C + (size_t)g * LD + p;
    #pragma unroll
    for (int q = 0; q < NB/4; ++q) {
        float4 v; v.x = l[4*q]; v.y = l[4*q+1]; v.z = l[4*q+2]; v.w = l[4*q+3];
        *(float4*)(rowp + 4*q) = v;
    }
    float b0 = 0.f, b1 = 0.f, b2 = 0.f, b3 = 0.f;
    #pragma unroll
    for (int j = 0; j < NB; j += 4) {
        b0 = fmaf(l[j],   sol_s[j],   b0);
        b1 = fmaf(l[j+1], sol_s[j+1], b1);
        b2 = fmaf(l[j+2], sol_s[j+2], b2);
        b3 = fmaf(l[j+3], sol_s[j+3], b3);
    }
    bvec[(size_t)m * NN + g] -= ((b0 + b1) + (b2 + b3));
}

// ---------------- tail SYRK, split-K partials ----------------
__global__ __launch_bounds__(256)
void tailsyrk_kernel(float* __restrict__ covb)
{
    int ml = blockIdx.y;
    float* C = covb + (size_t)ml * NN * LD;
    int z  = blockIdx.x;
    int k0 = z * (CROSS / 4);            // 224 per segment

    __shared__ __align__(16) float As[32][132];
    int tid = threadIdx.x;
    int tx = tid & 15, ty = tid >> 4;
    int c0 = tx * 8, r0 = ty * 8;

    float4 acc[8][2];
    #pragma unroll
    for (int r = 0; r < 8; ++r) { acc[r][0] = make_float4(0,0,0,0); acc[r][1] = make_float4(0,0,0,0); }

    for (int ks = k0; ks < k0 + CROSS/4; ks += 32) {
        for (int idx = tid; idx < 128 * 8; idx += 256) {
            int ii = idx >> 3;
            int c4 = (idx & 7) << 2;
            float4 v = *(const float4*)(C + (size_t)(CROSS + ii) * LD + ks + c4);
            As[c4+0][ii] = v.x; As[c4+1][ii] = v.y;
            As[c4+2][ii] = v.z; As[c4+3][ii] = v.w;
        }
        __syncthreads();
        #pragma unroll
        for (int k = 0; k < 32; ++k) {
            float4 b0 = *(const float4*)&As[k][c0];
            float4 b1 = *(const float4*)&As[k][c0 + 4];
            float4 a0 = *(const float4*)&As[k][r0];
            float4 a1 = *(const float4*)&As[k][r0 + 4];
            float ar[8] = {a0.x, a0.y, a0.z, a0.w, a1.x, a1.y, a1.z, a1.w};
            #pragma unroll
            for (int r = 0; r < 8; ++r) {
                fma4(acc[r][0], ar[r], b0);
                fma4(acc[r][1], ar[r], b1);
            }
        }
        __syncthreads();
    }

    #pragma unroll
    for (int r = 0; r < 8; ++r) {
        float* cp = C + (size_t)(r0 + r) * LD + 512 + z * 128 + c0;
        *(float4*)cp = acc[r][0];
        *((float4*)cp + 1) = acc[r][1];
    }
}

// ---------------- fused tailreduce + per-sample finish ----------------
__global__ __launch_bounds__(512)
void finish_kernel(const float* __restrict__ covb, const float* __restrict__ bvec,
                   const float* __restrict__ stats, float* __restrict__ out,
                   const float* __restrict__ scal, int mbase)
{
    int ml = blockIdx.x;
    int m  = mbase + ml;
    const float* C = covb + (size_t)ml * NN * LD;
    __shared__ __align__(16) float A11[NB][68];   // tail block 11; after TRSM: k-major L21 (Ps)
    __shared__ __align__(16) float A21[NB][68];   // tail rows 64..127, cols 0..63
    __shared__ __align__(16) float A22[NB][68];
    __shared__ float rs_s[NB], sol_s[NB];
    __shared__ float bt[TB];
    __shared__ float s_quad, s_ld;
    int tid = threadIdx.x;

    if (tid < TB) bt[tid] = bvec[(size_t)m * NN + CROSS + tid];
    if (tid == 0) { s_quad = 0.f; s_ld = 0.f; }

    // ---- fused tail reduce: A = C_tail - sum_z partials ----
    float4 tv[6], p0[6], p1[6], p2[6], p3[6];
    const float* pbase[6];
    #pragma unroll
    for (int u = 0; u < 6; ++u) {
        int f   = tid + u * 512;
        int i   = (f & 1023) >> 4;
        int c4  = (f & 15) << 2;
        int blk = f >> 10;
        int ti  = (blk == 0) ? i : (64 + i);         // tail-local row
        int tc  = (blk == 2) ? (64 + c4) : c4;       // tail-local col
        pbase[u] = C + (size_t)ti * LD + 512 + tc;
        tv[u] = *(const float4*)(C + (size_t)(CROSS + ti) * LD + CROSS + tc);
    }
    #pragma unroll
    for (int u = 0; u < 6; ++u) p0[u] = *(const float4*)(pbase[u]);
    #pragma unroll
    for (int u = 0; u < 6; ++u) p1[u] = *(const float4*)(pbase[u] + 128);
    #pragma unroll
    for (int u = 0; u < 6; ++u) p2[u] = *(const float4*)(pbase[u] + 256);
    #pragma unroll
    for (int u = 0; u < 6; ++u) p3[u] = *(const float4*)(pbase[u] + 384);
    #pragma unroll
    for (int u = 0; u < 6; ++u) {
        int f   = tid + u * 512;
        int i   = (f & 1023) >> 4;
        int c4  = (f & 15) << 2;
        int blk = f >> 10;
        float4 s;
        s.x = ((p0[u].x + p1[u].x) + p2[u].x) + p3[u].x;
        s.y = ((p0[u].y + p1[u].y) + p2[u].y) + p3[u].y;
        s.z = ((p0[u].z + p1[u].z) + p2[u].z) + p3[u].z;
        s.w = ((p0[u].w + p1[u].w) + p2[u].w) + p3[u].w;
        float4 t = tv[u];
        t.x -= s.x; t.y -= s.y; t.z -= s.z; t.w -= s.w;
        float* dst = (blk == 0) ? &A11[i][c4] : ((blk == 1) ? &A21[i][c4] : &A22[i][c4]);
        *(float4*)dst = t;
    }
    __syncthreads();

    // ---- factor A11 (64x64), scaled rows back into A11 ----
    if (tid < 64) {
        int r = tid;
        float row[NB];
        #pragma unroll
        for (int q = 0; q < NB/4; ++q) {
            float4 v = *(const float4*)&A11[r][4*q];
            row[4*q+0] = v.x; row[4*q+1] = v.y; row[4*q+2] = v.z; row[4*q+3] = v.w;
        }
        float b = bt[r];
        float quad_add = 0.f, my_d = 1.f;
        #pragma unroll
        for (int j = 0; j < NB; ++j) {
            float dj = fmaxf(bcastf(row[j], j), 1e-30f);
            float rs = rsqrtf(dj);
            if (r == j) my_d = dj;
            row[j] *= rs;
            float sj = bcastf(b, j) * rs;
            quad_add = fmaf(sj, sj, quad_add);
            b = fmaf(-row[j], sj, b);
            if (r == j) { rs_s[j] = rs; sol_s[j] = sj; }
            #pragma unroll
            for (int c = j + 1; c < NB; ++c) {
                float s = bcastf(row[j], c);
                row[c] = fmaf(-row[j], s, row[c]);
            }
        }
        #pragma unroll
        for (int q = 0; q < NB/4; ++q) {
            float4 v; v.x = row[4*q]; v.y = row[4*q+1]; v.z = row[4*q+2]; v.w = row[4*q+3];
            *(float4*)&A11[r][4*q] = v;
        }
        float ldv = logf(my_d);
        #pragma unroll
        for (int off = 32; off > 0; off >>= 1) ldv += __shfl_down(ldv, off);
        if (r == 0) { s_quad += quad_add; s_ld += ldv; }
    }
    __syncthreads();

    // ---- TRSM: rows of A21 (wave 1); result transposed into A11 (k-major Ps) ----
    if (tid >= 64 && tid < 128) {
        int rr = tid - 64;
        float l[NB];
        #pragma unroll
        for (int q = 0; q < NB/4; ++q) {
            float4 v = *(const float4*)&A21[rr][4*q];
            l[4*q] = v.x; l[4*q+1] = v.y; l[4*q+2] = v.z; l[4*q+3] = v.w;
        }
        #pragma unroll
        for (int j = 0; j < NB; ++j) {
            float s0 = l[j], s1 = 0.f, s2 = 0.f, s3 = 0.f;
            int c = 0;
            #pragma unroll
            for (; c + 4 <= j; c += 4) {
                float4 t = *(const float4*)&A11[j][c];
                s0 = fmaf(-l[c],   t.x, s0);
                s1 = fmaf(-l[c+1], t.y, s1);
                s2 = fmaf(-l[c+2], t.z, s2);
                s3 = fmaf(-l[c+3], t.w, s3);
            }
            #pragma unroll
            for (; c < j; ++c) s0 = fmaf(-l[c], A11[j][c], s0);
            l[j] = ((s0 + s1) + (s2 + s3)) * rs_s[j];
        }
        // A11 is dead now; single-wave program order makes this race-free.
        #pragma unroll
        for (int k = 0; k < NB; ++k) A11[k][rr] = l[k];   // Ps[k][rr]
        float bacc = 0.f;
        #pragma unroll
        for (int j = 0; j < NB; ++j) bacc = fmaf(l[j], sol_s[j], bacc);
        bt[64 + rr] -= bacc;
    }
    __syncthreads();

    // ---- SYRK: A22 -= L21 * L21^T, k-major Ps (= A11), conflict-free ----
    for (int idx = tid; idx < 64 * 16; idx += 512) {
        int i  = idx >> 4;
        int j4 = (idx & 15) << 2;
        if (j4 > i) continue;
        float4 a = make_float4(0,0,0,0);
        #pragma unroll 8
        for (int k = 0; k < NB; ++k) {
            float4 pj = *(const float4*)&A11[k][j4];
            fma4(a, A11[k][i], pj);
        }
        float* cp = &A22[i][j4];
        float4 uu = *(float4*)cp;
        uu.x -= a.x; uu.y -= a.y; uu.z -= a.z; uu.w -= a.w;
        *(float4*)cp = uu;
    }
    __syncthreads();

    // ---- factor A22 (64x64); only logdet + quad needed ----
    if (tid < 64) {
        int r = tid;
        float row[NB];
        #pragma unroll
        for (int q = 0; q < NB/4; ++q) {
            float4 v = *(const float4*)&A22[r][4*q];
            row[4*q+0] = v.x; row[4*q+1] = v.y; row[4*q+2] = v.z; row[4*q+3] = v.w;
        }
        float b = bt[64 + r];
        float quad_add = 0.f, my_d = 1.f;
        #pragma unroll
        for (int j = 0; j < NB; ++j) {
            float dj = fmaxf(bcastf(row[j], j), 1e-30f);
            float rs = rsqrtf(dj);
            if (r == j) my_d = dj;
            row[j] *= rs;
            float sj = bcastf(b, j) * rs;
            quad_add = fmaf(sj, sj, quad_add);
            b = fmaf(-row[j], sj, b);
            #pragma unroll
            for (int c = j + 1; c < NB; ++c) {
                float s = bcastf(row[j], c);
                row[c] = fmaf(-row[j], s, row[c]);
            }
        }
        float ldv = logf(my_d);
        #pragma unroll
        for (int off = 32; off > 0; off >>= 1) ldv += __shfl_down(ldv, off);
        if (r == 0) { s_quad += quad_add; s_ld += ldv; }
    }
    __syncthreads();

    if (tid == 0) {
        float qt = stats[2*m]   + s_quad;
        float lt = stats[2*m+1] + s_ld;
        out[m] = -0.5f * (qt + lt + (float)NN * LOG2PI) + scal[5*NSAMP + m];
    }
}

extern "C" void kernel_launch(void* const* d_in, const int* in_sizes, int n_in,
                              void* d_out, int out_size, void* d_ws, size_t ws_size,
                              hipStream_t stream)
{
    const float* x   = (const float*)d_in[0];
    const float* y   = (const float*)d_in[1];
    const float* z   = (const float*)d_in[2];
    const float* qbm = (const float*)d_in[3];
    const float* qbs = (const float*)d_in[4];
    const float* qsm = (const float*)d_in[5];
    const float* qss = (const float*)d_in[6];
    const float* qem = (const float*)d_in[7];
    const float* qes = (const float*)d_in[8];
    const float* qzm = (const float*)d_in[9];
    const float* qzs = (const float*)d_in[10];
    const float* qnm = (const float*)d_in[11];
    const float* qns = (const float*)d_in[12];
    float* out  = (float*)d_out;
    float* ws   = (float*)d_ws;

    // workspace layout (floats)
    float* scal   = ws;                                   // 384 used
    float* bvec   = ws + 1024;                            // 64*1024
    float* stats  = ws + 1024 + NSAMP*NN;                 // 128 used, 512 res
    float* cov    = ws + 1024 + NSAMP*NN + 512;
    size_t headF  = 1024 + (size_t)NSAMP*NN + 512;

    scal_kernel<<<1, 64, 0, stream>>>(z, qbm, qbs, qsm, qss, qem, qes, qzm, qzs, qnm, qns, scal);

    size_t availF = ws_size / 4;
    size_t perM   = (size_t)NN * LD;       // padded per-matrix footprint
    int mc_max = NSAMP;
    if (availF < headF + (size_t)NSAMP * perM) {
        size_t rem = (availF > headF) ? (availF - headF) : 0;
        mc_max = (int)(rem / perM);
        if (mc_max < 1) mc_max = 1;
        if (mc_max > NSAMP) mc_max = NSAMP;
    }

    for (int mb = 0; mb < NSAMP; mb += mc_max) {
        int mc = NSAMP - mb; if (mc > mc_max) mc = mc_max;
        covslim_kernel<<<dim3(16, mc), 256, 0, stream>>>(cov, scal, x, y, bvec, stats, mb);
        for (int q = 0; q < CROSS / NB; ++q) {   // panels p = 0..832
            int p = q * NB;
            int rows = NN - p;                   // includes the diag block
            int rt = (rows + 127) / 128;
            panel_kernel<<<dim3(rt, mc), 256, 0, stream>>>(cov, scal, x, bvec, stats, mb, p);
        }
        tailsyrk_kernel<<<dim3(4, mc), 256, 0, stream>>>(cov);
        finish_kernel<<<mc, 512, 0, stream>>>(cov, bvec, stats, out, scal, mb);
    }
}

// Round 11
// 2065.818 us; speedup vs baseline: 1.3767x; 1.3767x over previous
//
#include <hip/hip_runtime.h>
#include <math.h>

#define NN 1024           // N (logical)
#define LD 1040           // padded leading dimension
#define NB 64             // panel width
#define TB 128            // tail handled by tailsyrk+finish
#define CROSS (NN - TB)   // 896: panel loop covers p < CROSS
#define NSAMP 64          // n_mc

#define CCONST  (-0.91893853320467274f)   // -0.5*log(2*pi)
#define LOG2PI  (1.8378770664093453f)

__device__ __forceinline__ float bcastf(float v, int lane) {
    return __int_as_float(__builtin_amdgcn_readlane(__float_as_int(v), lane));
}
__device__ __forceinline__ float softplus_d(float v) {
    return (v > 20.f ? v : log1pf(expf(v))) + 1e-7f;
}
__device__ __forceinline__ float log_normal_f(float v, float mean, float s, float eps) {
    float d = v - mean;
    return -d * d / (2.f * s * s + eps) - logf(s) + CCONST;
}
__device__ __forceinline__ float log_lognormal_f(float v, float mean, float s) {
    float lv = logf(v);
    float d = lv - mean;
    return -d * d / (2.f * s * s + 1e-6f) - lv - logf(s) + CCONST;
}
__device__ __forceinline__ void fma4(float4& c, float a, const float4& b) {
    c.x = fmaf(a, b.x, c.x); c.y = fmaf(a, b.y, c.y);
    c.z = fmaf(a, b.z, c.z); c.w = fmaf(a, b.w, c.w);
}

// ---------------- per-sample scalars ----------------
__global__ void scal_kernel(const float* __restrict__ z,
    const float* qbm, const float* qbs, const float* qsm, const float* qss,
    const float* qem, const float* qes, const float* qzm, const float* qzs,
    const float* qnm, const float* qns, float* __restrict__ scal)
{
    int m = threadIdx.x;
    if (m >= NSAMP) return;
    float z0 = z[m*5+0], z1 = z[m*5+1], z2 = z[m*5+2], z3 = z[m*5+3], z4 = z[m*5+4];
    float spb = softplus_d(qbs[0]);
    float sps = softplus_d(qss[0]);
    float spe = softplus_d(qes[0]);
    float spz = softplus_d(qzs[0]);
    float spn = softplus_d(qns[0]);
    float sigma2 = expf(z0 * sps + qsm[0]);
    float beta   = z1 * spb + qbm[0];
    float eta    = expf(z2 * spe + qem[0]);
    float lsZ    = expf(z3 * spz + qzm[0]);
    float lsN    = expf(z4 * spn + qnm[0]);
    float s0 = softplus_d(sqrtf(logf(2.f)));
    float lp = log_normal_f(beta, 0.f, 1.f, 1e-5f)
             + log_lognormal_f(sigma2, 1.f, s0)
             + log_lognormal_f(eta,    1.f, s0)
             + log_lognormal_f(lsZ,    1.f, s0)
             + log_lognormal_f(lsN,    1.f, s0);
    float lq = log_normal_f(beta, qbm[0], spb, 1e-5f)
             + log_lognormal_f(sigma2, qsm[0], sps)
             + log_lognormal_f(eta,    qem[0], spe)
             + log_lognormal_f(lsZ,    qzm[0], spz)
             + log_lognormal_f(lsN,    qnm[0], spn);
    scal[m]           = sigma2;
    scal[NSAMP + m]   = eta;
    scal[2*NSAMP + m] = 1.f / lsZ;
    scal[3*NSAMP + m] = 1.f / lsN;
    scal[4*NSAMP + m] = beta;
    scal[5*NSAMP + m] = lp - lq;
}

// ---------------- slim covariance build + bvec/stats init ----------------
__global__ __launch_bounds__(256)
void covslim_kernel(float* __restrict__ cov, const float* __restrict__ scal,
                    const float* __restrict__ x, const float* __restrict__ y,
                    float* __restrict__ bvec, float* __restrict__ stats, int mbase)
{
    int ml = blockIdx.y;
    int m  = mbase + ml;
    float sigma2 = scal[m];
    float eta    = scal[NSAMP + m];
    float ilZ    = scal[2*NSAMP + m];
    float ilN    = scal[3*NSAMP + m];
    float* C = cov + (size_t)ml * NN * LD;
    int tid = threadIdx.x;

    if (blockIdx.x == 0 && tid == 0) { stats[2*m] = 0.f; stats[2*m+1] = 0.f; }

    if (blockIdx.x < 64) {
        // stripe: 16 rows x 64 cols per block (lower triangle only)
        int i  = blockIdx.x * 16 + (tid >> 4);
        int j0 = (tid & 15) * 4;
        if ((tid & 15) == 0) bvec[(size_t)m * NN + i] = y[i] - scal[4*NSAMP + m];
        if (j0 > i) return;
        float xi0 = x[2*i]   * ilZ;
        float xi1 = x[2*i+1] * ilN;
        float4 xa = *(const float4*)(x + 2*j0);
        float4 xb = *(const float4*)(x + 2*j0 + 4);
        float v[4]; float d0, d1;
        d0 = xa.x*ilZ - xi0; d1 = xa.y*ilN - xi1; v[0] = eta*__expf(-0.5f*(d0*d0+d1*d1));
        d0 = xa.z*ilZ - xi0; d1 = xa.w*ilN - xi1; v[1] = eta*__expf(-0.5f*(d0*d0+d1*d1));
        d0 = xb.x*ilZ - xi0; d1 = xb.y*ilN - xi1; v[2] = eta*__expf(-0.5f*(d0*d0+d1*d1));
        d0 = xb.z*ilZ - xi0; d1 = xb.w*ilN - xi1; v[3] = eta*__expf(-0.5f*(d0*d0+d1*d1));
        #pragma unroll
        for (int q = 0; q < 4; ++q) if (j0 + q == i) v[q] += sigma2;
        float* row = C + (size_t)i * LD;
        if (j0 + 3 <= i) {
            float4 o; o.x = v[0]; o.y = v[1]; o.z = v[2]; o.w = v[3];
            *(float4*)(row + j0) = o;
        } else {
            #pragma unroll
            for (int q = 0; q < 4; ++q) if (j0 + q <= i) row[j0+q] = v[q];
        }
    } else {
        // tail: 8 rows x 128 cols per block, full square (upper is harmless)
        int bx2 = blockIdx.x - 64;                 // 0..15
        int i   = CROSS + bx2 * 8 + (tid >> 5);    // 896..1023
        int j0  = CROSS + (tid & 31) * 4;          // 896..1020
        float xi0 = x[2*i]   * ilZ;
        float xi1 = x[2*i+1] * ilN;
        float4 xa = *(const float4*)(x + 2*j0);
        float4 xb = *(const float4*)(x + 2*j0 + 4);
        float v[4]; float d0, d1;
        d0 = xa.x*ilZ - xi0; d1 = xa.y*ilN - xi1; v[0] = eta*__expf(-0.5f*(d0*d0+d1*d1));
        d0 = xa.z*ilZ - xi0; d1 = xa.w*ilN - xi1; v[1] = eta*__expf(-0.5f*(d0*d0+d1*d1));
        d0 = xb.x*ilZ - xi0; d1 = xb.y*ilN - xi1; v[2] = eta*__expf(-0.5f*(d0*d0+d1*d1));
        d0 = xb.z*ilZ - xi0; d1 = xb.w*ilN - xi1; v[3] = eta*__expf(-0.5f*(d0*d0+d1*d1));
        #pragma unroll
        for (int q = 0; q < 4; ++q) if (j0 + q == i) v[q] += sigma2;
        float4 o; o.x = v[0]; o.y = v[1]; o.z = v[2]; o.w = v[3];
        *(float4*)(C + (size_t)i * LD + j0) = o;
    }
}

// ---------------- left-looking block-column update (GEMM, K = p) ----------------
// r22: r18 body, 1D grid with ml = bid % mc. mc=64 ≡ 0 (mod 8) puts all
// blocks of sample ml on XCD ml%8 (bid%8 = ml%8), so the B-panel — read
// redundantly by every row-tile block of the sample (the 28 vs 16.8 MB
// FETCH gap at p=64) — lands in ONE local L2 instead of 8.
__global__ __launch_bounds__(256)
void update_kernel(float* __restrict__ covb, const float* __restrict__ scal,
                   const float* __restrict__ x, int mbase, int p, int mc)
{
    int bid = blockIdx.x;
    int ml  = bid % mc;
    int bx  = bid / mc;
    int m  = mbase + ml;
    float* C = covb + (size_t)ml * NN * LD;
    int rowbase = p + bx * 128;

    __shared__ __align__(16) float As[32][132];  // k-major, 128 rows
    __shared__ __align__(16) float Bs[32][68];   // k-major, 64 rows

    int tid = threadIdx.x;
    int tx = tid & 7,  ty = tid >> 3;
    int c0 = tx * 8,   r0 = ty * 4;

    float4 acc[4][2];
    #pragma unroll
    for (int r = 0; r < 4; ++r) { acc[r][0] = make_float4(0,0,0,0); acc[r][1] = make_float4(0,0,0,0); }

    for (int ks = 0; ks < p; ks += 32) {
        for (int idx = tid; idx < 128 * 8; idx += 256) {
            int ii = idx >> 3;
            int c4 = (idx & 7) << 2;
            int gr = rowbase + ii;
            float4 v = make_float4(0,0,0,0);
            if (gr < NN) v = *(const float4*)(C + (size_t)gr * LD + ks + c4);
            As[c4+0][ii] = v.x; As[c4+1][ii] = v.y;
            As[c4+2][ii] = v.z; As[c4+3][ii] = v.w;
        }
        for (int idx = tid; idx < 64 * 8; idx += 256) {
            int ii = idx >> 3;
            int c4 = (idx & 7) << 2;
            float4 v = *(const float4*)(C + (size_t)(p + ii) * LD + ks + c4);
            Bs[c4+0][ii] = v.x; Bs[c4+1][ii] = v.y;
            Bs[c4+2][ii] = v.z; Bs[c4+3][ii] = v.w;
        }
        __syncthreads();
        #pragma unroll
        for (int k = 0; k < 32; ++k) {
            float4 b0 = *(const float4*)&Bs[k][c0];
            float4 b1 = *(const float4*)&Bs[k][c0 + 4];
            float4 a0 = *(const float4*)&As[k][r0];
            float ar[4] = {a0.x, a0.y, a0.z, a0.w};
            #pragma unroll
            for (int r = 0; r < 4; ++r) {
                fma4(acc[r][0], ar[r], b0);
                fma4(acc[r][1], ar[r], b1);
            }
        }
        __syncthreads();
    }

    int jcol = p + c0;
    float sigma2 = scal[m];
    float eta    = scal[NSAMP + m];
    float ilZ    = scal[2*NSAMP + m];
    float ilN    = scal[3*NSAMP + m];
    float4 xa0 = *(const float4*)(x + 2*jcol);
    float4 xb0 = *(const float4*)(x + 2*jcol + 4);
    float4 xa1 = *(const float4*)(x + 2*jcol + 8);
    float4 xb1 = *(const float4*)(x + 2*jcol + 12);
    #pragma unroll
    for (int r = 0; r < 4; ++r) {
        int g = rowbase + r0 + r;
        if (g < NN) {
            float xi0 = x[2*g]   * ilZ;
            float xi1 = x[2*g+1] * ilN;
            float v[8]; float d0, d1;
            d0 = xa0.x*ilZ - xi0; d1 = xa0.y*ilN - xi1; v[0] = eta*__expf(-0.5f*(d0*d0+d1*d1));
            d0 = xa0.z*ilZ - xi0; d1 = xa0.w*ilN - xi1; v[1] = eta*__expf(-0.5f*(d0*d0+d1*d1));
            d0 = xb0.x*ilZ - xi0; d1 = xb0.y*ilN - xi1; v[2] = eta*__expf(-0.5f*(d0*d0+d1*d1));
            d0 = xb0.z*ilZ - xi0; d1 = xb0.w*ilN - xi1; v[3] = eta*__expf(-0.5f*(d0*d0+d1*d1));
            d0 = xa1.x*ilZ - xi0; d1 = xa1.y*ilN - xi1; v[4] = eta*__expf(-0.5f*(d0*d0+d1*d1));
            d0 = xa1.z*ilZ - xi0; d1 = xa1.w*ilN - xi1; v[5] = eta*__expf(-0.5f*(d0*d0+d1*d1));
            d0 = xb1.x*ilZ - xi0; d1 = xb1.y*ilN - xi1; v[6] = eta*__expf(-0.5f*(d0*d0+d1*d1));
            d0 = xb1.z*ilZ - xi0; d1 = xb1.w*ilN - xi1; v[7] = eta*__expf(-0.5f*(d0*d0+d1*d1));
            #pragma unroll
            for (int qq = 0; qq < 8; ++qq) if (jcol + qq == g) v[qq] += sigma2;
            float* cp = C + (size_t)g * LD + jcol;
            float4 u0, u1;
            u0.x = v[0] - acc[r][0].x; u0.y = v[1] - acc[r][0].y;
            u0.z = v[2] - acc[r][0].z; u0.w = v[3] - acc[r][0].w;
            u1.x = v[4] - acc[r][1].x; u1.y = v[5] - acc[r][1].y;
            u1.z = v[6] - acc[r][1].z; u1.w = v[7] - acc[r][1].w;
            *(float4*)cp = u0;
            *((float4*)cp + 1) = u1;
        }
    }
}

// ---------------- small-tile update for late panels (rt*mc starved) ----------------
// r22: same 1D-flatten XCD-locality mapping (ml = bid % mc).
__global__ __launch_bounds__(256)
void update_small_kernel(float* __restrict__ covb, const float* __restrict__ scal,
                         const float* __restrict__ x, int mbase, int p, int mc, int nbx)
{
    int bid  = blockIdx.x;
    int ml   = bid % mc;
    int rest = bid / mc;
    int bx   = rest % nbx;
    int zz   = rest / nbx;
    int m  = mbase + ml;
    float* C = covb + (size_t)ml * NN * LD;
    int rowbase = p + bx * 64;
    int zoff = zz * 32;

    __shared__ __align__(16) float As[32][68];   // k-major, 64 rows
    __shared__ __align__(16) float Bs[32][36];   // k-major, 32 rows

    int tid = threadIdx.x;
    int tx = tid & 7,  ty = tid >> 3;   // 8 col-quads x 32 row-pairs
    int c0 = tx * 4,   r0 = ty * 2;

    float4 acc0 = make_float4(0,0,0,0), acc1 = make_float4(0,0,0,0);

    for (int ks = 0; ks < p; ks += 32) {
        for (int idx = tid; idx < 64 * 8; idx += 256) {
            int ii = idx >> 3;
            int c4 = (idx & 7) << 2;
            int gr = rowbase + ii;
            float4 v = make_float4(0,0,0,0);
            if (gr < NN) v = *(const float4*)(C + (size_t)gr * LD + ks + c4);
            As[c4+0][ii] = v.x; As[c4+1][ii] = v.y;
            As[c4+2][ii] = v.z; As[c4+3][ii] = v.w;
        }
        {
            int idx = tid;                      // 32*8 = 256 exactly
            int ii = idx >> 3;
            int c4 = (idx & 7) << 2;
            float4 v = *(const float4*)(C + (size_t)(p + zoff + ii) * LD + ks + c4);
            Bs[c4+0][ii] = v.x; Bs[c4+1][ii] = v.y;
            Bs[c4+2][ii] = v.z; Bs[c4+3][ii] = v.w;
        }
        __syncthreads();
        #pragma unroll
        for (int k = 0; k < 32; ++k) {
            float4 bv = *(const float4*)&Bs[k][c0];
            float2 av = *(const float2*)&As[k][r0];
            fma4(acc0, av.x, bv);
            fma4(acc1, av.y, bv);
        }
        __syncthreads();
    }

    int jcol = p + zoff + c0;
    float sigma2 = scal[m];
    float eta    = scal[NSAMP + m];
    float ilZ    = scal[2*NSAMP + m];
    float ilN    = scal[3*NSAMP + m];
    float4 xa = *(const float4*)(x + 2*jcol);
    float4 xb = *(const float4*)(x + 2*jcol + 4);
    int g0 = rowbase + r0;
    #pragma unroll
    for (int rr = 0; rr < 2; ++rr) {
        int g = g0 + rr;
        if (g < NN) {
            float xi0 = x[2*g]   * ilZ;
            float xi1 = x[2*g+1] * ilN;
            float v[4]; float d0, d1;
            d0 = xa.x*ilZ - xi0; d1 = xa.y*ilN - xi1; v[0] = eta*__expf(-0.5f*(d0*d0+d1*d1));
            d0 = xa.z*ilZ - xi0; d1 = xa.w*ilN - xi1; v[1] = eta*__expf(-0.5f*(d0*d0+d1*d1));
            d0 = xb.x*ilZ - xi0; d1 = xb.y*ilN - xi1; v[2] = eta*__expf(-0.5f*(d0*d0+d1*d1));
            d0 = xb.z*ilZ - xi0; d1 = xb.w*ilN - xi1; v[3] = eta*__expf(-0.5f*(d0*d0+d1*d1));
            #pragma unroll
            for (int qq = 0; qq < 4; ++qq) if (jcol + qq == g) v[qq] += sigma2;
            const float4 ac = (rr == 0) ? acc0 : acc1;
            float* cp = C + (size_t)g * LD + jcol;
            float4 u;
            u.x = v[0] - ac.x; u.y = v[1] - ac.y; u.z = v[2] - ac.z; u.w = v[3] - ac.w;
            *(float4*)cp = u;
        }
    }
}

// ---------------- fused diag-factor + panel TRSM ----------------
// r22: r18 body, 1D grid with ml = bid % mc. The diag tile (read by every
// block of the sample for the redundant in-block factor) now stays in the
// sample's local XCD L2.
__global__ __launch_bounds__(128)
void trsm_kernel(float* __restrict__ covb, float* __restrict__ bvec,
                 float* __restrict__ stats, int mbase, int p, int mc)
{
    int bid = blockIdx.x;
    int ml  = bid % mc;
    int bx  = bid / mc;
    int m  = mbase + ml;
    float* C = covb + (size_t)ml * NN * LD;
    __shared__ __align__(16) float Tl[NB][68];
    __shared__ float rs_s[NB], sol_s[NB];
    int tid = threadIdx.x;

    // preload solve rows (global loads in flight while wave 0 factors)
    int r0 = p + NB + bx * 128 + tid;
    bool have = (r0 < NN);
    float l[NB];
    if (have) {
        const float* rowp = C + (size_t)r0 * LD + p;
        #pragma unroll
        for (int q = 0; q < NB/4; ++q) {
            float4 v = *(const float4*)(rowp + 4*q);
            l[4*q] = v.x; l[4*q+1] = v.y; l[4*q+2] = v.z; l[4*q+3] = v.w;
        }
    }

    // ---- in-block diag factor (wave 0), verbatim old diag_kernel arithmetic
    if (tid < 64) {
        int r = tid;
        float row[NB];
        const float* src = C + (size_t)(p + r) * LD + p;
        #pragma unroll
        for (int q = 0; q < NB/4; ++q) {
            float4 v = *(const float4*)(src + 4*q);
            row[4*q+0] = v.x; row[4*q+1] = v.y; row[4*q+2] = v.z; row[4*q+3] = v.w;
        }
        float b = bvec[(size_t)m * NN + p + r];
        float quad_add = 0.f, my_d = 1.f, my_rs = 0.f, my_sol = 0.f;
        #pragma unroll
        for (int j = 0; j < NB; ++j) {
            float dj = fmaxf(bcastf(row[j], j), 1e-30f);
            float rs = rsqrtf(dj);
            if (r == j) my_d = dj;
            row[j] *= rs;                       // row[j] = L[r][j] for r>=j
            float sj = bcastf(b, j) * rs;
            quad_add = fmaf(sj, sj, quad_add);
            b = fmaf(-row[j], sj, b);
            if (r == j) { my_rs = rs; my_sol = sj; }
            #pragma unroll
            for (int c = j + 1; c < NB; ++c) {
                float s = bcastf(row[j], c);    // = L[c][j]
                row[c] = fmaf(-row[j], s, row[c]);
            }
        }
        #pragma unroll
        for (int q = 0; q < NB/4; ++q) {
            float4 v; v.x = row[4*q]; v.y = row[4*q+1]; v.z = row[4*q+2]; v.w = row[4*q+3];
            *(float4*)&Tl[r][4*q] = v;
        }
        rs_s[r]  = my_rs;
        sol_s[r] = my_sol;
        if (bx == 0) {
            float ldv = logf(my_d);
            #pragma unroll
            for (int off = 32; off > 0; off >>= 1) ldv += __shfl_down(ldv, off);
            if (r == 0) {
                stats[2*m]   += quad_add;
                stats[2*m+1] += ldv;
            }
        }
    }
    __syncthreads();

    if (!have) return;
    float* rowp = C + (size_t)r0 * LD + p;
    #pragma unroll
    for (int j = 0; j < NB; ++j) {
        float s0 = l[j], s1 = 0.f, s2 = 0.f, s3 = 0.f;
        int c = 0;
        #pragma unroll
        for (; c + 4 <= j; c += 4) {
            float4 t = *(const float4*)&Tl[j][c];
            s0 = fmaf(-l[c],   t.x, s0);
            s1 = fmaf(-l[c+1], t.y, s1);
            s2 = fmaf(-l[c+2], t.z, s2);
            s3 = fmaf(-l[c+3], t.w, s3);
        }
        #pragma unroll
        for (; c < j; ++c) s0 = fmaf(-l[c], Tl[j][c], s0);
        l[j] = ((s0 + s1) + (s2 + s3)) * rs_s[j];
    }
    #pragma unroll
    for (int q = 0; q < NB/4; ++q) {
        float4 v; v.x = l[4*q]; v.y = l[4*q+1]; v.z = l[4*q+2]; v.w = l[4*q+3];
        *(float4*)(rowp + 4*q) = v;
    }
    float b0 = 0.f, b1 = 0.f, b2 = 0.f, b3 = 0.f;
    #pragma unroll
    for (int j = 0; j < NB; j += 4) {
        b0 = fmaf(l[j],   sol_s[j],   b0);
        b1 = fmaf(l[j+1], sol_s[j+1], b1);
        b2 = fmaf(l[j+2], sol_s[j+2], b2);
        b3 = fmaf(l[j+3], sol_s[j+3], b3);
    }
    bvec[(size_t)m * NN + r0] -= ((b0 + b1) + (b2 + b3));
}

// ---------------- tail SYRK, split-K partials ----------------
__global__ __launch_bounds__(256)
void tailsyrk_kernel(float* __restrict__ covb)
{
    int ml = blockIdx.y;
    float* C = covb + (size_t)ml * NN * LD;
    int z  = blockIdx.x;
    int k0 = z * (CROSS / 4);            // 224 per segment

    __shared__ __align__(16) float As[32][132];
    int tid = threadIdx.x;
    int tx = tid & 15, ty = tid >> 4;
    int c0 = tx * 8, r0 = ty * 8;

    float4 acc[8][2];
    #pragma unroll
    for (int r = 0; r < 8; ++r) { acc[r][0] = make_float4(0,0,0,0); acc[r][1] = make_float4(0,0,0,0); }

    for (int ks = k0; ks < k0 + CROSS/4; ks += 32) {
        for (int idx = tid; idx < 128 * 8; idx += 256) {
            int ii = idx >> 3;
            int c4 = (idx & 7) << 2;
            float4 v = *(const float4*)(C + (size_t)(CROSS + ii) * LD + ks + c4);
            As[c4+0][ii] = v.x; As[c4+1][ii] = v.y;
            As[c4+2][ii] = v.z; As[c4+3][ii] = v.w;
        }
        __syncthreads();
        #pragma unroll
        for (int k = 0; k < 32; ++k) {
            float4 b0 = *(const float4*)&As[k][c0];
            float4 b1 = *(const float4*)&As[k][c0 + 4];
            float4 a0 = *(const float4*)&As[k][r0];
            float4 a1 = *(const float4*)&As[k][r0 + 4];
            float ar[8] = {a0.x, a0.y, a0.z, a0.w, a1.x, a1.y, a1.z, a1.w};
            #pragma unroll
            for (int r = 0; r < 8; ++r) {
                fma4(acc[r][0], ar[r], b0);
                fma4(acc[r][1], ar[r], b1);
            }
        }
        __syncthreads();
    }

    #pragma unroll
    for (int r = 0; r < 8; ++r) {
        float* cp = C + (size_t)(r0 + r) * LD + 512 + z * 128 + c0;
        *(float4*)cp = acc[r][0];
        *((float4*)cp + 1) = acc[r][1];
    }
}

// ---------------- fused tailreduce + per-sample finish ----------------
__global__ __launch_bounds__(512)
void finish_kernel(const float* __restrict__ covb, const float* __restrict__ bvec,
                   const float* __restrict__ stats, float* __restrict__ out,
                   const float* __restrict__ scal, int mbase)
{
    int ml = blockIdx.x;
    int m  = mbase + ml;
    const float* C = covb + (size_t)ml * NN * LD;
    __shared__ __align__(16) float A11[NB][68];   // tail block 11; after TRSM: k-major L21 (Ps)
    __shared__ __align__(16) float A21[NB][68];   // tail rows 64..127, cols 0..63
    __shared__ __align__(16) float A22[NB][68];
    __shared__ float rs_s[NB], sol_s[NB];
    __shared__ float bt[TB];
    __shared__ float s_quad, s_ld;
    int tid = threadIdx.x;

    if (tid < TB) bt[tid] = bvec[(size_t)m * NN + CROSS + tid];
    if (tid == 0) { s_quad = 0.f; s_ld = 0.f; }

    // ---- fused tail reduce: A = C_tail - sum_z partials ----
    float4 tv[6], p0[6], p1[6], p2[6], p3[6];
    const float* pbase[6];
    #pragma unroll
    for (int u = 0; u < 6; ++u) {
        int f   = tid + u * 512;
        int i   = (f & 1023) >> 4;
        int c4  = (f & 15) << 2;
        int blk = f >> 10;
        int ti  = (blk == 0) ? i : (64 + i);         // tail-local row
        int tc  = (blk == 2) ? (64 + c4) : c4;       // tail-local col
        pbase[u] = C + (size_t)ti * LD + 512 + tc;
        tv[u] = *(const float4*)(C + (size_t)(CROSS + ti) * LD + CROSS + tc);
    }
    #pragma unroll
    for (int u = 0; u < 6; ++u) p0[u] = *(const float4*)(pbase[u]);
    #pragma unroll
    for (int u = 0; u < 6; ++u) p1[u] = *(const float4*)(pbase[u] + 128);
    #pragma unroll
    for (int u = 0; u < 6; ++u) p2[u] = *(const float4*)(pbase[u] + 256);
    #pragma unroll
    for (int u = 0; u < 6; ++u) p3[u] = *(const float4*)(pbase[u] + 384);
    #pragma unroll
    for (int u = 0; u < 6; ++u) {
        int f   = tid + u * 512;
        int i   = (f & 1023) >> 4;
        int c4  = (f & 15) << 2;
        int blk = f >> 10;
        float4 s;
        s.x = ((p0[u].x + p1[u].x) + p2[u].x) + p3[u].x;
        s.y = ((p0[u].y + p1[u].y) + p2[u].y) + p3[u].y;
        s.z = ((p0[u].z + p1[u].z) + p2[u].z) + p3[u].z;
        s.w = ((p0[u].w + p1[u].w) + p2[u].w) + p3[u].w;
        float4 t = tv[u];
        t.x -= s.x; t.y -= s.y; t.z -= s.z; t.w -= s.w;
        float* dst = (blk == 0) ? &A11[i][c4] : ((blk == 1) ? &A21[i][c4] : &A22[i][c4]);
        *(float4*)dst = t;
    }
    __syncthreads();

    // ---- factor A11 (64x64), scaled rows back into A11 ----
    if (tid < 64) {
        int r = tid;
        float row[NB];
        #pragma unroll
        for (int q = 0; q < NB/4; ++q) {
            float4 v = *(const float4*)&A11[r][4*q];
            row[4*q+0] = v.x; row[4*q+1] = v.y; row[4*q+2] = v.z; row[4*q+3] = v.w;
        }
        float b = bt[r];
        float quad_add = 0.f, my_d = 1.f;
        #pragma unroll
        for (int j = 0; j < NB; ++j) {
            float dj = fmaxf(bcastf(row[j], j), 1e-30f);
            float rs = rsqrtf(dj);
            if (r == j) my_d = dj;
            row[j] *= rs;
            float sj = bcastf(b, j) * rs;
            quad_add = fmaf(sj, sj, quad_add);
            b = fmaf(-row[j], sj, b);
            if (r == j) { rs_s[j] = rs; sol_s[j] = sj; }
            #pragma unroll
            for (int c = j + 1; c < NB; ++c) {
                float s = bcastf(row[j], c);
                row[c] = fmaf(-row[j], s, row[c]);
            }
        }
        #pragma unroll
        for (int q = 0; q < NB/4; ++q) {
            float4 v; v.x = row[4*q]; v.y = row[4*q+1]; v.z = row[4*q+2]; v.w = row[4*q+3];
            *(float4*)&A11[r][4*q] = v;
        }
        float ldv = logf(my_d);
        #pragma unroll
        for (int off = 32; off > 0; off >>= 1) ldv += __shfl_down(ldv, off);
        if (r == 0) { s_quad += quad_add; s_ld += ldv; }
    }
    __syncthreads();

    // ---- TRSM: rows of A21 (wave 1); result transposed into A11 (k-major Ps) ----
    if (tid >= 64 && tid < 128) {
        int rr = tid - 64;
        float l[NB];
        #pragma unroll
        for (int q = 0; q < NB/4; ++q) {
            float4 v = *(const float4*)&A21[rr][4*q];
            l[4*q] = v.x; l[4*q+1] = v.y; l[4*q+2] = v.z; l[4*q+3] = v.w;
        }
        #pragma unroll
        for (int j = 0; j < NB; ++j) {
            float s0 = l[j], s1 = 0.f, s2 = 0.f, s3 = 0.f;
            int c = 0;
            #pragma unroll
            for (; c + 4 <= j; c += 4) {
                float4 t = *(const float4*)&A11[j][c];
                s0 = fmaf(-l[c],   t.x, s0);
                s1 = fmaf(-l[c+1], t.y, s1);
                s2 = fmaf(-l[c+2], t.z, s2);
                s3 = fmaf(-l[c+3], t.w, s3);
            }
            #pragma unroll
            for (; c < j; ++c) s0 = fmaf(-l[c], A11[j][c], s0);
            l[j] = ((s0 + s1) + (s2 + s3)) * rs_s[j];
        }
        // A11 is dead now; single-wave program order makes this race-free.
        #pragma unroll
        for (int k = 0; k < NB; ++k) A11[k][rr] = l[k];   // Ps[k][rr]
        float bacc = 0.f;
        #pragma unroll
        for (int j = 0; j < NB; ++j) bacc = fmaf(l[j], sol_s[j], bacc);
        bt[64 + rr] -= bacc;
    }
    __syncthreads();

    // ---- SYRK: A22 -= L21 * L21^T, k-major Ps (= A11), conflict-free ----
    for (int idx = tid; idx < 64 * 16; idx += 512) {
        int i  = idx >> 4;
        int j4 = (idx & 15) << 2;
        if (j4 > i) continue;
        float4 a = make_float4(0,0,0,0);
        #pragma unroll 8
        for (int k = 0; k < NB; ++k) {
            float4 pj = *(const float4*)&A11[k][j4];
            fma4(a, A11[k][i], pj);
        }
        float* cp = &A22[i][j4];
        float4 uu = *(float4*)cp;
        uu.x -= a.x; uu.y -= a.y; uu.z -= a.z; uu.w -= a.w;
        *(float4*)cp = uu;
    }
    __syncthreads();

    // ---- factor A22 (64x64); only logdet + quad needed ----
    if (tid < 64) {
        int r = tid;
        float row[NB];
        #pragma unroll
        for (int q = 0; q < NB/4; ++q) {
            float4 v = *(const float4*)&A22[r][4*q];
            row[4*q+0] = v.x; row[4*q+1] = v.y; row[4*q+2] = v.z; row[4*q+3] = v.w;
        }
        float b = bt[64 + r];
        float quad_add = 0.f, my_d = 1.f;
        #pragma unroll
        for (int j = 0; j < NB; ++j) {
            float dj = fmaxf(bcastf(row[j], j), 1e-30f);
            float rs = rsqrtf(dj);
            if (r == j) my_d = dj;
            row[j] *= rs;
            float sj = bcastf(b, j) * rs;
            quad_add = fmaf(sj, sj, quad_add);
            b = fmaf(-row[j], sj, b);
            #pragma unroll
            for (int c = j + 1; c < NB; ++c) {
                float s = bcastf(row[j], c);
                row[c] = fmaf(-row[j], s, row[c]);
            }
        }
        float ldv = logf(my_d);
        #pragma unroll
        for (int off = 32; off > 0; off >>= 1) ldv += __shfl_down(ldv, off);
        if (r == 0) { s_quad += quad_add; s_ld += ldv; }
    }
    __syncthreads();

    if (tid == 0) {
        float qt = stats[2*m]   + s_quad;
        float lt = stats[2*m+1] + s_ld;
        out[m] = -0.5f * (qt + lt + (float)NN * LOG2PI) + scal[5*NSAMP + m];
    }
}

extern "C" void kernel_launch(void* const* d_in, const int* in_sizes, int n_in,
                              void* d_out, int out_size, void* d_ws, size_t ws_size,
                              hipStream_t stream)
{
    const float* x   = (const float*)d_in[0];
    const float* y   = (const float*)d_in[1];
    const float* z   = (const float*)d_in[2];
    const float* qbm = (const float*)d_in[3];
    const float* qbs = (const float*)d_in[4];
    const float* qsm = (const float*)d_in[5];
    const float* qss = (const float*)d_in[6];
    const float* qem = (const float*)d_in[7];
    const float* qes = (const float*)d_in[8];
    const float* qzm = (const float*)d_in[9];
    const float* qzs = (const float*)d_in[10];
    const float* qnm = (const float*)d_in[11];
    const float* qns = (const float*)d_in[12];
    float* out  = (float*)d_out;
    float* ws   = (float*)d_ws;

    // workspace layout (floats)
    float* scal   = ws;                                   // 384 used
    float* bvec   = ws + 1024;                            // 64*1024
    float* stats  = ws + 1024 + NSAMP*NN;                 // 128 used, 512 res
    float* cov    = ws + 1024 + NSAMP*NN + 512;
    size_t headF  = 1024 + (size_t)NSAMP*NN + 512;

    scal_kernel<<<1, 64, 0, stream>>>(z, qbm, qbs, qsm, qss, qem, qes, qzm, qzs, qnm, qns, scal);

    size_t availF = ws_size / 4;
    size_t perM   = (size_t)NN * LD;       // padded per-matrix footprint
    int mc_max = NSAMP;
    if (availF < headF + (size_t)NSAMP * perM) {
        size_t rem = (availF > headF) ? (availF - headF) : 0;
        mc_max = (int)(rem / perM);
        if (mc_max < 1) mc_max = 1;
        if (mc_max > NSAMP) mc_max = NSAMP;
    }

    for (int mb = 0; mb < NSAMP; mb += mc_max) {
        int mc = NSAMP - mb; if (mc > mc_max) mc = mc_max;
        covslim_kernel<<<dim3(80, mc), 256, 0, stream>>>(cov, scal, x, y, bvec, stats, mb);
        for (int q = 0; q < CROSS / NB; ++q) {   // panels p = 0..832
            int p = q * NB;
            if (q > 0) {
                int rows = NN - p;
                int rt128 = (rows + 127) / 128;
                if (rt128 * mc >= 256) {
                    update_kernel<<<dim3(rt128 * mc), 256, 0, stream>>>(cov, scal, x, mb, p, mc);
                } else {
                    int rt64 = (rows + 63) / 64;
                    update_small_kernel<<<dim3(rt64 * mc * 2), 256, 0, stream>>>(cov, scal, x, mb, p, mc, rt64);
                }
            }
            int rb = NN - p - NB;
            int rtiles = (rb + 127) / 128;
            trsm_kernel<<<dim3(rtiles * mc), 128, 0, stream>>>(cov, bvec, stats, mb, p, mc);
        }
        tailsyrk_kernel<<<dim3(4, mc), 256, 0, stream>>>(cov);
        finish_kernel<<<mc, 512, 0, stream>>>(cov, bvec, stats, out, scal, mb);
    }
}

// Round 12
// 2045.595 us; speedup vs baseline: 1.3903x; 1.0099x over previous
//
#include <hip/hip_runtime.h>
#include <math.h>

#define NN 1024           // N (logical)
#define LD 1040           // padded leading dimension
#define NB 64             // panel width
#define TB 128            // tail handled by tailsyrk+finish
#define CROSS (NN - TB)   // 896: panel loop covers p < CROSS
#define NSAMP 64          // n_mc

#define CCONST  (-0.91893853320467274f)   // -0.5*log(2*pi)
#define LOG2PI  (1.8378770664093453f)

__device__ __forceinline__ float bcastf(float v, int lane) {
    return __int_as_float(__builtin_amdgcn_readlane(__float_as_int(v), lane));
}
__device__ __forceinline__ float softplus_d(float v) {
    return (v > 20.f ? v : log1pf(expf(v))) + 1e-7f;
}
__device__ __forceinline__ float log_normal_f(float v, float mean, float s, float eps) {
    float d = v - mean;
    return -d * d / (2.f * s * s + eps) - logf(s) + CCONST;
}
__device__ __forceinline__ float log_lognormal_f(float v, float mean, float s) {
    float lv = logf(v);
    float d = lv - mean;
    return -d * d / (2.f * s * s + 1e-6f) - lv - logf(s) + CCONST;
}
__device__ __forceinline__ void fma4(float4& c, float a, const float4& b) {
    c.x = fmaf(a, b.x, c.x); c.y = fmaf(a, b.y, c.y);
    c.z = fmaf(a, b.z, c.z); c.w = fmaf(a, b.w, c.w);
}

// ---------------- per-sample scalars ----------------
__global__ void scal_kernel(const float* __restrict__ z,
    const float* qbm, const float* qbs, const float* qsm, const float* qss,
    const float* qem, const float* qes, const float* qzm, const float* qzs,
    const float* qnm, const float* qns, float* __restrict__ scal)
{
    int m = threadIdx.x;
    if (m >= NSAMP) return;
    float z0 = z[m*5+0], z1 = z[m*5+1], z2 = z[m*5+2], z3 = z[m*5+3], z4 = z[m*5+4];
    float spb = softplus_d(qbs[0]);
    float sps = softplus_d(qss[0]);
    float spe = softplus_d(qes[0]);
    float spz = softplus_d(qzs[0]);
    float spn = softplus_d(qns[0]);
    float sigma2 = expf(z0 * sps + qsm[0]);
    float beta   = z1 * spb + qbm[0];
    float eta    = expf(z2 * spe + qem[0]);
    float lsZ    = expf(z3 * spz + qzm[0]);
    float lsN    = expf(z4 * spn + qnm[0]);
    float s0 = softplus_d(sqrtf(logf(2.f)));
    float lp = log_normal_f(beta, 0.f, 1.f, 1e-5f)
             + log_lognormal_f(sigma2, 1.f, s0)
             + log_lognormal_f(eta,    1.f, s0)
             + log_lognormal_f(lsZ,    1.f, s0)
             + log_lognormal_f(lsN,    1.f, s0);
    float lq = log_normal_f(beta, qbm[0], spb, 1e-5f)
             + log_lognormal_f(sigma2, qsm[0], sps)
             + log_lognormal_f(eta,    qem[0], spe)
             + log_lognormal_f(lsZ,    qzm[0], spz)
             + log_lognormal_f(lsN,    qnm[0], spn);
    scal[m]           = sigma2;
    scal[NSAMP + m]   = eta;
    scal[2*NSAMP + m] = 1.f / lsZ;
    scal[3*NSAMP + m] = 1.f / lsN;
    scal[4*NSAMP + m] = beta;
    scal[5*NSAMP + m] = lp - lq;
}

// ---------------- slim covariance build + bvec/stats init ----------------
__global__ __launch_bounds__(256)
void covslim_kernel(float* __restrict__ cov, const float* __restrict__ scal,
                    const float* __restrict__ x, const float* __restrict__ y,
                    float* __restrict__ bvec, float* __restrict__ stats, int mbase)
{
    int ml = blockIdx.y;
    int m  = mbase + ml;
    float sigma2 = scal[m];
    float eta    = scal[NSAMP + m];
    float ilZ    = scal[2*NSAMP + m];
    float ilN    = scal[3*NSAMP + m];
    float* C = cov + (size_t)ml * NN * LD;
    int tid = threadIdx.x;

    if (blockIdx.x == 0 && tid == 0) { stats[2*m] = 0.f; stats[2*m+1] = 0.f; }

    if (blockIdx.x < 64) {
        // stripe: 16 rows x 64 cols per block (lower triangle only)
        int i  = blockIdx.x * 16 + (tid >> 4);
        int j0 = (tid & 15) * 4;
        if ((tid & 15) == 0) bvec[(size_t)m * NN + i] = y[i] - scal[4*NSAMP + m];
        if (j0 > i) return;
        float xi0 = x[2*i]   * ilZ;
        float xi1 = x[2*i+1] * ilN;
        float4 xa = *(const float4*)(x + 2*j0);
        float4 xb = *(const float4*)(x + 2*j0 + 4);
        float v[4]; float d0, d1;
        d0 = xa.x*ilZ - xi0; d1 = xa.y*ilN - xi1; v[0] = eta*__expf(-0.5f*(d0*d0+d1*d1));
        d0 = xa.z*ilZ - xi0; d1 = xa.w*ilN - xi1; v[1] = eta*__expf(-0.5f*(d0*d0+d1*d1));
        d0 = xb.x*ilZ - xi0; d1 = xb.y*ilN - xi1; v[2] = eta*__expf(-0.5f*(d0*d0+d1*d1));
        d0 = xb.z*ilZ - xi0; d1 = xb.w*ilN - xi1; v[3] = eta*__expf(-0.5f*(d0*d0+d1*d1));
        #pragma unroll
        for (int q = 0; q < 4; ++q) if (j0 + q == i) v[q] += sigma2;
        float* row = C + (size_t)i * LD;
        if (j0 + 3 <= i) {
            float4 o; o.x = v[0]; o.y = v[1]; o.z = v[2]; o.w = v[3];
            *(float4*)(row + j0) = o;
        } else {
            #pragma unroll
            for (int q = 0; q < 4; ++q) if (j0 + q <= i) row[j0+q] = v[q];
        }
    } else {
        // tail: 8 rows x 128 cols per block, full square (upper is harmless)
        int bx2 = blockIdx.x - 64;                 // 0..15
        int i   = CROSS + bx2 * 8 + (tid >> 5);    // 896..1023
        int j0  = CROSS + (tid & 31) * 4;          // 896..1020
        float xi0 = x[2*i]   * ilZ;
        float xi1 = x[2*i+1] * ilN;
        float4 xa = *(const float4*)(x + 2*j0);
        float4 xb = *(const float4*)(x + 2*j0 + 4);
        float v[4]; float d0, d1;
        d0 = xa.x*ilZ - xi0; d1 = xa.y*ilN - xi1; v[0] = eta*__expf(-0.5f*(d0*d0+d1*d1));
        d0 = xa.z*ilZ - xi0; d1 = xa.w*ilN - xi1; v[1] = eta*__expf(-0.5f*(d0*d0+d1*d1));
        d0 = xb.x*ilZ - xi0; d1 = xb.y*ilN - xi1; v[2] = eta*__expf(-0.5f*(d0*d0+d1*d1));
        d0 = xb.z*ilZ - xi0; d1 = xb.w*ilN - xi1; v[3] = eta*__expf(-0.5f*(d0*d0+d1*d1));
        #pragma unroll
        for (int q = 0; q < 4; ++q) if (j0 + q == i) v[q] += sigma2;
        float4 o; o.x = v[0]; o.y = v[1]; o.z = v[2]; o.w = v[3];
        *(float4*)(C + (size_t)i * LD + j0) = o;
    }
}

// ---------------- left-looking block-column update (GEMM, K = p) ----------------
// r22: r18 body, 1D grid with ml = bid % mc (XCD-local B-panel reuse).
// r23: only used when rt128*mc >= 448 (>= ~2 blocks/CU). At exactly 256
// blocks (1/CU) it is maximally latency-exposed; those panels now route
// to update_small (4-6x the blocks).
__global__ __launch_bounds__(256)
void update_kernel(float* __restrict__ covb, const float* __restrict__ scal,
                   const float* __restrict__ x, int mbase, int p, int mc)
{
    int bid = blockIdx.x;
    int ml  = bid % mc;
    int bx  = bid / mc;
    int m  = mbase + ml;
    float* C = covb + (size_t)ml * NN * LD;
    int rowbase = p + bx * 128;

    __shared__ __align__(16) float As[32][132];  // k-major, 128 rows
    __shared__ __align__(16) float Bs[32][68];   // k-major, 64 rows

    int tid = threadIdx.x;
    int tx = tid & 7,  ty = tid >> 3;
    int c0 = tx * 8,   r0 = ty * 4;

    float4 acc[4][2];
    #pragma unroll
    for (int r = 0; r < 4; ++r) { acc[r][0] = make_float4(0,0,0,0); acc[r][1] = make_float4(0,0,0,0); }

    for (int ks = 0; ks < p; ks += 32) {
        for (int idx = tid; idx < 128 * 8; idx += 256) {
            int ii = idx >> 3;
            int c4 = (idx & 7) << 2;
            int gr = rowbase + ii;
            float4 v = make_float4(0,0,0,0);
            if (gr < NN) v = *(const float4*)(C + (size_t)gr * LD + ks + c4);
            As[c4+0][ii] = v.x; As[c4+1][ii] = v.y;
            As[c4+2][ii] = v.z; As[c4+3][ii] = v.w;
        }
        for (int idx = tid; idx < 64 * 8; idx += 256) {
            int ii = idx >> 3;
            int c4 = (idx & 7) << 2;
            float4 v = *(const float4*)(C + (size_t)(p + ii) * LD + ks + c4);
            Bs[c4+0][ii] = v.x; Bs[c4+1][ii] = v.y;
            Bs[c4+2][ii] = v.z; Bs[c4+3][ii] = v.w;
        }
        __syncthreads();
        #pragma unroll
        for (int k = 0; k < 32; ++k) {
            float4 b0 = *(const float4*)&Bs[k][c0];
            float4 b1 = *(const float4*)&Bs[k][c0 + 4];
            float4 a0 = *(const float4*)&As[k][r0];
            float ar[4] = {a0.x, a0.y, a0.z, a0.w};
            #pragma unroll
            for (int r = 0; r < 4; ++r) {
                fma4(acc[r][0], ar[r], b0);
                fma4(acc[r][1], ar[r], b1);
            }
        }
        __syncthreads();
    }

    int jcol = p + c0;
    float sigma2 = scal[m];
    float eta    = scal[NSAMP + m];
    float ilZ    = scal[2*NSAMP + m];
    float ilN    = scal[3*NSAMP + m];
    float4 xa0 = *(const float4*)(x + 2*jcol);
    float4 xb0 = *(const float4*)(x + 2*jcol + 4);
    float4 xa1 = *(const float4*)(x + 2*jcol + 8);
    float4 xb1 = *(const float4*)(x + 2*jcol + 12);
    #pragma unroll
    for (int r = 0; r < 4; ++r) {
        int g = rowbase + r0 + r;
        if (g < NN) {
            float xi0 = x[2*g]   * ilZ;
            float xi1 = x[2*g+1] * ilN;
            float v[8]; float d0, d1;
            d0 = xa0.x*ilZ - xi0; d1 = xa0.y*ilN - xi1; v[0] = eta*__expf(-0.5f*(d0*d0+d1*d1));
            d0 = xa0.z*ilZ - xi0; d1 = xa0.w*ilN - xi1; v[1] = eta*__expf(-0.5f*(d0*d0+d1*d1));
            d0 = xb0.x*ilZ - xi0; d1 = xb0.y*ilN - xi1; v[2] = eta*__expf(-0.5f*(d0*d0+d1*d1));
            d0 = xb0.z*ilZ - xi0; d1 = xb0.w*ilN - xi1; v[3] = eta*__expf(-0.5f*(d0*d0+d1*d1));
            d0 = xa1.x*ilZ - xi0; d1 = xa1.y*ilN - xi1; v[4] = eta*__expf(-0.5f*(d0*d0+d1*d1));
            d0 = xa1.z*ilZ - xi0; d1 = xa1.w*ilN - xi1; v[5] = eta*__expf(-0.5f*(d0*d0+d1*d1));
            d0 = xb1.x*ilZ - xi0; d1 = xb1.y*ilN - xi1; v[6] = eta*__expf(-0.5f*(d0*d0+d1*d1));
            d0 = xb1.z*ilZ - xi0; d1 = xb1.w*ilN - xi1; v[7] = eta*__expf(-0.5f*(d0*d0+d1*d1));
            #pragma unroll
            for (int qq = 0; qq < 8; ++qq) if (jcol + qq == g) v[qq] += sigma2;
            float* cp = C + (size_t)g * LD + jcol;
            float4 u0, u1;
            u0.x = v[0] - acc[r][0].x; u0.y = v[1] - acc[r][0].y;
            u0.z = v[2] - acc[r][0].z; u0.w = v[3] - acc[r][0].w;
            u1.x = v[4] - acc[r][1].x; u1.y = v[5] - acc[r][1].y;
            u1.z = v[6] - acc[r][1].z; u1.w = v[7] - acc[r][1].w;
            *(float4*)cp = u0;
            *((float4*)cp + 1) = u1;
        }
    }
}

// ---------------- small-tile update for late panels (rt*mc starved) ----------------
// r22: same 1D-flatten XCD-locality mapping (ml = bid % mc).
__global__ __launch_bounds__(256)
void update_small_kernel(float* __restrict__ covb, const float* __restrict__ scal,
                         const float* __restrict__ x, int mbase, int p, int mc, int nbx)
{
    int bid  = blockIdx.x;
    int ml   = bid % mc;
    int rest = bid / mc;
    int bx   = rest % nbx;
    int zz   = rest / nbx;
    int m  = mbase + ml;
    float* C = covb + (size_t)ml * NN * LD;
    int rowbase = p + bx * 64;
    int zoff = zz * 32;

    __shared__ __align__(16) float As[32][68];   // k-major, 64 rows
    __shared__ __align__(16) float Bs[32][36];   // k-major, 32 rows

    int tid = threadIdx.x;
    int tx = tid & 7,  ty = tid >> 3;   // 8 col-quads x 32 row-pairs
    int c0 = tx * 4,   r0 = ty * 2;

    float4 acc0 = make_float4(0,0,0,0), acc1 = make_float4(0,0,0,0);

    for (int ks = 0; ks < p; ks += 32) {
        for (int idx = tid; idx < 64 * 8; idx += 256) {
            int ii = idx >> 3;
            int c4 = (idx & 7) << 2;
            int gr = rowbase + ii;
            float4 v = make_float4(0,0,0,0);
            if (gr < NN) v = *(const float4*)(C + (size_t)gr * LD + ks + c4);
            As[c4+0][ii] = v.x; As[c4+1][ii] = v.y;
            As[c4+2][ii] = v.z; As[c4+3][ii] = v.w;
        }
        {
            int idx = tid;                      // 32*8 = 256 exactly
            int ii = idx >> 3;
            int c4 = (idx & 7) << 2;
            float4 v = *(const float4*)(C + (size_t)(p + zoff + ii) * LD + ks + c4);
            Bs[c4+0][ii] = v.x; Bs[c4+1][ii] = v.y;
            Bs[c4+2][ii] = v.z; Bs[c4+3][ii] = v.w;
        }
        __syncthreads();
        #pragma unroll
        for (int k = 0; k < 32; ++k) {
            float4 bv = *(const float4*)&Bs[k][c0];
            float2 av = *(const float2*)&As[k][r0];
            fma4(acc0, av.x, bv);
            fma4(acc1, av.y, bv);
        }
        __syncthreads();
    }

    int jcol = p + zoff + c0;
    float sigma2 = scal[m];
    float eta    = scal[NSAMP + m];
    float ilZ    = scal[2*NSAMP + m];
    float ilN    = scal[3*NSAMP + m];
    float4 xa = *(const float4*)(x + 2*jcol);
    float4 xb = *(const float4*)(x + 2*jcol + 4);
    int g0 = rowbase + r0;
    #pragma unroll
    for (int rr = 0; rr < 2; ++rr) {
        int g = g0 + rr;
        if (g < NN) {
            float xi0 = x[2*g]   * ilZ;
            float xi1 = x[2*g+1] * ilN;
            float v[4]; float d0, d1;
            d0 = xa.x*ilZ - xi0; d1 = xa.y*ilN - xi1; v[0] = eta*__expf(-0.5f*(d0*d0+d1*d1));
            d0 = xa.z*ilZ - xi0; d1 = xa.w*ilN - xi1; v[1] = eta*__expf(-0.5f*(d0*d0+d1*d1));
            d0 = xb.x*ilZ - xi0; d1 = xb.y*ilN - xi1; v[2] = eta*__expf(-0.5f*(d0*d0+d1*d1));
            d0 = xb.z*ilZ - xi0; d1 = xb.w*ilN - xi1; v[3] = eta*__expf(-0.5f*(d0*d0+d1*d1));
            #pragma unroll
            for (int qq = 0; qq < 4; ++qq) if (jcol + qq == g) v[qq] += sigma2;
            const float4 ac = (rr == 0) ? acc0 : acc1;
            float* cp = C + (size_t)g * LD + jcol;
            float4 u;
            u.x = v[0] - ac.x; u.y = v[1] - ac.y; u.z = v[2] - ac.z; u.w = v[3] - ac.w;
            *(float4*)cp = u;
        }
    }
}

// ---------------- fused diag-factor + panel TRSM ----------------
// r22: r18 body, 1D grid with ml = bid % mc (diag tile stays XCD-local).
__global__ __launch_bounds__(128)
void trsm_kernel(float* __restrict__ covb, float* __restrict__ bvec,
                 float* __restrict__ stats, int mbase, int p, int mc)
{
    int bid = blockIdx.x;
    int ml  = bid % mc;
    int bx  = bid / mc;
    int m  = mbase + ml;
    float* C = covb + (size_t)ml * NN * LD;
    __shared__ __align__(16) float Tl[NB][68];
    __shared__ float rs_s[NB], sol_s[NB];
    int tid = threadIdx.x;

    // preload solve rows (global loads in flight while wave 0 factors)
    int r0 = p + NB + bx * 128 + tid;
    bool have = (r0 < NN);
    float l[NB];
    if (have) {
        const float* rowp = C + (size_t)r0 * LD + p;
        #pragma unroll
        for (int q = 0; q < NB/4; ++q) {
            float4 v = *(const float4*)(rowp + 4*q);
            l[4*q] = v.x; l[4*q+1] = v.y; l[4*q+2] = v.z; l[4*q+3] = v.w;
        }
    }

    // ---- in-block diag factor (wave 0), verbatim old diag_kernel arithmetic
    if (tid < 64) {
        int r = tid;
        float row[NB];
        const float* src = C + (size_t)(p + r) * LD + p;
        #pragma unroll
        for (int q = 0; q < NB/4; ++q) {
            float4 v = *(const float4*)(src + 4*q);
            row[4*q+0] = v.x; row[4*q+1] = v.y; row[4*q+2] = v.z; row[4*q+3] = v.w;
        }
        float b = bvec[(size_t)m * NN + p + r];
        float quad_add = 0.f, my_d = 1.f, my_rs = 0.f, my_sol = 0.f;
        #pragma unroll
        for (int j = 0; j < NB; ++j) {
            float dj = fmaxf(bcastf(row[j], j), 1e-30f);
            float rs = rsqrtf(dj);
            if (r == j) my_d = dj;
            row[j] *= rs;                       // row[j] = L[r][j] for r>=j
            float sj = bcastf(b, j) * rs;
            quad_add = fmaf(sj, sj, quad_add);
            b = fmaf(-row[j], sj, b);
            if (r == j) { my_rs = rs; my_sol = sj; }
            #pragma unroll
            for (int c = j + 1; c < NB; ++c) {
                float s = bcastf(row[j], c);    // = L[c][j]
                row[c] = fmaf(-row[j], s, row[c]);
            }
        }
        #pragma unroll
        for (int q = 0; q < NB/4; ++q) {
            float4 v; v.x = row[4*q]; v.y = row[4*q+1]; v.z = row[4*q+2]; v.w = row[4*q+3];
            *(float4*)&Tl[r][4*q] = v;
        }
        rs_s[r]  = my_rs;
        sol_s[r] = my_sol;
        if (bx == 0) {
            float ldv = logf(my_d);
            #pragma unroll
            for (int off = 32; off > 0; off >>= 1) ldv += __shfl_down(ldv, off);
            if (r == 0) {
                stats[2*m]   += quad_add;
                stats[2*m+1] += ldv;
            }
        }
    }
    __syncthreads();

    if (!have) return;
    float* rowp = C + (size_t)r0 * LD + p;
    #pragma unroll
    for (int j = 0; j < NB; ++j) {
        float s0 = l[j], s1 = 0.f, s2 = 0.f, s3 = 0.f;
        int c = 0;
        #pragma unroll
        for (; c + 4 <= j; c += 4) {
            float4 t = *(const float4*)&Tl[j][c];
            s0 = fmaf(-l[c],   t.x, s0);
            s1 = fmaf(-l[c+1], t.y, s1);
            s2 = fmaf(-l[c+2], t.z, s2);
            s3 = fmaf(-l[c+3], t.w, s3);
        }
        #pragma unroll
        for (; c < j; ++c) s0 = fmaf(-l[c], Tl[j][c], s0);
        l[j] = ((s0 + s1) + (s2 + s3)) * rs_s[j];
    }
    #pragma unroll
    for (int q = 0; q < NB/4; ++q) {
        float4 v; v.x = l[4*q]; v.y = l[4*q+1]; v.z = l[4*q+2]; v.w = l[4*q+3];
        *(float4*)(rowp + 4*q) = v;
    }
    float b0 = 0.f, b1 = 0.f, b2 = 0.f, b3 = 0.f;
    #pragma unroll
    for (int j = 0; j < NB; j += 4) {
        b0 = fmaf(l[j],   sol_s[j],   b0);
        b1 = fmaf(l[j+1], sol_s[j+1], b1);
        b2 = fmaf(l[j+2], sol_s[j+2], b2);
        b3 = fmaf(l[j+3], sol_s[j+3], b3);
    }
    bvec[(size_t)m * NN + r0] -= ((b0 + b1) + (b2 + b3));
}

// ---------------- tail SYRK, split-K partials ----------------
__global__ __launch_bounds__(256)
void tailsyrk_kernel(float* __restrict__ covb)
{
    int ml = blockIdx.y;
    float* C = covb + (size_t)ml * NN * LD;
    int z  = blockIdx.x;
    int k0 = z * (CROSS / 4);            // 224 per segment

    __shared__ __align__(16) float As[32][132];
    int tid = threadIdx.x;
    int tx = tid & 15, ty = tid >> 4;
    int c0 = tx * 8, r0 = ty * 8;

    float4 acc[8][2];
    #pragma unroll
    for (int r = 0; r < 8; ++r) { acc[r][0] = make_float4(0,0,0,0); acc[r][1] = make_float4(0,0,0,0); }

    for (int ks = k0; ks < k0 + CROSS/4; ks += 32) {
        for (int idx = tid; idx < 128 * 8; idx += 256) {
            int ii = idx >> 3;
            int c4 = (idx & 7) << 2;
            float4 v = *(const float4*)(C + (size_t)(CROSS + ii) * LD + ks + c4);
            As[c4+0][ii] = v.x; As[c4+1][ii] = v.y;
            As[c4+2][ii] = v.z; As[c4+3][ii] = v.w;
        }
        __syncthreads();
        #pragma unroll
        for (int k = 0; k < 32; ++k) {
            float4 b0 = *(const float4*)&As[k][c0];
            float4 b1 = *(const float4*)&As[k][c0 + 4];
            float4 a0 = *(const float4*)&As[k][r0];
            float4 a1 = *(const float4*)&As[k][r0 + 4];
            float ar[8] = {a0.x, a0.y, a0.z, a0.w, a1.x, a1.y, a1.z, a1.w};
            #pragma unroll
            for (int r = 0; r < 8; ++r) {
                fma4(acc[r][0], ar[r], b0);
                fma4(acc[r][1], ar[r], b1);
            }
        }
        __syncthreads();
    }

    #pragma unroll
    for (int r = 0; r < 8; ++r) {
        float* cp = C + (size_t)(r0 + r) * LD + 512 + z * 128 + c0;
        *(float4*)cp = acc[r][0];
        *((float4*)cp + 1) = acc[r][1];
    }
}

// ---------------- fused tailreduce + per-sample finish ----------------
__global__ __launch_bounds__(512)
void finish_kernel(const float* __restrict__ covb, const float* __restrict__ bvec,
                   const float* __restrict__ stats, float* __restrict__ out,
                   const float* __restrict__ scal, int mbase)
{
    int ml = blockIdx.x;
    int m  = mbase + ml;
    const float* C = covb + (size_t)ml * NN * LD;
    __shared__ __align__(16) float A11[NB][68];   // tail block 11; after TRSM: k-major L21 (Ps)
    __shared__ __align__(16) float A21[NB][68];   // tail rows 64..127, cols 0..63
    __shared__ __align__(16) float A22[NB][68];
    __shared__ float rs_s[NB], sol_s[NB];
    __shared__ float bt[TB];
    __shared__ float s_quad, s_ld;
    int tid = threadIdx.x;

    if (tid < TB) bt[tid] = bvec[(size_t)m * NN + CROSS + tid];
    if (tid == 0) { s_quad = 0.f; s_ld = 0.f; }

    // ---- fused tail reduce: A = C_tail - sum_z partials ----
    float4 tv[6], p0[6], p1[6], p2[6], p3[6];
    const float* pbase[6];
    #pragma unroll
    for (int u = 0; u < 6; ++u) {
        int f   = tid + u * 512;
        int i   = (f & 1023) >> 4;
        int c4  = (f & 15) << 2;
        int blk = f >> 10;
        int ti  = (blk == 0) ? i : (64 + i);         // tail-local row
        int tc  = (blk == 2) ? (64 + c4) : c4;       // tail-local col
        pbase[u] = C + (size_t)ti * LD + 512 + tc;
        tv[u] = *(const float4*)(C + (size_t)(CROSS + ti) * LD + CROSS + tc);
    }
    #pragma unroll
    for (int u = 0; u < 6; ++u) p0[u] = *(const float4*)(pbase[u]);
    #pragma unroll
    for (int u = 0; u < 6; ++u) p1[u] = *(const float4*)(pbase[u] + 128);
    #pragma unroll
    for (int u = 0; u < 6; ++u) p2[u] = *(const float4*)(pbase[u] + 256);
    #pragma unroll
    for (int u = 0; u < 6; ++u) p3[u] = *(const float4*)(pbase[u] + 384);
    #pragma unroll
    for (int u = 0; u < 6; ++u) {
        int f   = tid + u * 512;
        int i   = (f & 1023) >> 4;
        int c4  = (f & 15) << 2;
        int blk = f >> 10;
        float4 s;
        s.x = ((p0[u].x + p1[u].x) + p2[u].x) + p3[u].x;
        s.y = ((p0[u].y + p1[u].y) + p2[u].y) + p3[u].y;
        s.z = ((p0[u].z + p1[u].z) + p2[u].z) + p3[u].z;
        s.w = ((p0[u].w + p1[u].w) + p2[u].w) + p3[u].w;
        float4 t = tv[u];
        t.x -= s.x; t.y -= s.y; t.z -= s.z; t.w -= s.w;
        float* dst = (blk == 0) ? &A11[i][c4] : ((blk == 1) ? &A21[i][c4] : &A22[i][c4]);
        *(float4*)dst = t;
    }
    __syncthreads();

    // ---- factor A11 (64x64), scaled rows back into A11 ----
    if (tid < 64) {
        int r = tid;
        float row[NB];
        #pragma unroll
        for (int q = 0; q < NB/4; ++q) {
            float4 v = *(const float4*)&A11[r][4*q];
            row[4*q+0] = v.x; row[4*q+1] = v.y; row[4*q+2] = v.z; row[4*q+3] = v.w;
        }
        float b = bt[r];
        float quad_add = 0.f, my_d = 1.f;
        #pragma unroll
        for (int j = 0; j < NB; ++j) {
            float dj = fmaxf(bcastf(row[j], j), 1e-30f);
            float rs = rsqrtf(dj);
            if (r == j) my_d = dj;
            row[j] *= rs;
            float sj = bcastf(b, j) * rs;
            quad_add = fmaf(sj, sj, quad_add);
            b = fmaf(-row[j], sj, b);
            if (r == j) { rs_s[j] = rs; sol_s[j] = sj; }
            #pragma unroll
            for (int c = j + 1; c < NB; ++c) {
                float s = bcastf(row[j], c);
                row[c] = fmaf(-row[j], s, row[c]);
            }
        }
        #pragma unroll
        for (int q = 0; q < NB/4; ++q) {
            float4 v; v.x = row[4*q]; v.y = row[4*q+1]; v.z = row[4*q+2]; v.w = row[4*q+3];
            *(float4*)&A11[r][4*q] = v;
        }
        float ldv = logf(my_d);
        #pragma unroll
        for (int off = 32; off > 0; off >>= 1) ldv += __shfl_down(ldv, off);
        if (r == 0) { s_quad += quad_add; s_ld += ldv; }
    }
    __syncthreads();

    // ---- TRSM: rows of A21 (wave 1); result transposed into A11 (k-major Ps) ----
    if (tid >= 64 && tid < 128) {
        int rr = tid - 64;
        float l[NB];
        #pragma unroll
        for (int q = 0; q < NB/4; ++q) {
            float4 v = *(const float4*)&A21[rr][4*q];
            l[4*q] = v.x; l[4*q+1] = v.y; l[4*q+2] = v.z; l[4*q+3] = v.w;
        }
        #pragma unroll
        for (int j = 0; j < NB; ++j) {
            float s0 = l[j], s1 = 0.f, s2 = 0.f, s3 = 0.f;
            int c = 0;
            #pragma unroll
            for (; c + 4 <= j; c += 4) {
                float4 t = *(const float4*)&A11[j][c];
                s0 = fmaf(-l[c],   t.x, s0);
                s1 = fmaf(-l[c+1], t.y, s1);
                s2 = fmaf(-l[c+2], t.z, s2);
                s3 = fmaf(-l[c+3], t.w, s3);
            }
            #pragma unroll
            for (; c < j; ++c) s0 = fmaf(-l[c], A11[j][c], s0);
            l[j] = ((s0 + s1) + (s2 + s3)) * rs_s[j];
        }
        // A11 is dead now; single-wave program order makes this race-free.
        #pragma unroll
        for (int k = 0; k < NB; ++k) A11[k][rr] = l[k];   // Ps[k][rr]
        float bacc = 0.f;
        #pragma unroll
        for (int j = 0; j < NB; ++j) bacc = fmaf(l[j], sol_s[j], bacc);
        bt[64 + rr] -= bacc;
    }
    __syncthreads();

    // ---- SYRK: A22 -= L21 * L21^T, k-major Ps (= A11), conflict-free ----
    for (int idx = tid; idx < 64 * 16; idx += 512) {
        int i  = idx >> 4;
        int j4 = (idx & 15) << 2;
        if (j4 > i) continue;
        float4 a = make_float4(0,0,0,0);
        #pragma unroll 8
        for (int k = 0; k < NB; ++k) {
            float4 pj = *(const float4*)&A11[k][j4];
            fma4(a, A11[k][i], pj);
        }
        float* cp = &A22[i][j4];
        float4 uu = *(float4*)cp;
        uu.x -= a.x; uu.y -= a.y; uu.z -= a.z; uu.w -= a.w;
        *(float4*)cp = uu;
    }
    __syncthreads();

    // ---- factor A22 (64x64); only logdet + quad needed ----
    if (tid < 64) {
        int r = tid;
        float row[NB];
        #pragma unroll
        for (int q = 0; q < NB/4; ++q) {
            float4 v = *(const float4*)&A22[r][4*q];
            row[4*q+0] = v.x; row[4*q+1] = v.y; row[4*q+2] = v.z; row[4*q+3] = v.w;
        }
        float b = bt[64 + r];
        float quad_add = 0.f, my_d = 1.f;
        #pragma unroll
        for (int j = 0; j < NB; ++j) {
            float dj = fmaxf(bcastf(row[j], j), 1e-30f);
            float rs = rsqrtf(dj);
            if (r == j) my_d = dj;
            row[j] *= rs;
            float sj = bcastf(b, j) * rs;
            quad_add = fmaf(sj, sj, quad_add);
            b = fmaf(-row[j], sj, b);
            #pragma unroll
            for (int c = j + 1; c < NB; ++c) {
                float s = bcastf(row[j], c);
                row[c] = fmaf(-row[j], s, row[c]);
            }
        }
        float ldv = logf(my_d);
        #pragma unroll
        for (int off = 32; off > 0; off >>= 1) ldv += __shfl_down(ldv, off);
        if (r == 0) { s_quad += quad_add; s_ld += ldv; }
    }
    __syncthreads();

    if (tid == 0) {
        float qt = stats[2*m]   + s_quad;
        float lt = stats[2*m+1] + s_ld;
        out[m] = -0.5f * (qt + lt + (float)NN * LOG2PI) + scal[5*NSAMP + m];
    }
}

extern "C" void kernel_launch(void* const* d_in, const int* in_sizes, int n_in,
                              void* d_out, int out_size, void* d_ws, size_t ws_size,
                              hipStream_t stream)
{
    const float* x   = (const float*)d_in[0];
    const float* y   = (const float*)d_in[1];
    const float* z   = (const float*)d_in[2];
    const float* qbm = (const float*)d_in[3];
    const float* qbs = (const float*)d_in[4];
    const float* qsm = (const float*)d_in[5];
    const float* qss = (const float*)d_in[6];
    const float* qem = (const float*)d_in[7];
    const float* qes = (const float*)d_in[8];
    const float* qzm = (const float*)d_in[9];
    const float* qzs = (const float*)d_in[10];
    const float* qnm = (const float*)d_in[11];
    const float* qns = (const float*)d_in[12];
    float* out  = (float*)d_out;
    float* ws   = (float*)d_ws;

    // workspace layout (floats)
    float* scal   = ws;                                   // 384 used
    float* bvec   = ws + 1024;                            // 64*1024
    float* stats  = ws + 1024 + NSAMP*NN;                 // 128 used, 512 res
    float* cov    = ws + 1024 + NSAMP*NN + 512;
    size_t headF  = 1024 + (size_t)NSAMP*NN + 512;

    scal_kernel<<<1, 64, 0, stream>>>(z, qbm, qbs, qsm, qss, qem, qes, qzm, qzs, qnm, qns, scal);

    size_t availF = ws_size / 4;
    size_t perM   = (size_t)NN * LD;       // padded per-matrix footprint
    int mc_max = NSAMP;
    if (availF < headF + (size_t)NSAMP * perM) {
        size_t rem = (availF > headF) ? (availF - headF) : 0;
        mc_max = (int)(rem / perM);
        if (mc_max < 1) mc_max = 1;
        if (mc_max > NSAMP) mc_max = NSAMP;
    }

    for (int mb = 0; mb < NSAMP; mb += mc_max) {
        int mc = NSAMP - mb; if (mc > mc_max) mc = mc_max;
        covslim_kernel<<<dim3(80, mc), 256, 0, stream>>>(cov, scal, x, y, bvec, stats, mb);
        for (int q = 0; q < CROSS / NB; ++q) {   // panels p = 0..832
            int p = q * NB;
            if (q > 0) {
                int rows = NN - p;
                int rt128 = (rows + 127) / 128;
                // r23: threshold 256 -> 448. At 256-384 blocks (1-1.5/CU) the
                // big kernel is maximally latency-exposed; route those panels
                // to update_small (4-6x blocks, now L2-local via r22 mapping).
                if (rt128 * mc >= 448) {
                    update_kernel<<<dim3(rt128 * mc), 256, 0, stream>>>(cov, scal, x, mb, p, mc);
                } else {
                    int rt64 = (rows + 63) / 64;
                    update_small_kernel<<<dim3(rt64 * mc * 2), 256, 0, stream>>>(cov, scal, x, mb, p, mc, rt64);
                }
            }
            int rb = NN - p - NB;
            int rtiles = (rb + 127) / 128;
            trsm_kernel<<<dim3(rtiles * mc), 128, 0, stream>>>(cov, bvec, stats, mb, p, mc);
        }
        tailsyrk_kernel<<<dim3(4, mc), 256, 0, stream>>>(cov);
        finish_kernel<<<mc, 512, 0, stream>>>(cov, bvec, stats, out, scal, mb);
    }
}

// Round 13
// 1893.107 us; speedup vs baseline: 1.5023x; 1.0805x over previous
//
#include <hip/hip_runtime.h>
#include <math.h>

#define NN 1024           // N (logical)
#define LD 1040           // padded leading dimension
#define NB 64             // panel width
#define TB 128            // tail handled by tailsyrk+finish
#define CROSS (NN - TB)   // 896: panel loop covers p < CROSS
#define NSAMP 64          // n_mc

#define CCONST  (-0.91893853320467274f)   // -0.5*log(2*pi)
#define LOG2PI  (1.8378770664093453f)

__device__ __forceinline__ float bcastf(float v, int lane) {
    return __int_as_float(__builtin_amdgcn_readlane(__float_as_int(v), lane));
}
__device__ __forceinline__ float softplus_d(float v) {
    return (v > 20.f ? v : log1pf(expf(v))) + 1e-7f;
}
__device__ __forceinline__ float log_normal_f(float v, float mean, float s, float eps) {
    float d = v - mean;
    return -d * d / (2.f * s * s + eps) - logf(s) + CCONST;
}
__device__ __forceinline__ float log_lognormal_f(float v, float mean, float s) {
    float lv = logf(v);
    float d = lv - mean;
    return -d * d / (2.f * s * s + 1e-6f) - lv - logf(s) + CCONST;
}
__device__ __forceinline__ void fma4(float4& c, float a, const float4& b) {
    c.x = fmaf(a, b.x, c.x); c.y = fmaf(a, b.y, c.y);
    c.z = fmaf(a, b.z, c.z); c.w = fmaf(a, b.w, c.w);
}

// ---------------- per-sample scalars ----------------
__global__ void scal_kernel(const float* __restrict__ z,
    const float* qbm, const float* qbs, const float* qsm, const float* qss,
    const float* qem, const float* qes, const float* qzm, const float* qzs,
    const float* qnm, const float* qns, float* __restrict__ scal)
{
    int m = threadIdx.x;
    if (m >= NSAMP) return;
    float z0 = z[m*5+0], z1 = z[m*5+1], z2 = z[m*5+2], z3 = z[m*5+3], z4 = z[m*5+4];
    float spb = softplus_d(qbs[0]);
    float sps = softplus_d(qss[0]);
    float spe = softplus_d(qes[0]);
    float spz = softplus_d(qzs[0]);
    float spn = softplus_d(qns[0]);
    float sigma2 = expf(z0 * sps + qsm[0]);
    float beta   = z1 * spb + qbm[0];
    float eta    = expf(z2 * spe + qem[0]);
    float lsZ    = expf(z3 * spz + qzm[0]);
    float lsN    = expf(z4 * spn + qnm[0]);
    float s0 = softplus_d(sqrtf(logf(2.f)));
    float lp = log_normal_f(beta, 0.f, 1.f, 1e-5f)
             + log_lognormal_f(sigma2, 1.f, s0)
             + log_lognormal_f(eta,    1.f, s0)
             + log_lognormal_f(lsZ,    1.f, s0)
             + log_lognormal_f(lsN,    1.f, s0);
    float lq = log_normal_f(beta, qbm[0], spb, 1e-5f)
             + log_lognormal_f(sigma2, qsm[0], sps)
             + log_lognormal_f(eta,    qem[0], spe)
             + log_lognormal_f(lsZ,    qzm[0], spz)
             + log_lognormal_f(lsN,    qnm[0], spn);
    scal[m]           = sigma2;
    scal[NSAMP + m]   = eta;
    scal[2*NSAMP + m] = 1.f / lsZ;
    scal[3*NSAMP + m] = 1.f / lsN;
    scal[4*NSAMP + m] = beta;
    scal[5*NSAMP + m] = lp - lq;
}

// ---------------- slim covariance build + bvec/stats init ----------------
__global__ __launch_bounds__(256)
void covslim_kernel(float* __restrict__ cov, const float* __restrict__ scal,
                    const float* __restrict__ x, const float* __restrict__ y,
                    float* __restrict__ bvec, float* __restrict__ stats, int mbase)
{
    int ml = blockIdx.y;
    int m  = mbase + ml;
    float sigma2 = scal[m];
    float eta    = scal[NSAMP + m];
    float ilZ    = scal[2*NSAMP + m];
    float ilN    = scal[3*NSAMP + m];
    float* C = cov + (size_t)ml * NN * LD;
    int tid = threadIdx.x;

    if (blockIdx.x == 0 && tid == 0) { stats[2*m] = 0.f; stats[2*m+1] = 0.f; }

    if (blockIdx.x < 64) {
        // stripe: 16 rows x 64 cols per block (lower triangle only)
        int i  = blockIdx.x * 16 + (tid >> 4);
        int j0 = (tid & 15) * 4;
        if ((tid & 15) == 0) bvec[(size_t)m * NN + i] = y[i] - scal[4*NSAMP + m];
        if (j0 > i) return;
        float xi0 = x[2*i]   * ilZ;
        float xi1 = x[2*i+1] * ilN;
        float4 xa = *(const float4*)(x + 2*j0);
        float4 xb = *(const float4*)(x + 2*j0 + 4);
        float v[4]; float d0, d1;
        d0 = xa.x*ilZ - xi0; d1 = xa.y*ilN - xi1; v[0] = eta*__expf(-0.5f*(d0*d0+d1*d1));
        d0 = xa.z*ilZ - xi0; d1 = xa.w*ilN - xi1; v[1] = eta*__expf(-0.5f*(d0*d0+d1*d1));
        d0 = xb.x*ilZ - xi0; d1 = xb.y*ilN - xi1; v[2] = eta*__expf(-0.5f*(d0*d0+d1*d1));
        d0 = xb.z*ilZ - xi0; d1 = xb.w*ilN - xi1; v[3] = eta*__expf(-0.5f*(d0*d0+d1*d1));
        #pragma unroll
        for (int q = 0; q < 4; ++q) if (j0 + q == i) v[q] += sigma2;
        float* row = C + (size_t)i * LD;
        if (j0 + 3 <= i) {
            float4 o; o.x = v[0]; o.y = v[1]; o.z = v[2]; o.w = v[3];
            *(float4*)(row + j0) = o;
        } else {
            #pragma unroll
            for (int q = 0; q < 4; ++q) if (j0 + q <= i) row[j0+q] = v[q];
        }
    } else {
        // tail: 8 rows x 128 cols per block, full square (upper is harmless)
        int bx2 = blockIdx.x - 64;                 // 0..15
        int i   = CROSS + bx2 * 8 + (tid >> 5);    // 896..1023
        int j0  = CROSS + (tid & 31) * 4;          // 896..1020
        float xi0 = x[2*i]   * ilZ;
        float xi1 = x[2*i+1] * ilN;
        float4 xa = *(const float4*)(x + 2*j0);
        float4 xb = *(const float4*)(x + 2*j0 + 4);
        float v[4]; float d0, d1;
        d0 = xa.x*ilZ - xi0; d1 = xa.y*ilN - xi1; v[0] = eta*__expf(-0.5f*(d0*d0+d1*d1));
        d0 = xa.z*ilZ - xi0; d1 = xa.w*ilN - xi1; v[1] = eta*__expf(-0.5f*(d0*d0+d1*d1));
        d0 = xb.x*ilZ - xi0; d1 = xb.y*ilN - xi1; v[2] = eta*__expf(-0.5f*(d0*d0+d1*d1));
        d0 = xb.z*ilZ - xi0; d1 = xb.w*ilN - xi1; v[3] = eta*__expf(-0.5f*(d0*d0+d1*d1));
        #pragma unroll
        for (int q = 0; q < 4; ++q) if (j0 + q == i) v[q] += sigma2;
        float4 o; o.x = v[0]; o.y = v[1]; o.z = v[2]; o.w = v[3];
        *(float4*)(C + (size_t)i * LD + j0) = o;
    }
}

// ---------------- left-looking block-column update (GEMM, K = p) ----------------
// r22: r18 body, 1D grid with ml = bid % mc (XCD-local B-panel reuse).
// r23: only used when rt128*mc >= 448 (>= ~2 blocks/CU).
__global__ __launch_bounds__(256)
void update_kernel(float* __restrict__ covb, const float* __restrict__ scal,
                   const float* __restrict__ x, int mbase, int p, int mc)
{
    int bid = blockIdx.x;
    int ml  = bid % mc;
    int bx  = bid / mc;
    int m  = mbase + ml;
    float* C = covb + (size_t)ml * NN * LD;
    int rowbase = p + bx * 128;

    __shared__ __align__(16) float As[32][132];  // k-major, 128 rows
    __shared__ __align__(16) float Bs[32][68];   // k-major, 64 rows

    int tid = threadIdx.x;
    int tx = tid & 7,  ty = tid >> 3;
    int c0 = tx * 8,   r0 = ty * 4;

    float4 acc[4][2];
    #pragma unroll
    for (int r = 0; r < 4; ++r) { acc[r][0] = make_float4(0,0,0,0); acc[r][1] = make_float4(0,0,0,0); }

    for (int ks = 0; ks < p; ks += 32) {
        for (int idx = tid; idx < 128 * 8; idx += 256) {
            int ii = idx >> 3;
            int c4 = (idx & 7) << 2;
            int gr = rowbase + ii;
            float4 v = make_float4(0,0,0,0);
            if (gr < NN) v = *(const float4*)(C + (size_t)gr * LD + ks + c4);
            As[c4+0][ii] = v.x; As[c4+1][ii] = v.y;
            As[c4+2][ii] = v.z; As[c4+3][ii] = v.w;
        }
        for (int idx = tid; idx < 64 * 8; idx += 256) {
            int ii = idx >> 3;
            int c4 = (idx & 7) << 2;
            float4 v = *(const float4*)(C + (size_t)(p + ii) * LD + ks + c4);
            Bs[c4+0][ii] = v.x; Bs[c4+1][ii] = v.y;
            Bs[c4+2][ii] = v.z; Bs[c4+3][ii] = v.w;
        }
        __syncthreads();
        #pragma unroll
        for (int k = 0; k < 32; ++k) {
            float4 b0 = *(const float4*)&Bs[k][c0];
            float4 b1 = *(const float4*)&Bs[k][c0 + 4];
            float4 a0 = *(const float4*)&As[k][r0];
            float ar[4] = {a0.x, a0.y, a0.z, a0.w};
            #pragma unroll
            for (int r = 0; r < 4; ++r) {
                fma4(acc[r][0], ar[r], b0);
                fma4(acc[r][1], ar[r], b1);
            }
        }
        __syncthreads();
    }

    int jcol = p + c0;
    float sigma2 = scal[m];
    float eta    = scal[NSAMP + m];
    float ilZ    = scal[2*NSAMP + m];
    float ilN    = scal[3*NSAMP + m];
    float4 xa0 = *(const float4*)(x + 2*jcol);
    float4 xb0 = *(const float4*)(x + 2*jcol + 4);
    float4 xa1 = *(const float4*)(x + 2*jcol + 8);
    float4 xb1 = *(const float4*)(x + 2*jcol + 12);
    #pragma unroll
    for (int r = 0; r < 4; ++r) {
        int g = rowbase + r0 + r;
        if (g < NN) {
            float xi0 = x[2*g]   * ilZ;
            float xi1 = x[2*g+1] * ilN;
            float v[8]; float d0, d1;
            d0 = xa0.x*ilZ - xi0; d1 = xa0.y*ilN - xi1; v[0] = eta*__expf(-0.5f*(d0*d0+d1*d1));
            d0 = xa0.z*ilZ - xi0; d1 = xa0.w*ilN - xi1; v[1] = eta*__expf(-0.5f*(d0*d0+d1*d1));
            d0 = xb0.x*ilZ - xi0; d1 = xb0.y*ilN - xi1; v[2] = eta*__expf(-0.5f*(d0*d0+d1*d1));
            d0 = xb0.z*ilZ - xi0; d1 = xb0.w*ilN - xi1; v[3] = eta*__expf(-0.5f*(d0*d0+d1*d1));
            d0 = xa1.x*ilZ - xi0; d1 = xa1.y*ilN - xi1; v[4] = eta*__expf(-0.5f*(d0*d0+d1*d1));
            d0 = xa1.z*ilZ - xi0; d1 = xa1.w*ilN - xi1; v[5] = eta*__expf(-0.5f*(d0*d0+d1*d1));
            d0 = xb1.x*ilZ - xi0; d1 = xb1.y*ilN - xi1; v[6] = eta*__expf(-0.5f*(d0*d0+d1*d1));
            d0 = xb1.z*ilZ - xi0; d1 = xb1.w*ilN - xi1; v[7] = eta*__expf(-0.5f*(d0*d0+d1*d1));
            #pragma unroll
            for (int qq = 0; qq < 8; ++qq) if (jcol + qq == g) v[qq] += sigma2;
            float* cp = C + (size_t)g * LD + jcol;
            float4 u0, u1;
            u0.x = v[0] - acc[r][0].x; u0.y = v[1] - acc[r][0].y;
            u0.z = v[2] - acc[r][0].z; u0.w = v[3] - acc[r][0].w;
            u1.x = v[4] - acc[r][1].x; u1.y = v[5] - acc[r][1].y;
            u1.z = v[6] - acc[r][1].z; u1.w = v[7] - acc[r][1].w;
            *(float4*)cp = u0;
            *((float4*)cp + 1) = u1;
        }
    }
}

// ---------------- small-tile update for late panels (rt*mc starved) ----------------
// r22: same 1D-flatten XCD-locality mapping (ml = bid % mc).
__global__ __launch_bounds__(256)
void update_small_kernel(float* __restrict__ covb, const float* __restrict__ scal,
                         const float* __restrict__ x, int mbase, int p, int mc, int nbx)
{
    int bid  = blockIdx.x;
    int ml   = bid % mc;
    int rest = bid / mc;
    int bx   = rest % nbx;
    int zz   = rest / nbx;
    int m  = mbase + ml;
    float* C = covb + (size_t)ml * NN * LD;
    int rowbase = p + bx * 64;
    int zoff = zz * 32;

    __shared__ __align__(16) float As[32][68];   // k-major, 64 rows
    __shared__ __align__(16) float Bs[32][36];   // k-major, 32 rows

    int tid = threadIdx.x;
    int tx = tid & 7,  ty = tid >> 3;   // 8 col-quads x 32 row-pairs
    int c0 = tx * 4,   r0 = ty * 2;

    float4 acc0 = make_float4(0,0,0,0), acc1 = make_float4(0,0,0,0);

    for (int ks = 0; ks < p; ks += 32) {
        for (int idx = tid; idx < 64 * 8; idx += 256) {
            int ii = idx >> 3;
            int c4 = (idx & 7) << 2;
            int gr = rowbase + ii;
            float4 v = make_float4(0,0,0,0);
            if (gr < NN) v = *(const float4*)(C + (size_t)gr * LD + ks + c4);
            As[c4+0][ii] = v.x; As[c4+1][ii] = v.y;
            As[c4+2][ii] = v.z; As[c4+3][ii] = v.w;
        }
        {
            int idx = tid;                      // 32*8 = 256 exactly
            int ii = idx >> 3;
            int c4 = (idx & 7) << 2;
            float4 v = *(const float4*)(C + (size_t)(p + zoff + ii) * LD + ks + c4);
            Bs[c4+0][ii] = v.x; Bs[c4+1][ii] = v.y;
            Bs[c4+2][ii] = v.z; Bs[c4+3][ii] = v.w;
        }
        __syncthreads();
        #pragma unroll
        for (int k = 0; k < 32; ++k) {
            float4 bv = *(const float4*)&Bs[k][c0];
            float2 av = *(const float2*)&As[k][r0];
            fma4(acc0, av.x, bv);
            fma4(acc1, av.y, bv);
        }
        __syncthreads();
    }

    int jcol = p + zoff + c0;
    float sigma2 = scal[m];
    float eta    = scal[NSAMP + m];
    float ilZ    = scal[2*NSAMP + m];
    float ilN    = scal[3*NSAMP + m];
    float4 xa = *(const float4*)(x + 2*jcol);
    float4 xb = *(const float4*)(x + 2*jcol + 4);
    int g0 = rowbase + r0;
    #pragma unroll
    for (int rr = 0; rr < 2; ++rr) {
        int g = g0 + rr;
        if (g < NN) {
            float xi0 = x[2*g]   * ilZ;
            float xi1 = x[2*g+1] * ilN;
            float v[4]; float d0, d1;
            d0 = xa.x*ilZ - xi0; d1 = xa.y*ilN - xi1; v[0] = eta*__expf(-0.5f*(d0*d0+d1*d1));
            d0 = xa.z*ilZ - xi0; d1 = xa.w*ilN - xi1; v[1] = eta*__expf(-0.5f*(d0*d0+d1*d1));
            d0 = xb.x*ilZ - xi0; d1 = xb.y*ilN - xi1; v[2] = eta*__expf(-0.5f*(d0*d0+d1*d1));
            d0 = xb.z*ilZ - xi0; d1 = xb.w*ilN - xi1; v[3] = eta*__expf(-0.5f*(d0*d0+d1*d1));
            #pragma unroll
            for (int qq = 0; qq < 4; ++qq) if (jcol + qq == g) v[qq] += sigma2;
            const float4 ac = (rr == 0) ? acc0 : acc1;
            float* cp = C + (size_t)g * LD + jcol;
            float4 u;
            u.x = v[0] - ac.x; u.y = v[1] - ac.y; u.z = v[2] - ac.z; u.w = v[3] - ac.w;
            *(float4*)cp = u;
        }
    }
}

// ---------------- fused diag-factor + panel TRSM ----------------
// r22: r18 body, 1D grid with ml = bid % mc (diag tile stays XCD-local).
__global__ __launch_bounds__(128)
void trsm_kernel(float* __restrict__ covb, float* __restrict__ bvec,
                 float* __restrict__ stats, int mbase, int p, int mc)
{
    int bid = blockIdx.x;
    int ml  = bid % mc;
    int bx  = bid / mc;
    int m  = mbase + ml;
    float* C = covb + (size_t)ml * NN * LD;
    __shared__ __align__(16) float Tl[NB][68];
    __shared__ float rs_s[NB], sol_s[NB];
    int tid = threadIdx.x;

    // preload solve rows (global loads in flight while wave 0 factors)
    int r0 = p + NB + bx * 128 + tid;
    bool have = (r0 < NN);
    float l[NB];
    if (have) {
        const float* rowp = C + (size_t)r0 * LD + p;
        #pragma unroll
        for (int q = 0; q < NB/4; ++q) {
            float4 v = *(const float4*)(rowp + 4*q);
            l[4*q] = v.x; l[4*q+1] = v.y; l[4*q+2] = v.z; l[4*q+3] = v.w;
        }
    }

    // ---- in-block diag factor (wave 0), verbatim old diag_kernel arithmetic
    if (tid < 64) {
        int r = tid;
        float row[NB];
        const float* src = C + (size_t)(p + r) * LD + p;
        #pragma unroll
        for (int q = 0; q < NB/4; ++q) {
            float4 v = *(const float4*)(src + 4*q);
            row[4*q+0] = v.x; row[4*q+1] = v.y; row[4*q+2] = v.z; row[4*q+3] = v.w;
        }
        float b = bvec[(size_t)m * NN + p + r];
        float quad_add = 0.f, my_d = 1.f, my_rs = 0.f, my_sol = 0.f;
        #pragma unroll
        for (int j = 0; j < NB; ++j) {
            float dj = fmaxf(bcastf(row[j], j), 1e-30f);
            float rs = rsqrtf(dj);
            if (r == j) my_d = dj;
            row[j] *= rs;                       // row[j] = L[r][j] for r>=j
            float sj = bcastf(b, j) * rs;
            quad_add = fmaf(sj, sj, quad_add);
            b = fmaf(-row[j], sj, b);
            if (r == j) { my_rs = rs; my_sol = sj; }
            #pragma unroll
            for (int c = j + 1; c < NB; ++c) {
                float s = bcastf(row[j], c);    // = L[c][j]
                row[c] = fmaf(-row[j], s, row[c]);
            }
        }
        #pragma unroll
        for (int q = 0; q < NB/4; ++q) {
            float4 v; v.x = row[4*q]; v.y = row[4*q+1]; v.z = row[4*q+2]; v.w = row[4*q+3];
            *(float4*)&Tl[r][4*q] = v;
        }
        rs_s[r]  = my_rs;
        sol_s[r] = my_sol;
        if (bx == 0) {
            float ldv = logf(my_d);
            #pragma unroll
            for (int off = 32; off > 0; off >>= 1) ldv += __shfl_down(ldv, off);
            if (r == 0) {
                stats[2*m]   += quad_add;
                stats[2*m+1] += ldv;
            }
        }
    }
    __syncthreads();

    if (!have) return;
    float* rowp = C + (size_t)r0 * LD + p;
    #pragma unroll
    for (int j = 0; j < NB; ++j) {
        float s0 = l[j], s1 = 0.f, s2 = 0.f, s3 = 0.f;
        int c = 0;
        #pragma unroll
        for (; c + 4 <= j; c += 4) {
            float4 t = *(const float4*)&Tl[j][c];
            s0 = fmaf(-l[c],   t.x, s0);
            s1 = fmaf(-l[c+1], t.y, s1);
            s2 = fmaf(-l[c+2], t.z, s2);
            s3 = fmaf(-l[c+3], t.w, s3);
        }
        #pragma unroll
        for (; c < j; ++c) s0 = fmaf(-l[c], Tl[j][c], s0);
        l[j] = ((s0 + s1) + (s2 + s3)) * rs_s[j];
    }
    #pragma unroll
    for (int q = 0; q < NB/4; ++q) {
        float4 v; v.x = l[4*q]; v.y = l[4*q+1]; v.z = l[4*q+2]; v.w = l[4*q+3];
        *(float4*)(rowp + 4*q) = v;
    }
    float b0 = 0.f, b1 = 0.f, b2 = 0.f, b3 = 0.f;
    #pragma unroll
    for (int j = 0; j < NB; j += 4) {
        b0 = fmaf(l[j],   sol_s[j],   b0);
        b1 = fmaf(l[j+1], sol_s[j+1], b1);
        b2 = fmaf(l[j+2], sol_s[j+2], b2);
        b3 = fmaf(l[j+3], sol_s[j+3], b3);
    }
    bvec[(size_t)m * NN + r0] -= ((b0 + b1) + (b2 + b3));
}

// ---------------- tail SYRK, split-K partials ----------------
__global__ __launch_bounds__(256)
void tailsyrk_kernel(float* __restrict__ covb)
{
    int ml = blockIdx.y;
    float* C = covb + (size_t)ml * NN * LD;
    int z  = blockIdx.x;
    int k0 = z * (CROSS / 4);            // 224 per segment

    __shared__ __align__(16) float As[32][132];
    int tid = threadIdx.x;
    int tx = tid & 15, ty = tid >> 4;
    int c0 = tx * 8, r0 = ty * 8;

    float4 acc[8][2];
    #pragma unroll
    for (int r = 0; r < 8; ++r) { acc[r][0] = make_float4(0,0,0,0); acc[r][1] = make_float4(0,0,0,0); }

    for (int ks = k0; ks < k0 + CROSS/4; ks += 32) {
        for (int idx = tid; idx < 128 * 8; idx += 256) {
            int ii = idx >> 3;
            int c4 = (idx & 7) << 2;
            float4 v = *(const float4*)(C + (size_t)(CROSS + ii) * LD + ks + c4);
            As[c4+0][ii] = v.x; As[c4+1][ii] = v.y;
            As[c4+2][ii] = v.z; As[c4+3][ii] = v.w;
        }
        __syncthreads();
        #pragma unroll
        for (int k = 0; k < 32; ++k) {
            float4 b0 = *(const float4*)&As[k][c0];
            float4 b1 = *(const float4*)&As[k][c0 + 4];
            float4 a0 = *(const float4*)&As[k][r0];
            float4 a1 = *(const float4*)&As[k][r0 + 4];
            float ar[8] = {a0.x, a0.y, a0.z, a0.w, a1.x, a1.y, a1.z, a1.w};
            #pragma unroll
            for (int r = 0; r < 8; ++r) {
                fma4(acc[r][0], ar[r], b0);
                fma4(acc[r][1], ar[r], b1);
            }
        }
        __syncthreads();
    }

    #pragma unroll
    for (int r = 0; r < 8; ++r) {
        float* cp = C + (size_t)(r0 + r) * LD + 512 + z * 128 + c0;
        *(float4*)cp = acc[r][0];
        *((float4*)cp + 1) = acc[r][1];
    }
}

// ---------------- fused tailreduce + per-sample finish ----------------
__global__ __launch_bounds__(512)
void finish_kernel(const float* __restrict__ covb, const float* __restrict__ bvec,
                   const float* __restrict__ stats, float* __restrict__ out,
                   const float* __restrict__ scal, int mbase)
{
    int ml = blockIdx.x;
    int m  = mbase + ml;
    const float* C = covb + (size_t)ml * NN * LD;
    __shared__ __align__(16) float A11[NB][68];   // tail block 11; after TRSM: k-major L21 (Ps)
    __shared__ __align__(16) float A21[NB][68];   // tail rows 64..127, cols 0..63
    __shared__ __align__(16) float A22[NB][68];
    __shared__ float rs_s[NB], sol_s[NB];
    __shared__ float bt[TB];
    __shared__ float s_quad, s_ld;
    int tid = threadIdx.x;

    if (tid < TB) bt[tid] = bvec[(size_t)m * NN + CROSS + tid];
    if (tid == 0) { s_quad = 0.f; s_ld = 0.f; }

    // ---- fused tail reduce: A = C_tail - sum_z partials ----
    float4 tv[6], p0[6], p1[6], p2[6], p3[6];
    const float* pbase[6];
    #pragma unroll
    for (int u = 0; u < 6; ++u) {
        int f   = tid + u * 512;
        int i   = (f & 1023) >> 4;
        int c4  = (f & 15) << 2;
        int blk = f >> 10;
        int ti  = (blk == 0) ? i : (64 + i);         // tail-local row
        int tc  = (blk == 2) ? (64 + c4) : c4;       // tail-local col
        pbase[u] = C + (size_t)ti * LD + 512 + tc;
        tv[u] = *(const float4*)(C + (size_t)(CROSS + ti) * LD + CROSS + tc);
    }
    #pragma unroll
    for (int u = 0; u < 6; ++u) p0[u] = *(const float4*)(pbase[u]);
    #pragma unroll
    for (int u = 0; u < 6; ++u) p1[u] = *(const float4*)(pbase[u] + 128);
    #pragma unroll
    for (int u = 0; u < 6; ++u) p2[u] = *(const float4*)(pbase[u] + 256);
    #pragma unroll
    for (int u = 0; u < 6; ++u) p3[u] = *(const float4*)(pbase[u] + 384);
    #pragma unroll
    for (int u = 0; u < 6; ++u) {
        int f   = tid + u * 512;
        int i   = (f & 1023) >> 4;
        int c4  = (f & 15) << 2;
        int blk = f >> 10;
        float4 s;
        s.x = ((p0[u].x + p1[u].x) + p2[u].x) + p3[u].x;
        s.y = ((p0[u].y + p1[u].y) + p2[u].y) + p3[u].y;
        s.z = ((p0[u].z + p1[u].z) + p2[u].z) + p3[u].z;
        s.w = ((p0[u].w + p1[u].w) + p2[u].w) + p3[u].w;
        float4 t = tv[u];
        t.x -= s.x; t.y -= s.y; t.z -= s.z; t.w -= s.w;
        float* dst = (blk == 0) ? &A11[i][c4] : ((blk == 1) ? &A21[i][c4] : &A22[i][c4]);
        *(float4*)dst = t;
    }
    __syncthreads();

    // ---- factor A11 (64x64), scaled rows back into A11 ----
    if (tid < 64) {
        int r = tid;
        float row[NB];
        #pragma unroll
        for (int q = 0; q < NB/4; ++q) {
            float4 v = *(const float4*)&A11[r][4*q];
            row[4*q+0] = v.x; row[4*q+1] = v.y; row[4*q+2] = v.z; row[4*q+3] = v.w;
        }
        float b = bt[r];
        float quad_add = 0.f, my_d = 1.f;
        #pragma unroll
        for (int j = 0; j < NB; ++j) {
            float dj = fmaxf(bcastf(row[j], j), 1e-30f);
            float rs = rsqrtf(dj);
            if (r == j) my_d = dj;
            row[j] *= rs;
            float sj = bcastf(b, j) * rs;
            quad_add = fmaf(sj, sj, quad_add);
            b = fmaf(-row[j], sj, b);
            if (r == j) { rs_s[j] = rs; sol_s[j] = sj; }
            #pragma unroll
            for (int c = j + 1; c < NB; ++c) {
                float s = bcastf(row[j], c);
                row[c] = fmaf(-row[j], s, row[c]);
            }
        }
        #pragma unroll
        for (int q = 0; q < NB/4; ++q) {
            float4 v; v.x = row[4*q]; v.y = row[4*q+1]; v.z = row[4*q+2]; v.w = row[4*q+3];
            *(float4*)&A11[r][4*q] = v;
        }
        float ldv = logf(my_d);
        #pragma unroll
        for (int off = 32; off > 0; off >>= 1) ldv += __shfl_down(ldv, off);
        if (r == 0) { s_quad += quad_add; s_ld += ldv; }
    }
    __syncthreads();

    // ---- TRSM: rows of A21 (wave 1); result transposed into A11 (k-major Ps) ----
    if (tid >= 64 && tid < 128) {
        int rr = tid - 64;
        float l[NB];
        #pragma unroll
        for (int q = 0; q < NB/4; ++q) {
            float4 v = *(const float4*)&A21[rr][4*q];
            l[4*q] = v.x; l[4*q+1] = v.y; l[4*q+2] = v.z; l[4*q+3] = v.w;
        }
        #pragma unroll
        for (int j = 0; j < NB; ++j) {
            float s0 = l[j], s1 = 0.f, s2 = 0.f, s3 = 0.f;
            int c = 0;
            #pragma unroll
            for (; c + 4 <= j; c += 4) {
                float4 t = *(const float4*)&A11[j][c];
                s0 = fmaf(-l[c],   t.x, s0);
                s1 = fmaf(-l[c+1], t.y, s1);
                s2 = fmaf(-l[c+2], t.z, s2);
                s3 = fmaf(-l[c+3], t.w, s3);
            }
            #pragma unroll
            for (; c < j; ++c) s0 = fmaf(-l[c], A11[j][c], s0);
            l[j] = ((s0 + s1) + (s2 + s3)) * rs_s[j];
        }
        // A11 is dead now; single-wave program order makes this race-free.
        #pragma unroll
        for (int k = 0; k < NB; ++k) A11[k][rr] = l[k];   // Ps[k][rr]
        float bacc = 0.f;
        #pragma unroll
        for (int j = 0; j < NB; ++j) bacc = fmaf(l[j], sol_s[j], bacc);
        bt[64 + rr] -= bacc;
    }
    __syncthreads();

    // ---- SYRK: A22 -= L21 * L21^T, k-major Ps (= A11), conflict-free ----
    for (int idx = tid; idx < 64 * 16; idx += 512) {
        int i  = idx >> 4;
        int j4 = (idx & 15) << 2;
        if (j4 > i) continue;
        float4 a = make_float4(0,0,0,0);
        #pragma unroll 8
        for (int k = 0; k < NB; ++k) {
            float4 pj = *(const float4*)&A11[k][j4];
            fma4(a, A11[k][i], pj);
        }
        float* cp = &A22[i][j4];
        float4 uu = *(float4*)cp;
        uu.x -= a.x; uu.y -= a.y; uu.z -= a.z; uu.w -= a.w;
        *(float4*)cp = uu;
    }
    __syncthreads();

    // ---- factor A22 (64x64); only logdet + quad needed ----
    if (tid < 64) {
        int r = tid;
        float row[NB];
        #pragma unroll
        for (int q = 0; q < NB/4; ++q) {
            float4 v = *(const float4*)&A22[r][4*q];
            row[4*q+0] = v.x; row[4*q+1] = v.y; row[4*q+2] = v.z; row[4*q+3] = v.w;
        }
        float b = bt[64 + r];
        float quad_add = 0.f, my_d = 1.f;
        #pragma unroll
        for (int j = 0; j < NB; ++j) {
            float dj = fmaxf(bcastf(row[j], j), 1e-30f);
            float rs = rsqrtf(dj);
            if (r == j) my_d = dj;
            row[j] *= rs;
            float sj = bcastf(b, j) * rs;
            quad_add = fmaf(sj, sj, quad_add);
            b = fmaf(-row[j], sj, b);
            #pragma unroll
            for (int c = j + 1; c < NB; ++c) {
                float s = bcastf(row[j], c);
                row[c] = fmaf(-row[j], s, row[c]);
            }
        }
        float ldv = logf(my_d);
        #pragma unroll
        for (int off = 32; off > 0; off >>= 1) ldv += __shfl_down(ldv, off);
        if (r == 0) { s_quad += quad_add; s_ld += ldv; }
    }
    __syncthreads();

    if (tid == 0) {
        float qt = stats[2*m]   + s_quad;
        float lt = stats[2*m+1] + s_ld;
        out[m] = -0.5f * (qt + lt + (float)NN * LOG2PI) + scal[5*NSAMP + m];
    }
}

extern "C" void kernel_launch(void* const* d_in, const int* in_sizes, int n_in,
                              void* d_out, int out_size, void* d_ws, size_t ws_size,
                              hipStream_t stream)
{
    const float* x   = (const float*)d_in[0];
    const float* y   = (const float*)d_in[1];
    const float* z   = (const float*)d_in[2];
    const float* qbm = (const float*)d_in[3];
    const float* qbs = (const float*)d_in[4];
    const float* qsm = (const float*)d_in[5];
    const float* qss = (const float*)d_in[6];
    const float* qem = (const float*)d_in[7];
    const float* qes = (const float*)d_in[8];
    const float* qzm = (const float*)d_in[9];
    const float* qzs = (const float*)d_in[10];
    const float* qnm = (const float*)d_in[11];
    const float* qns = (const float*)d_in[12];
    float* out  = (float*)d_out;
    float* ws   = (float*)d_ws;

    // workspace layout (floats)
    float* scal   = ws;                                   // 384 used
    float* bvec   = ws + 1024;                            // 64*1024
    float* stats  = ws + 1024 + NSAMP*NN;                 // 128 used, 512 res
    float* cov    = ws + 1024 + NSAMP*NN + 512;
    size_t headF  = 1024 + (size_t)NSAMP*NN + 512;

    scal_kernel<<<1, 64, 0, stream>>>(z, qbm, qbs, qsm, qss, qem, qes, qzm, qzs, qnm, qns, scal);

    size_t availF = ws_size / 4;
    size_t perM   = (size_t)NN * LD;       // padded per-matrix footprint
    int mc_max = NSAMP;
    if (availF < headF + (size_t)NSAMP * perM) {
        size_t rem = (availF > headF) ? (availF - headF) : 0;
        mc_max = (int)(rem / perM);
        if (mc_max < 1) mc_max = 1;
        if (mc_max > NSAMP) mc_max = NSAMP;
    }
    // r24: cap the batch at 32 samples so the per-batch cov footprint
    // (32 x 4.26 MB = 136 MB) fits the 256 MB Infinity Cache. At mc=64
    // (272 MB) every panel re-read missed L3 (update p=64: FETCH 28 MB of
    // HBM traffic for data written moments earlier) -> all GEMM dispatches
    // were HBM-latency-bound. The cov buffer is ml-indexed, so both batches
    // reuse the same 136 MB region.
    if (mc_max > 32) mc_max = 32;

    for (int mb = 0; mb < NSAMP; mb += mc_max) {
        int mc = NSAMP - mb; if (mc > mc_max) mc = mc_max;
        covslim_kernel<<<dim3(80, mc), 256, 0, stream>>>(cov, scal, x, y, bvec, stats, mb);
        for (int q = 0; q < CROSS / NB; ++q) {   // panels p = 0..832
            int p = q * NB;
            if (q > 0) {
                int rows = NN - p;
                int rt128 = (rows + 127) / 128;
                if (rt128 * mc >= 448) {
                    update_kernel<<<dim3(rt128 * mc), 256, 0, stream>>>(cov, scal, x, mb, p, mc);
                } else {
                    int rt64 = (rows + 63) / 64;
                    update_small_kernel<<<dim3(rt64 * mc * 2), 256, 0, stream>>>(cov, scal, x, mb, p, mc, rt64);
                }
            }
            int rb = NN - p - NB;
            int rtiles = (rb + 127) / 128;
            trsm_kernel<<<dim3(rtiles * mc), 128, 0, stream>>>(cov, bvec, stats, mb, p, mc);
        }
        tailsyrk_kernel<<<dim3(4, mc), 256, 0, stream>>>(cov);
        finish_kernel<<<mc, 512, 0, stream>>>(cov, bvec, stats, out, scal, mb);
    }
}

// Round 14
// 1205.688 us; speedup vs baseline: 2.3589x; 1.5701x over previous
//
#include <hip/hip_runtime.h>
#include <math.h>

#define NN 1024           // N (logical)
#define NB 64             // panel width
#define TB 128            // tail handled by tailsyrk+finish
#define CROSS (NN - TB)   // 896: panel loop covers p < CROSS
#define NSAMP 64          // n_mc
// r25: banded-packed cov. Band b (rows 64b..64b+63) stores cols 0..64(b+1)+15
// (stride bs(b)=64b+80; +16 pad absorbs diag-block upper-tri writes, col <=
// p+63 <= capacity p+79). Per-sample 573440 floats (2.29MB vs 4.26 dense) ->
// 64 samples = 147MB, ONE L3-resident batch (was 2 batches at mc=32).
#define SMPL 573440
#define TSQN (TB*TB)      // dense tail square per sample (finish input)
#define PSQN (TB*512)     // tailsyrk split-K partials per sample

#define CCONST  (-0.91893853320467274f)   // -0.5*log(2*pi)
#define LOG2PI  (1.8378770664093453f)

__device__ __forceinline__ int rowoff(int i) {
    int b = i >> 6;
    return (2048*b + 3072)*b + (i & 63)*(64*b + 80);
}
__device__ __forceinline__ float bcastf(float v, int lane) {
    return __int_as_float(__builtin_amdgcn_readlane(__float_as_int(v), lane));
}
__device__ __forceinline__ float softplus_d(float v) {
    return (v > 20.f ? v : log1pf(expf(v))) + 1e-7f;
}
__device__ __forceinline__ float log_normal_f(float v, float mean, float s, float eps) {
    float d = v - mean;
    return -d * d / (2.f * s * s + eps) - logf(s) + CCONST;
}
__device__ __forceinline__ float log_lognormal_f(float v, float mean, float s) {
    float lv = logf(v);
    float d = lv - mean;
    return -d * d / (2.f * s * s + 1e-6f) - lv - logf(s) + CCONST;
}
__device__ __forceinline__ void fma4(float4& c, float a, const float4& b) {
    c.x = fmaf(a, b.x, c.x); c.y = fmaf(a, b.y, c.y);
    c.z = fmaf(a, b.z, c.z); c.w = fmaf(a, b.w, c.w);
}

// ---------------- per-sample scalars ----------------
__global__ void scal_kernel(const float* __restrict__ z,
    const float* qbm, const float* qbs, const float* qsm, const float* qss,
    const float* qem, const float* qes, const float* qzm, const float* qzs,
    const float* qnm, const float* qns, float* __restrict__ scal)
{
    int m = threadIdx.x;
    if (m >= NSAMP) return;
    float z0 = z[m*5+0], z1 = z[m*5+1], z2 = z[m*5+2], z3 = z[m*5+3], z4 = z[m*5+4];
    float spb = softplus_d(qbs[0]);
    float sps = softplus_d(qss[0]);
    float spe = softplus_d(qes[0]);
    float spz = softplus_d(qzs[0]);
    float spn = softplus_d(qns[0]);
    float sigma2 = expf(z0 * sps + qsm[0]);
    float beta   = z1 * spb + qbm[0];
    float eta    = expf(z2 * spe + qem[0]);
    float lsZ    = expf(z3 * spz + qzm[0]);
    float lsN    = expf(z4 * spn + qnm[0]);
    float s0 = softplus_d(sqrtf(logf(2.f)));
    float lp = log_normal_f(beta, 0.f, 1.f, 1e-5f)
             + log_lognormal_f(sigma2, 1.f, s0)
             + log_lognormal_f(eta,    1.f, s0)
             + log_lognormal_f(lsZ,    1.f, s0)
             + log_lognormal_f(lsN,    1.f, s0);
    float lq = log_normal_f(beta, qbm[0], spb, 1e-5f)
             + log_lognormal_f(sigma2, qsm[0], sps)
             + log_lognormal_f(eta,    qem[0], spe)
             + log_lognormal_f(lsZ,    qzm[0], spz)
             + log_lognormal_f(lsN,    qnm[0], spn);
    scal[m]           = sigma2;
    scal[NSAMP + m]   = eta;
    scal[2*NSAMP + m] = 1.f / lsZ;
    scal[3*NSAMP + m] = 1.f / lsN;
    scal[4*NSAMP + m] = beta;
    scal[5*NSAMP + m] = lp - lq;
}

// ---------------- slim covariance build + bvec/stats init ----------------
// Tail square now goes to the dense tsq side-buffer (banded rows can't hold
// cols > capacity); stripe writes into banded cov. Expressions unchanged.
__global__ __launch_bounds__(256)
void covslim_kernel(float* __restrict__ cov, float* __restrict__ tsq,
                    const float* __restrict__ scal,
                    const float* __restrict__ x, const float* __restrict__ y,
                    float* __restrict__ bvec, float* __restrict__ stats, int mbase)
{
    int ml = blockIdx.y;
    int m  = mbase + ml;
    float sigma2 = scal[m];
    float eta    = scal[NSAMP + m];
    float ilZ    = scal[2*NSAMP + m];
    float ilN    = scal[3*NSAMP + m];
    float* C = cov + (size_t)ml * SMPL;
    int tid = threadIdx.x;

    if (blockIdx.x == 0 && tid == 0) { stats[2*m] = 0.f; stats[2*m+1] = 0.f; }

    if (blockIdx.x < 64) {
        // stripe: 16 rows x 64 cols per block (lower triangle only)
        int i  = blockIdx.x * 16 + (tid >> 4);
        int j0 = (tid & 15) * 4;
        if ((tid & 15) == 0) bvec[(size_t)m * NN + i] = y[i] - scal[4*NSAMP + m];
        if (j0 > i) return;
        float xi0 = x[2*i]   * ilZ;
        float xi1 = x[2*i+1] * ilN;
        float4 xa = *(const float4*)(x + 2*j0);
        float4 xb = *(const float4*)(x + 2*j0 + 4);
        float v[4]; float d0, d1;
        d0 = xa.x*ilZ - xi0; d1 = xa.y*ilN - xi1; v[0] = eta*__expf(-0.5f*(d0*d0+d1*d1));
        d0 = xa.z*ilZ - xi0; d1 = xa.w*ilN - xi1; v[1] = eta*__expf(-0.5f*(d0*d0+d1*d1));
        d0 = xb.x*ilZ - xi0; d1 = xb.y*ilN - xi1; v[2] = eta*__expf(-0.5f*(d0*d0+d1*d1));
        d0 = xb.z*ilZ - xi0; d1 = xb.w*ilN - xi1; v[3] = eta*__expf(-0.5f*(d0*d0+d1*d1));
        #pragma unroll
        for (int q = 0; q < 4; ++q) if (j0 + q == i) v[q] += sigma2;
        float* row = C + rowoff(i);
        if (j0 + 3 <= i) {
            float4 o; o.x = v[0]; o.y = v[1]; o.z = v[2]; o.w = v[3];
            *(float4*)(row + j0) = o;
        } else {
            #pragma unroll
            for (int q = 0; q < 4; ++q) if (j0 + q <= i) row[j0+q] = v[q];
        }
    } else {
        // tail: 8 rows x 128 cols per block -> dense tsq[128][128]
        int bx2 = blockIdx.x - 64;                 // 0..15
        int tr  = bx2 * 8 + (tid >> 5);            // 0..127 tail-local row
        int tc  = (tid & 31) * 4;                  // 0..124 tail-local col
        int i   = CROSS + tr;
        int j0  = CROSS + tc;
        float xi0 = x[2*i]   * ilZ;
        float xi1 = x[2*i+1] * ilN;
        float4 xa = *(const float4*)(x + 2*j0);
        float4 xb = *(const float4*)(x + 2*j0 + 4);
        float v[4]; float d0, d1;
        d0 = xa.x*ilZ - xi0; d1 = xa.y*ilN - xi1; v[0] = eta*__expf(-0.5f*(d0*d0+d1*d1));
        d0 = xa.z*ilZ - xi0; d1 = xa.w*ilN - xi1; v[1] = eta*__expf(-0.5f*(d0*d0+d1*d1));
        d0 = xb.x*ilZ - xi0; d1 = xb.y*ilN - xi1; v[2] = eta*__expf(-0.5f*(d0*d0+d1*d1));
        d0 = xb.z*ilZ - xi0; d1 = xb.w*ilN - xi1; v[3] = eta*__expf(-0.5f*(d0*d0+d1*d1));
        #pragma unroll
        for (int q = 0; q < 4; ++q) if (j0 + q == i) v[q] += sigma2;
        float4 o; o.x = v[0]; o.y = v[1]; o.z = v[2]; o.w = v[3];
        *(float4*)(tsq + (size_t)ml * TSQN + tr * TB + tc) = o;
    }
}

// ---------------- left-looking block-column update (GEMM, K = p) ----------------
// r22 body + banded addressing. 1D grid, ml = bid % mc (XCD-local B reuse).
__global__ __launch_bounds__(256)
void update_kernel(float* __restrict__ covb, const float* __restrict__ scal,
                   const float* __restrict__ x, int mbase, int p, int mc)
{
    int bid = blockIdx.x;
    int ml  = bid % mc;
    int bx  = bid / mc;
    int m  = mbase + ml;
    float* C = covb + (size_t)ml * SMPL;
    int rowbase = p + bx * 128;
    int bofp = rowoff(p);
    int bsp  = 64*(p>>6) + 80;

    __shared__ __align__(16) float As[32][132];  // k-major, 128 rows
    __shared__ __align__(16) float Bs[32][68];   // k-major, 64 rows

    int tid = threadIdx.x;
    int tx = tid & 7,  ty = tid >> 3;
    int c0 = tx * 8,   r0 = ty * 4;

    float4 acc[4][2];
    #pragma unroll
    for (int r = 0; r < 4; ++r) { acc[r][0] = make_float4(0,0,0,0); acc[r][1] = make_float4(0,0,0,0); }

    for (int ks = 0; ks < p; ks += 32) {
        for (int idx = tid; idx < 128 * 8; idx += 256) {
            int ii = idx >> 3;
            int c4 = (idx & 7) << 2;
            int gr = rowbase + ii;
            float4 v = make_float4(0,0,0,0);
            if (gr < NN) v = *(const float4*)(C + rowoff(gr) + ks + c4);
            As[c4+0][ii] = v.x; As[c4+1][ii] = v.y;
            As[c4+2][ii] = v.z; As[c4+3][ii] = v.w;
        }
        for (int idx = tid; idx < 64 * 8; idx += 256) {
            int ii = idx >> 3;
            int c4 = (idx & 7) << 2;
            float4 v = *(const float4*)(C + bofp + ii * bsp + ks + c4);
            Bs[c4+0][ii] = v.x; Bs[c4+1][ii] = v.y;
            Bs[c4+2][ii] = v.z; Bs[c4+3][ii] = v.w;
        }
        __syncthreads();
        #pragma unroll
        for (int k = 0; k < 32; ++k) {
            float4 b0 = *(const float4*)&Bs[k][c0];
            float4 b1 = *(const float4*)&Bs[k][c0 + 4];
            float4 a0 = *(const float4*)&As[k][r0];
            float ar[4] = {a0.x, a0.y, a0.z, a0.w};
            #pragma unroll
            for (int r = 0; r < 4; ++r) {
                fma4(acc[r][0], ar[r], b0);
                fma4(acc[r][1], ar[r], b1);
            }
        }
        __syncthreads();
    }

    int jcol = p + c0;
    float sigma2 = scal[m];
    float eta    = scal[NSAMP + m];
    float ilZ    = scal[2*NSAMP + m];
    float ilN    = scal[3*NSAMP + m];
    float4 xa0 = *(const float4*)(x + 2*jcol);
    float4 xb0 = *(const float4*)(x + 2*jcol + 4);
    float4 xa1 = *(const float4*)(x + 2*jcol + 8);
    float4 xb1 = *(const float4*)(x + 2*jcol + 12);
    #pragma unroll
    for (int r = 0; r < 4; ++r) {
        int g = rowbase + r0 + r;
        if (g < NN) {
            float xi0 = x[2*g]   * ilZ;
            float xi1 = x[2*g+1] * ilN;
            float v[8]; float d0, d1;
            d0 = xa0.x*ilZ - xi0; d1 = xa0.y*ilN - xi1; v[0] = eta*__expf(-0.5f*(d0*d0+d1*d1));
            d0 = xa0.z*ilZ - xi0; d1 = xa0.w*ilN - xi1; v[1] = eta*__expf(-0.5f*(d0*d0+d1*d1));
            d0 = xb0.x*ilZ - xi0; d1 = xb0.y*ilN - xi1; v[2] = eta*__expf(-0.5f*(d0*d0+d1*d1));
            d0 = xb0.z*ilZ - xi0; d1 = xb0.w*ilN - xi1; v[3] = eta*__expf(-0.5f*(d0*d0+d1*d1));
            d0 = xa1.x*ilZ - xi0; d1 = xa1.y*ilN - xi1; v[4] = eta*__expf(-0.5f*(d0*d0+d1*d1));
            d0 = xa1.z*ilZ - xi0; d1 = xa1.w*ilN - xi1; v[5] = eta*__expf(-0.5f*(d0*d0+d1*d1));
            d0 = xb1.x*ilZ - xi0; d1 = xb1.y*ilN - xi1; v[6] = eta*__expf(-0.5f*(d0*d0+d1*d1));
            d0 = xb1.z*ilZ - xi0; d1 = xb1.w*ilN - xi1; v[7] = eta*__expf(-0.5f*(d0*d0+d1*d1));
            #pragma unroll
            for (int qq = 0; qq < 8; ++qq) if (jcol + qq == g) v[qq] += sigma2;
            float* cp = C + rowoff(g) + jcol;
            float4 u0, u1;
            u0.x = v[0] - acc[r][0].x; u0.y = v[1] - acc[r][0].y;
            u0.z = v[2] - acc[r][0].z; u0.w = v[3] - acc[r][0].w;
            u1.x = v[4] - acc[r][1].x; u1.y = v[5] - acc[r][1].y;
            u1.z = v[6] - acc[r][1].z; u1.w = v[7] - acc[r][1].w;
            *(float4*)cp = u0;
            *((float4*)cp + 1) = u1;
        }
    }
}

// ---------------- small-tile update for late panels ----------------
__global__ __launch_bounds__(256)
void update_small_kernel(float* __restrict__ covb, const float* __restrict__ scal,
                         const float* __restrict__ x, int mbase, int p, int mc, int nbx)
{
    int bid  = blockIdx.x;
    int ml   = bid % mc;
    int rest = bid / mc;
    int bx   = rest % nbx;
    int zz   = rest / nbx;
    int m  = mbase + ml;
    float* C = covb + (size_t)ml * SMPL;
    int rowbase = p + bx * 64;
    int zoff = zz * 32;
    int bofp = rowoff(p);
    int bsp  = 64*(p>>6) + 80;

    __shared__ __align__(16) float As[32][68];   // k-major, 64 rows
    __shared__ __align__(16) float Bs[32][36];   // k-major, 32 rows

    int tid = threadIdx.x;
    int tx = tid & 7,  ty = tid >> 3;   // 8 col-quads x 32 row-pairs
    int c0 = tx * 4,   r0 = ty * 2;

    float4 acc0 = make_float4(0,0,0,0), acc1 = make_float4(0,0,0,0);

    for (int ks = 0; ks < p; ks += 32) {
        for (int idx = tid; idx < 64 * 8; idx += 256) {
            int ii = idx >> 3;
            int c4 = (idx & 7) << 2;
            int gr = rowbase + ii;
            float4 v = make_float4(0,0,0,0);
            if (gr < NN) v = *(const float4*)(C + rowoff(gr) + ks + c4);
            As[c4+0][ii] = v.x; As[c4+1][ii] = v.y;
            As[c4+2][ii] = v.z; As[c4+3][ii] = v.w;
        }
        {
            int idx = tid;                      // 32*8 = 256 exactly
            int ii = idx >> 3;
            int c4 = (idx & 7) << 2;
            float4 v = *(const float4*)(C + bofp + (zoff + ii) * bsp + ks + c4);
            Bs[c4+0][ii] = v.x; Bs[c4+1][ii] = v.y;
            Bs[c4+2][ii] = v.z; Bs[c4+3][ii] = v.w;
        }
        __syncthreads();
        #pragma unroll
        for (int k = 0; k < 32; ++k) {
            float4 bv = *(const float4*)&Bs[k][c0];
            float2 av = *(const float2*)&As[k][r0];
            fma4(acc0, av.x, bv);
            fma4(acc1, av.y, bv);
        }
        __syncthreads();
    }

    int jcol = p + zoff + c0;
    float sigma2 = scal[m];
    float eta    = scal[NSAMP + m];
    float ilZ    = scal[2*NSAMP + m];
    float ilN    = scal[3*NSAMP + m];
    float4 xa = *(const float4*)(x + 2*jcol);
    float4 xb = *(const float4*)(x + 2*jcol + 4);
    int g0 = rowbase + r0;
    #pragma unroll
    for (int rr = 0; rr < 2; ++rr) {
        int g = g0 + rr;
        if (g < NN) {
            float xi0 = x[2*g]   * ilZ;
            float xi1 = x[2*g+1] * ilN;
            float v[4]; float d0, d1;
            d0 = xa.x*ilZ - xi0; d1 = xa.y*ilN - xi1; v[0] = eta*__expf(-0.5f*(d0*d0+d1*d1));
            d0 = xa.z*ilZ - xi0; d1 = xa.w*ilN - xi1; v[1] = eta*__expf(-0.5f*(d0*d0+d1*d1));
            d0 = xb.x*ilZ - xi0; d1 = xb.y*ilN - xi1; v[2] = eta*__expf(-0.5f*(d0*d0+d1*d1));
            d0 = xb.z*ilZ - xi0; d1 = xb.w*ilN - xi1; v[3] = eta*__expf(-0.5f*(d0*d0+d1*d1));
            #pragma unroll
            for (int qq = 0; qq < 4; ++qq) if (jcol + qq == g) v[qq] += sigma2;
            const float4 ac = (rr == 0) ? acc0 : acc1;
            float* cp = C + rowoff(g) + jcol;
            float4 u;
            u.x = v[0] - ac.x; u.y = v[1] - ac.y; u.z = v[2] - ac.z; u.w = v[3] - ac.w;
            *(float4*)cp = u;
        }
    }
}

// ---------------- fused diag-factor + panel TRSM ----------------
__global__ __launch_bounds__(128)
void trsm_kernel(float* __restrict__ covb, float* __restrict__ bvec,
                 float* __restrict__ stats, int mbase, int p, int mc)
{
    int bid = blockIdx.x;
    int ml  = bid % mc;
    int bx  = bid / mc;
    int m  = mbase + ml;
    float* C = covb + (size_t)ml * SMPL;
    __shared__ __align__(16) float Tl[NB][68];
    __shared__ float rs_s[NB], sol_s[NB];
    int tid = threadIdx.x;
    int bofp = rowoff(p);
    int bsp  = 64*(p>>6) + 80;

    // preload solve rows (global loads in flight while wave 0 factors)
    int r0 = p + NB + bx * 128 + tid;
    bool have = (r0 < NN);
    float l[NB];
    int roff = have ? rowoff(r0) : 0;
    if (have) {
        const float* rowp = C + roff + p;
        #pragma unroll
        for (int q = 0; q < NB/4; ++q) {
            float4 v = *(const float4*)(rowp + 4*q);
            l[4*q] = v.x; l[4*q+1] = v.y; l[4*q+2] = v.z; l[4*q+3] = v.w;
        }
    }

    // ---- in-block diag factor (wave 0), verbatim diag arithmetic
    if (tid < 64) {
        int r = tid;
        float row[NB];
        const float* src = C + bofp + r * bsp + p;
        #pragma unroll
        for (int q = 0; q < NB/4; ++q) {
            float4 v = *(const float4*)(src + 4*q);
            row[4*q+0] = v.x; row[4*q+1] = v.y; row[4*q+2] = v.z; row[4*q+3] = v.w;
        }
        float b = bvec[(size_t)m * NN + p + r];
        float quad_add = 0.f, my_d = 1.f, my_rs = 0.f, my_sol = 0.f;
        #pragma unroll
        for (int j = 0; j < NB; ++j) {
            float dj = fmaxf(bcastf(row[j], j), 1e-30f);
            float rs = rsqrtf(dj);
            if (r == j) my_d = dj;
            row[j] *= rs;                       // row[j] = L[r][j] for r>=j
            float sj = bcastf(b, j) * rs;
            quad_add = fmaf(sj, sj, quad_add);
            b = fmaf(-row[j], sj, b);
            if (r == j) { my_rs = rs; my_sol = sj; }
            #pragma unroll
            for (int c = j + 1; c < NB; ++c) {
                float s = bcastf(row[j], c);    // = L[c][j]
                row[c] = fmaf(-row[j], s, row[c]);
            }
        }
        #pragma unroll
        for (int q = 0; q < NB/4; ++q) {
            float4 v; v.x = row[4*q]; v.y = row[4*q+1]; v.z = row[4*q+2]; v.w = row[4*q+3];
            *(float4*)&Tl[r][4*q] = v;
        }
        rs_s[r]  = my_rs;
        sol_s[r] = my_sol;
        if (bx == 0) {
            float ldv = logf(my_d);
            #pragma unroll
            for (int off = 32; off > 0; off >>= 1) ldv += __shfl_down(ldv, off);
            if (r == 0) {
                stats[2*m]   += quad_add;
                stats[2*m+1] += ldv;
            }
        }
    }
    __syncthreads();

    if (!have) return;
    float* rowp = C + roff + p;
    #pragma unroll
    for (int j = 0; j < NB; ++j) {
        float s0 = l[j], s1 = 0.f, s2 = 0.f, s3 = 0.f;
        int c = 0;
        #pragma unroll
        for (; c + 4 <= j; c += 4) {
            float4 t = *(const float4*)&Tl[j][c];
            s0 = fmaf(-l[c],   t.x, s0);
            s1 = fmaf(-l[c+1], t.y, s1);
            s2 = fmaf(-l[c+2], t.z, s2);
            s3 = fmaf(-l[c+3], t.w, s3);
        }
        #pragma unroll
        for (; c < j; ++c) s0 = fmaf(-l[c], Tl[j][c], s0);
        l[j] = ((s0 + s1) + (s2 + s3)) * rs_s[j];
    }
    #pragma unroll
    for (int q = 0; q < NB/4; ++q) {
        float4 v; v.x = l[4*q]; v.y = l[4*q+1]; v.z = l[4*q+2]; v.w = l[4*q+3];
        *(float4*)(rowp + 4*q) = v;
    }
    float b0 = 0.f, b1 = 0.f, b2 = 0.f, b3 = 0.f;
    #pragma unroll
    for (int j = 0; j < NB; j += 4) {
        b0 = fmaf(l[j],   sol_s[j],   b0);
        b1 = fmaf(l[j+1], sol_s[j+1], b1);
        b2 = fmaf(l[j+2], sol_s[j+2], b2);
        b3 = fmaf(l[j+3], sol_s[j+3], b3);
    }
    bvec[(size_t)m * NN + r0] -= ((b0 + b1) + (b2 + b3));
}

// ---------------- tail SYRK, split-K partials -> psq ----------------
__global__ __launch_bounds__(256)
void tailsyrk_kernel(const float* __restrict__ covb, float* __restrict__ psq)
{
    int ml = blockIdx.y;
    const float* C = covb + (size_t)ml * SMPL;
    float* P = psq + (size_t)ml * PSQN;
    int z  = blockIdx.x;
    int k0 = z * (CROSS / 4);            // 224 per segment

    __shared__ __align__(16) float As[32][132];
    int tid = threadIdx.x;
    int tx = tid & 15, ty = tid >> 4;
    int c0 = tx * 8, r0 = ty * 8;

    float4 acc[8][2];
    #pragma unroll
    for (int r = 0; r < 8; ++r) { acc[r][0] = make_float4(0,0,0,0); acc[r][1] = make_float4(0,0,0,0); }

    for (int ks = k0; ks < k0 + CROSS/4; ks += 32) {
        for (int idx = tid; idx < 128 * 8; idx += 256) {
            int ii = idx >> 3;
            int c4 = (idx & 7) << 2;
            float4 v = *(const float4*)(C + rowoff(CROSS + ii) + ks + c4);
            As[c4+0][ii] = v.x; As[c4+1][ii] = v.y;
            As[c4+2][ii] = v.z; As[c4+3][ii] = v.w;
        }
        __syncthreads();
        #pragma unroll
        for (int k = 0; k < 32; ++k) {
            float4 b0 = *(const float4*)&As[k][c0];
            float4 b1 = *(const float4*)&As[k][c0 + 4];
            float4 a0 = *(const float4*)&As[k][r0];
            float4 a1 = *(const float4*)&As[k][r0 + 4];
            float ar[8] = {a0.x, a0.y, a0.z, a0.w, a1.x, a1.y, a1.z, a1.w};
            #pragma unroll
            for (int r = 0; r < 8; ++r) {
                fma4(acc[r][0], ar[r], b0);
                fma4(acc[r][1], ar[r], b1);
            }
        }
        __syncthreads();
    }

    #pragma unroll
    for (int r = 0; r < 8; ++r) {
        float* cp = P + (r0 + r) * 512 + z * 128 + c0;
        *(float4*)cp = acc[r][0];
        *((float4*)cp + 1) = acc[r][1];
    }
}

// ---------------- fused tailreduce + per-sample finish ----------------
__global__ __launch_bounds__(512)
void finish_kernel(const float* __restrict__ tsq, const float* __restrict__ psq,
                   const float* __restrict__ bvec,
                   const float* __restrict__ stats, float* __restrict__ out,
                   const float* __restrict__ scal, int mbase)
{
    int ml = blockIdx.x;
    int m  = mbase + ml;
    const float* T = tsq + (size_t)ml * TSQN;
    const float* P = psq + (size_t)ml * PSQN;
    __shared__ __align__(16) float A11[NB][68];   // tail 11; after TRSM: k-major L21 (Ps)
    __shared__ __align__(16) float A21[NB][68];   // tail rows 64..127, cols 0..63
    __shared__ __align__(16) float A22[NB][68];
    __shared__ float rs_s[NB], sol_s[NB];
    __shared__ float bt[TB];
    __shared__ float s_quad, s_ld;
    int tid = threadIdx.x;

    if (tid < TB) bt[tid] = bvec[(size_t)m * NN + CROSS + tid];
    if (tid == 0) { s_quad = 0.f; s_ld = 0.f; }

    // ---- fused tail reduce: A = tsq - sum_z psq partials ----
    float4 tv[6], p0[6], p1[6], p2[6], p3[6];
    const float* pbase[6];
    #pragma unroll
    for (int u = 0; u < 6; ++u) {
        int f   = tid + u * 512;
        int i   = (f & 1023) >> 4;
        int c4  = (f & 15) << 2;
        int blk = f >> 10;
        int ti  = (blk == 0) ? i : (64 + i);         // tail-local row
        int tc  = (blk == 2) ? (64 + c4) : c4;       // tail-local col
        pbase[u] = P + ti * 512 + tc;
        tv[u] = *(const float4*)(T + ti * TB + tc);
    }
    #pragma unroll
    for (int u = 0; u < 6; ++u) p0[u] = *(const float4*)(pbase[u]);
    #pragma unroll
    for (int u = 0; u < 6; ++u) p1[u] = *(const float4*)(pbase[u] + 128);
    #pragma unroll
    for (int u = 0; u < 6; ++u) p2[u] = *(const float4*)(pbase[u] + 256);
    #pragma unroll
    for (int u = 0; u < 6; ++u) p3[u] = *(const float4*)(pbase[u] + 384);
    #pragma unroll
    for (int u = 0; u < 6; ++u) {
        int f   = tid + u * 512;
        int i   = (f & 1023) >> 4;
        int c4  = (f & 15) << 2;
        int blk = f >> 10;
        float4 s;
        s.x = ((p0[u].x + p1[u].x) + p2[u].x) + p3[u].x;
        s.y = ((p0[u].y + p1[u].y) + p2[u].y) + p3[u].y;
        s.z = ((p0[u].z + p1[u].z) + p2[u].z) + p3[u].z;
        s.w = ((p0[u].w + p1[u].w) + p2[u].w) + p3[u].w;
        float4 t = tv[u];
        t.x -= s.x; t.y -= s.y; t.z -= s.z; t.w -= s.w;
        float* dst = (blk == 0) ? &A11[i][c4] : ((blk == 1) ? &A21[i][c4] : &A22[i][c4]);
        *(float4*)dst = t;
    }
    __syncthreads();

    // ---- factor A11 (64x64), scaled rows back into A11 ----
    if (tid < 64) {
        int r = tid;
        float row[NB];
        #pragma unroll
        for (int q = 0; q < NB/4; ++q) {
            float4 v = *(const float4*)&A11[r][4*q];
            row[4*q+0] = v.x; row[4*q+1] = v.y; row[4*q+2] = v.z; row[4*q+3] = v.w;
        }
        float b = bt[r];
        float quad_add = 0.f, my_d = 1.f;
        #pragma unroll
        for (int j = 0; j < NB; ++j) {
            float dj = fmaxf(bcastf(row[j], j), 1e-30f);
            float rs = rsqrtf(dj);
            if (r == j) my_d = dj;
            row[j] *= rs;
            float sj = bcastf(b, j) * rs;
            quad_add = fmaf(sj, sj, quad_add);
            b = fmaf(-row[j], sj, b);
            if (r == j) { rs_s[j] = rs; sol_s[j] = sj; }
            #pragma unroll
            for (int c = j + 1; c < NB; ++c) {
                float s = bcastf(row[j], c);
                row[c] = fmaf(-row[j], s, row[c]);
            }
        }
        #pragma unroll
        for (int q = 0; q < NB/4; ++q) {
            float4 v; v.x = row[4*q]; v.y = row[4*q+1]; v.z = row[4*q+2]; v.w = row[4*q+3];
            *(float4*)&A11[r][4*q] = v;
        }
        float ldv = logf(my_d);
        #pragma unroll
        for (int off = 32; off > 0; off >>= 1) ldv += __shfl_down(ldv, off);
        if (r == 0) { s_quad += quad_add; s_ld += ldv; }
    }
    __syncthreads();

    // ---- TRSM: rows of A21 (wave 1); result transposed into A11 (k-major Ps) ----
    if (tid >= 64 && tid < 128) {
        int rr = tid - 64;
        float l[NB];
        #pragma unroll
        for (int q = 0; q < NB/4; ++q) {
            float4 v = *(const float4*)&A21[rr][4*q];
            l[4*q] = v.x; l[4*q+1] = v.y; l[4*q+2] = v.z; l[4*q+3] = v.w;
        }
        #pragma unroll
        for (int j = 0; j < NB; ++j) {
            float s0 = l[j], s1 = 0.f, s2 = 0.f, s3 = 0.f;
            int c = 0;
            #pragma unroll
            for (; c + 4 <= j; c += 4) {
                float4 t = *(const float4*)&A11[j][c];
                s0 = fmaf(-l[c],   t.x, s0);
                s1 = fmaf(-l[c+1], t.y, s1);
                s2 = fmaf(-l[c+2], t.z, s2);
                s3 = fmaf(-l[c+3], t.w, s3);
            }
            #pragma unroll
            for (; c < j; ++c) s0 = fmaf(-l[c], A11[j][c], s0);
            l[j] = ((s0 + s1) + (s2 + s3)) * rs_s[j];
        }
        // A11 is dead now; single-wave program order makes this race-free.
        #pragma unroll
        for (int k = 0; k < NB; ++k) A11[k][rr] = l[k];   // Ps[k][rr]
        float bacc = 0.f;
        #pragma unroll
        for (int j = 0; j < NB; ++j) bacc = fmaf(l[j], sol_s[j], bacc);
        bt[64 + rr] -= bacc;
    }
    __syncthreads();

    // ---- SYRK: A22 -= L21 * L21^T, k-major Ps (= A11), conflict-free ----
    for (int idx = tid; idx < 64 * 16; idx += 512) {
        int i  = idx >> 4;
        int j4 = (idx & 15) << 2;
        if (j4 > i) continue;
        float4 a = make_float4(0,0,0,0);
        #pragma unroll 8
        for (int k = 0; k < NB; ++k) {
            float4 pj = *(const float4*)&A11[k][j4];
            fma4(a, A11[k][i], pj);
        }
        float* cp = &A22[i][j4];
        float4 uu = *(float4*)cp;
        uu.x -= a.x; uu.y -= a.y; uu.z -= a.z; uu.w -= a.w;
        *(float4*)cp = uu;
    }
    __syncthreads();

    // ---- factor A22 (64x64); only logdet + quad needed ----
    if (tid < 64) {
        int r = tid;
        float row[NB];
        #pragma unroll
        for (int q = 0; q < NB/4; ++q) {
            float4 v = *(const float4*)&A22[r][4*q];
            row[4*q+0] = v.x; row[4*q+1] = v.y; row[4*q+2] = v.z; row[4*q+3] = v.w;
        }
        float b = bt[64 + r];
        float quad_add = 0.f, my_d = 1.f;
        #pragma unroll
        for (int j = 0; j < NB; ++j) {
            float dj = fmaxf(bcastf(row[j], j), 1e-30f);
            float rs = rsqrtf(dj);
            if (r == j) my_d = dj;
            row[j] *= rs;
            float sj = bcastf(b, j) * rs;
            quad_add = fmaf(sj, sj, quad_add);
            b = fmaf(-row[j], sj, b);
            #pragma unroll
            for (int c = j + 1; c < NB; ++c) {
                float s = bcastf(row[j], c);
                row[c] = fmaf(-row[j], s, row[c]);
            }
        }
        float ldv = logf(my_d);
        #pragma unroll
        for (int off = 32; off > 0; off >>= 1) ldv += __shfl_down(ldv, off);
        if (r == 0) { s_quad += quad_add; s_ld += ldv; }
    }
    __syncthreads();

    if (tid == 0) {
        float qt = stats[2*m]   + s_quad;
        float lt = stats[2*m+1] + s_ld;
        out[m] = -0.5f * (qt + lt + (float)NN * LOG2PI) + scal[5*NSAMP + m];
    }
}

extern "C" void kernel_launch(void* const* d_in, const int* in_sizes, int n_in,
                              void* d_out, int out_size, void* d_ws, size_t ws_size,
                              hipStream_t stream)
{
    const float* x   = (const float*)d_in[0];
    const float* y   = (const float*)d_in[1];
    const float* z   = (const float*)d_in[2];
    const float* qbm = (const float*)d_in[3];
    const float* qbs = (const float*)d_in[4];
    const float* qsm = (const float*)d_in[5];
    const float* qss = (const float*)d_in[6];
    const float* qem = (const float*)d_in[7];
    const float* qes = (const float*)d_in[8];
    const float* qzm = (const float*)d_in[9];
    const float* qzs = (const float*)d_in[10];
    const float* qnm = (const float*)d_in[11];
    const float* qns = (const float*)d_in[12];
    float* out  = (float*)d_out;
    float* ws   = (float*)d_ws;

    // workspace layout (floats)
    float* scal   = ws;                                   // 384 used
    float* bvec   = ws + 1024;                            // 64*1024
    float* stats  = ws + 1024 + NSAMP*NN;                 // 128 used, 512 res
    float* tsq    = ws + 1024 + NSAMP*NN + 512;           // 64 * 128*128 (4MB)
    float* psq    = tsq + (size_t)NSAMP * TSQN;           // 64 * 128*512 (16MB)
    float* cov    = psq + (size_t)NSAMP * PSQN;           // 64 * SMPL (147MB banded)
    size_t headF  = 1024 + (size_t)NSAMP*NN + 512;

    scal_kernel<<<1, 64, 0, stream>>>(z, qbm, qbs, qsm, qss, qem, qes, qzm, qzs, qnm, qns, scal);

    size_t availF = ws_size / 4;
    size_t perM   = (size_t)SMPL + TSQN + PSQN;   // per-sample footprint
    int mc_max = NSAMP;
    if (availF < headF + (size_t)NSAMP * perM) {
        size_t rem = (availF > headF) ? (availF - headF) : 0;
        mc_max = (int)(rem / perM);
        if (mc_max < 1) mc_max = 1;
        if (mc_max > NSAMP) mc_max = NSAMP;
    }

    for (int mb = 0; mb < NSAMP; mb += mc_max) {
        int mc = NSAMP - mb; if (mc > mc_max) mc = mc_max;
        covslim_kernel<<<dim3(80, mc), 256, 0, stream>>>(cov, tsq, scal, x, y, bvec, stats, mb);
        for (int q = 0; q < CROSS / NB; ++q) {   // panels p = 0..832
            int p = q * NB;
            if (q > 0) {
                int rows = NN - p;
                int rt128 = (rows + 127) / 128;
                if (rt128 * mc >= 448) {
                    update_kernel<<<dim3(rt128 * mc), 256, 0, stream>>>(cov, scal, x, mb, p, mc);
                } else {
                    int rt64 = (rows + 63) / 64;
                    update_small_kernel<<<dim3(rt64 * mc * 2), 256, 0, stream>>>(cov, scal, x, mb, p, mc, rt64);
                }
            }
            int rb = NN - p - NB;
            int rtiles = (rb + 127) / 128;
            trsm_kernel<<<dim3(rtiles * mc), 128, 0, stream>>>(cov, bvec, stats, mb, p, mc);
        }
        tailsyrk_kernel<<<dim3(4, mc), 256, 0, stream>>>(cov, psq);
        finish_kernel<<<mc, 512, 0, stream>>>(tsq, psq, bvec, stats, out, scal, mb);
    }
}

// Round 15
// 1153.655 us; speedup vs baseline: 2.4653x; 1.0451x over previous
//
#include <hip/hip_runtime.h>
#include <math.h>

#define NN 1024           // N (logical)
#define NB 64             // panel width
#define TB 128            // tail handled by tailsyrk+finish
#define CROSS (NN - TB)   // 896: panel loop covers p < CROSS
#define NSAMP 64          // n_mc
// r25: banded-packed cov. Band b (rows 64b..64b+63) stores cols 0..64(b+1)+15
// (stride bs(b)=64b+80). Per-sample 573440 floats -> 64 samples = 147MB,
// ONE L3-resident batch.
#define SMPL 573440
#define TSQN (TB*TB)      // dense tail square per sample (finish input)
#define PSQN (TB*512)     // tailsyrk split-K partials per sample

#define CCONST  (-0.91893853320467274f)   // -0.5*log(2*pi)
#define LOG2PI  (1.8378770664093453f)

__device__ __forceinline__ int rowoff(int i) {
    int b = i >> 6;
    return (2048*b + 3072)*b + (i & 63)*(64*b + 80);
}
__device__ __forceinline__ float bcastf(float v, int lane) {
    return __int_as_float(__builtin_amdgcn_readlane(__float_as_int(v), lane));
}
__device__ __forceinline__ float softplus_d(float v) {
    return (v > 20.f ? v : log1pf(expf(v))) + 1e-7f;
}
__device__ __forceinline__ float log_normal_f(float v, float mean, float s, float eps) {
    float d = v - mean;
    return -d * d / (2.f * s * s + eps) - logf(s) + CCONST;
}
__device__ __forceinline__ float log_lognormal_f(float v, float mean, float s) {
    float lv = logf(v);
    float d = lv - mean;
    return -d * d / (2.f * s * s + 1e-6f) - lv - logf(s) + CCONST;
}
__device__ __forceinline__ void fma4(float4& c, float a, const float4& b) {
    c.x = fmaf(a, b.x, c.x); c.y = fmaf(a, b.y, c.y);
    c.z = fmaf(a, b.z, c.z); c.w = fmaf(a, b.w, c.w);
}

// ---------------- per-sample scalars ----------------
__global__ void scal_kernel(const float* __restrict__ z,
    const float* qbm, const float* qbs, const float* qsm, const float* qss,
    const float* qem, const float* qes, const float* qzm, const float* qzs,
    const float* qnm, const float* qns, float* __restrict__ scal)
{
    int m = threadIdx.x;
    if (m >= NSAMP) return;
    float z0 = z[m*5+0], z1 = z[m*5+1], z2 = z[m*5+2], z3 = z[m*5+3], z4 = z[m*5+4];
    float spb = softplus_d(qbs[0]);
    float sps = softplus_d(qss[0]);
    float spe = softplus_d(qes[0]);
    float spz = softplus_d(qzs[0]);
    float spn = softplus_d(qns[0]);
    float sigma2 = expf(z0 * sps + qsm[0]);
    float beta   = z1 * spb + qbm[0];
    float eta    = expf(z2 * spe + qem[0]);
    float lsZ    = expf(z3 * spz + qzm[0]);
    float lsN    = expf(z4 * spn + qnm[0]);
    float s0 = softplus_d(sqrtf(logf(2.f)));
    float lp = log_normal_f(beta, 0.f, 1.f, 1e-5f)
             + log_lognormal_f(sigma2, 1.f, s0)
             + log_lognormal_f(eta,    1.f, s0)
             + log_lognormal_f(lsZ,    1.f, s0)
             + log_lognormal_f(lsN,    1.f, s0);
    float lq = log_normal_f(beta, qbm[0], spb, 1e-5f)
             + log_lognormal_f(sigma2, qsm[0], sps)
             + log_lognormal_f(eta,    qem[0], spe)
             + log_lognormal_f(lsZ,    qzm[0], spz)
             + log_lognormal_f(lsN,    qnm[0], spn);
    scal[m]           = sigma2;
    scal[NSAMP + m]   = eta;
    scal[2*NSAMP + m] = 1.f / lsZ;
    scal[3*NSAMP + m] = 1.f / lsN;
    scal[4*NSAMP + m] = beta;
    scal[5*NSAMP + m] = lp - lq;
}

// ---------------- slim covariance build + bvec/stats init ----------------
__global__ __launch_bounds__(256)
void covslim_kernel(float* __restrict__ cov, float* __restrict__ tsq,
                    const float* __restrict__ scal,
                    const float* __restrict__ x, const float* __restrict__ y,
                    float* __restrict__ bvec, float* __restrict__ stats, int mbase)
{
    int ml = blockIdx.y;
    int m  = mbase + ml;
    float sigma2 = scal[m];
    float eta    = scal[NSAMP + m];
    float ilZ    = scal[2*NSAMP + m];
    float ilN    = scal[3*NSAMP + m];
    float* C = cov + (size_t)ml * SMPL;
    int tid = threadIdx.x;

    if (blockIdx.x == 0 && tid == 0) { stats[2*m] = 0.f; stats[2*m+1] = 0.f; }

    if (blockIdx.x < 64) {
        // stripe: 16 rows x 64 cols per block (lower triangle only)
        int i  = blockIdx.x * 16 + (tid >> 4);
        int j0 = (tid & 15) * 4;
        if ((tid & 15) == 0) bvec[(size_t)m * NN + i] = y[i] - scal[4*NSAMP + m];
        if (j0 > i) return;
        float xi0 = x[2*i]   * ilZ;
        float xi1 = x[2*i+1] * ilN;
        float4 xa = *(const float4*)(x + 2*j0);
        float4 xb = *(const float4*)(x + 2*j0 + 4);
        float v[4]; float d0, d1;
        d0 = xa.x*ilZ - xi0; d1 = xa.y*ilN - xi1; v[0] = eta*__expf(-0.5f*(d0*d0+d1*d1));
        d0 = xa.z*ilZ - xi0; d1 = xa.w*ilN - xi1; v[1] = eta*__expf(-0.5f*(d0*d0+d1*d1));
        d0 = xb.x*ilZ - xi0; d1 = xb.y*ilN - xi1; v[2] = eta*__expf(-0.5f*(d0*d0+d1*d1));
        d0 = xb.z*ilZ - xi0; d1 = xb.w*ilN - xi1; v[3] = eta*__expf(-0.5f*(d0*d0+d1*d1));
        #pragma unroll
        for (int q = 0; q < 4; ++q) if (j0 + q == i) v[q] += sigma2;
        float* row = C + rowoff(i);
        if (j0 + 3 <= i) {
            float4 o; o.x = v[0]; o.y = v[1]; o.z = v[2]; o.w = v[3];
            *(float4*)(row + j0) = o;
        } else {
            #pragma unroll
            for (int q = 0; q < 4; ++q) if (j0 + q <= i) row[j0+q] = v[q];
        }
    } else {
        // tail: 8 rows x 128 cols per block -> dense tsq[128][128]
        int bx2 = blockIdx.x - 64;                 // 0..15
        int tr  = bx2 * 8 + (tid >> 5);            // 0..127 tail-local row
        int tc  = (tid & 31) * 4;                  // 0..124 tail-local col
        int i   = CROSS + tr;
        int j0  = CROSS + tc;
        float xi0 = x[2*i]   * ilZ;
        float xi1 = x[2*i+1] * ilN;
        float4 xa = *(const float4*)(x + 2*j0);
        float4 xb = *(const float4*)(x + 2*j0 + 4);
        float v[4]; float d0, d1;
        d0 = xa.x*ilZ - xi0; d1 = xa.y*ilN - xi1; v[0] = eta*__expf(-0.5f*(d0*d0+d1*d1));
        d0 = xa.z*ilZ - xi0; d1 = xa.w*ilN - xi1; v[1] = eta*__expf(-0.5f*(d0*d0+d1*d1));
        d0 = xb.x*ilZ - xi0; d1 = xb.y*ilN - xi1; v[2] = eta*__expf(-0.5f*(d0*d0+d1*d1));
        d0 = xb.z*ilZ - xi0; d1 = xb.w*ilN - xi1; v[3] = eta*__expf(-0.5f*(d0*d0+d1*d1));
        #pragma unroll
        for (int q = 0; q < 4; ++q) if (j0 + q == i) v[q] += sigma2;
        float4 o; o.x = v[0]; o.y = v[1]; o.z = v[2]; o.w = v[3];
        *(float4*)(tsq + (size_t)ml * TSQN + tr * TB + tc) = o;
    }
}

// ---------------- left-looking block-column update (GEMM, K = p) ----------------
// r26: software-pipelined staging (retry of r19 now that the working set is
// fully L3-resident — r19's regression mechanism was L3-cliff eviction at
// 272MB, structurally removed at 167MB). Next k-step's loads issue into regs
// right after the barrier and complete under the compute. Addresses, values,
// fma order bit-identical.
__global__ __launch_bounds__(256)
void update_kernel(float* __restrict__ covb, const float* __restrict__ scal,
                   const float* __restrict__ x, int mbase, int p, int mc)
{
    int bid = blockIdx.x;
    int ml  = bid % mc;
    int bx  = bid / mc;
    int m  = mbase + ml;
    float* C = covb + (size_t)ml * SMPL;
    int rowbase = p + bx * 128;
    int bofp = rowoff(p);
    int bsp  = 64*(p>>6) + 80;

    __shared__ __align__(16) float As[32][132];  // k-major, 128 rows
    __shared__ __align__(16) float Bs[32][68];   // k-major, 64 rows

    int tid = threadIdx.x;
    int tx = tid & 7,  ty = tid >> 3;
    int c0 = tx * 8,   r0 = ty * 4;

    float4 acc[4][2];
    #pragma unroll
    for (int r = 0; r < 4; ++r) { acc[r][0] = make_float4(0,0,0,0); acc[r][1] = make_float4(0,0,0,0); }

    // prefetch k-step 0 into registers
    float4 ra[4], rb[2];
    #pragma unroll
    for (int t = 0; t < 4; ++t) {
        int idx = tid + t * 256;
        int ii = idx >> 3, c4 = (idx & 7) << 2;
        int gr = rowbase + ii;
        ra[t] = make_float4(0,0,0,0);
        if (gr < NN) ra[t] = *(const float4*)(C + rowoff(gr) + c4);
    }
    #pragma unroll
    for (int t = 0; t < 2; ++t) {
        int idx = tid + t * 256;
        int ii = idx >> 3, c4 = (idx & 7) << 2;
        rb[t] = *(const float4*)(C + bofp + ii * bsp + c4);
    }

    for (int ks = 0; ks < p; ks += 32) {
        // regs -> LDS
        #pragma unroll
        for (int t = 0; t < 4; ++t) {
            int idx = tid + t * 256;
            int ii = idx >> 3, c4 = (idx & 7) << 2;
            As[c4+0][ii] = ra[t].x; As[c4+1][ii] = ra[t].y;
            As[c4+2][ii] = ra[t].z; As[c4+3][ii] = ra[t].w;
        }
        #pragma unroll
        for (int t = 0; t < 2; ++t) {
            int idx = tid + t * 256;
            int ii = idx >> 3, c4 = (idx & 7) << 2;
            Bs[c4+0][ii] = rb[t].x; Bs[c4+1][ii] = rb[t].y;
            Bs[c4+2][ii] = rb[t].z; Bs[c4+3][ii] = rb[t].w;
        }
        __syncthreads();
        // issue next k-step's loads; they complete under the compute below
        int kn = ks + 32;
        if (kn < p) {
            #pragma unroll
            for (int t = 0; t < 4; ++t) {
                int idx = tid + t * 256;
                int ii = idx >> 3, c4 = (idx & 7) << 2;
                int gr = rowbase + ii;
                ra[t] = make_float4(0,0,0,0);
                if (gr < NN) ra[t] = *(const float4*)(C + rowoff(gr) + kn + c4);
            }
            #pragma unroll
            for (int t = 0; t < 2; ++t) {
                int idx = tid + t * 256;
                int ii = idx >> 3, c4 = (idx & 7) << 2;
                rb[t] = *(const float4*)(C + bofp + ii * bsp + kn + c4);
            }
        }
        #pragma unroll
        for (int k = 0; k < 32; ++k) {
            float4 b0 = *(const float4*)&Bs[k][c0];
            float4 b1 = *(const float4*)&Bs[k][c0 + 4];
            float4 a0 = *(const float4*)&As[k][r0];
            float ar[4] = {a0.x, a0.y, a0.z, a0.w};
            #pragma unroll
            for (int r = 0; r < 4; ++r) {
                fma4(acc[r][0], ar[r], b0);
                fma4(acc[r][1], ar[r], b1);
            }
        }
        __syncthreads();
    }

    int jcol = p + c0;
    float sigma2 = scal[m];
    float eta    = scal[NSAMP + m];
    float ilZ    = scal[2*NSAMP + m];
    float ilN    = scal[3*NSAMP + m];
    float4 xa0 = *(const float4*)(x + 2*jcol);
    float4 xb0 = *(const float4*)(x + 2*jcol + 4);
    float4 xa1 = *(const float4*)(x + 2*jcol + 8);
    float4 xb1 = *(const float4*)(x + 2*jcol + 12);
    #pragma unroll
    for (int r = 0; r < 4; ++r) {
        int g = rowbase + r0 + r;
        if (g < NN) {
            float xi0 = x[2*g]   * ilZ;
            float xi1 = x[2*g+1] * ilN;
            float v[8]; float d0, d1;
            d0 = xa0.x*ilZ - xi0; d1 = xa0.y*ilN - xi1; v[0] = eta*__expf(-0.5f*(d0*d0+d1*d1));
            d0 = xa0.z*ilZ - xi0; d1 = xa0.w*ilN - xi1; v[1] = eta*__expf(-0.5f*(d0*d0+d1*d1));
            d0 = xb0.x*ilZ - xi0; d1 = xb0.y*ilN - xi1; v[2] = eta*__expf(-0.5f*(d0*d0+d1*d1));
            d0 = xb0.z*ilZ - xi0; d1 = xb0.w*ilN - xi1; v[3] = eta*__expf(-0.5f*(d0*d0+d1*d1));
            d0 = xa1.x*ilZ - xi0; d1 = xa1.y*ilN - xi1; v[4] = eta*__expf(-0.5f*(d0*d0+d1*d1));
            d0 = xa1.z*ilZ - xi0; d1 = xa1.w*ilN - xi1; v[5] = eta*__expf(-0.5f*(d0*d0+d1*d1));
            d0 = xb1.x*ilZ - xi0; d1 = xb1.y*ilN - xi1; v[6] = eta*__expf(-0.5f*(d0*d0+d1*d1));
            d0 = xb1.z*ilZ - xi0; d1 = xb1.w*ilN - xi1; v[7] = eta*__expf(-0.5f*(d0*d0+d1*d1));
            #pragma unroll
            for (int qq = 0; qq < 8; ++qq) if (jcol + qq == g) v[qq] += sigma2;
            float* cp = C + rowoff(g) + jcol;
            float4 u0, u1;
            u0.x = v[0] - acc[r][0].x; u0.y = v[1] - acc[r][0].y;
            u0.z = v[2] - acc[r][0].z; u0.w = v[3] - acc[r][0].w;
            u1.x = v[4] - acc[r][1].x; u1.y = v[5] - acc[r][1].y;
            u1.z = v[6] - acc[r][1].z; u1.w = v[7] - acc[r][1].w;
            *(float4*)cp = u0;
            *((float4*)cp + 1) = u1;
        }
    }
}

// ---------------- small-tile update for late panels ----------------
// r26: same software pipeline.
__global__ __launch_bounds__(256)
void update_small_kernel(float* __restrict__ covb, const float* __restrict__ scal,
                         const float* __restrict__ x, int mbase, int p, int mc, int nbx)
{
    int bid  = blockIdx.x;
    int ml   = bid % mc;
    int rest = bid / mc;
    int bx   = rest % nbx;
    int zz   = rest / nbx;
    int m  = mbase + ml;
    float* C = covb + (size_t)ml * SMPL;
    int rowbase = p + bx * 64;
    int zoff = zz * 32;
    int bofp = rowoff(p);
    int bsp  = 64*(p>>6) + 80;

    __shared__ __align__(16) float As[32][68];   // k-major, 64 rows
    __shared__ __align__(16) float Bs[32][36];   // k-major, 32 rows

    int tid = threadIdx.x;
    int tx = tid & 7,  ty = tid >> 3;   // 8 col-quads x 32 row-pairs
    int c0 = tx * 4,   r0 = ty * 2;

    float4 acc0 = make_float4(0,0,0,0), acc1 = make_float4(0,0,0,0);

    float4 ra[2], rb1;
    #pragma unroll
    for (int t = 0; t < 2; ++t) {
        int idx = tid + t * 256;
        int ii = idx >> 3, c4 = (idx & 7) << 2;
        int gr = rowbase + ii;
        ra[t] = make_float4(0,0,0,0);
        if (gr < NN) ra[t] = *(const float4*)(C + rowoff(gr) + c4);
    }
    {
        int ii = tid >> 3, c4 = (tid & 7) << 2;
        rb1 = *(const float4*)(C + bofp + (zoff + ii) * bsp + c4);
    }

    for (int ks = 0; ks < p; ks += 32) {
        #pragma unroll
        for (int t = 0; t < 2; ++t) {
            int idx = tid + t * 256;
            int ii = idx >> 3, c4 = (idx & 7) << 2;
            As[c4+0][ii] = ra[t].x; As[c4+1][ii] = ra[t].y;
            As[c4+2][ii] = ra[t].z; As[c4+3][ii] = ra[t].w;
        }
        {
            int ii = tid >> 3, c4 = (tid & 7) << 2;
            Bs[c4+0][ii] = rb1.x; Bs[c4+1][ii] = rb1.y;
            Bs[c4+2][ii] = rb1.z; Bs[c4+3][ii] = rb1.w;
        }
        __syncthreads();
        int kn = ks + 32;
        if (kn < p) {
            #pragma unroll
            for (int t = 0; t < 2; ++t) {
                int idx = tid + t * 256;
                int ii = idx >> 3, c4 = (idx & 7) << 2;
                int gr = rowbase + ii;
                ra[t] = make_float4(0,0,0,0);
                if (gr < NN) ra[t] = *(const float4*)(C + rowoff(gr) + kn + c4);
            }
            {
                int ii = tid >> 3, c4 = (tid & 7) << 2;
                rb1 = *(const float4*)(C + bofp + (zoff + ii) * bsp + kn + c4);
            }
        }
        #pragma unroll
        for (int k = 0; k < 32; ++k) {
            float4 bv = *(const float4*)&Bs[k][c0];
            float2 av = *(const float2*)&As[k][r0];
            fma4(acc0, av.x, bv);
            fma4(acc1, av.y, bv);
        }
        __syncthreads();
    }

    int jcol = p + zoff + c0;
    float sigma2 = scal[m];
    float eta    = scal[NSAMP + m];
    float ilZ    = scal[2*NSAMP + m];
    float ilN    = scal[3*NSAMP + m];
    float4 xa = *(const float4*)(x + 2*jcol);
    float4 xb = *(const float4*)(x + 2*jcol + 4);
    int g0 = rowbase + r0;
    #pragma unroll
    for (int rr = 0; rr < 2; ++rr) {
        int g = g0 + rr;
        if (g < NN) {
            float xi0 = x[2*g]   * ilZ;
            float xi1 = x[2*g+1] * ilN;
            float v[4]; float d0, d1;
            d0 = xa.x*ilZ - xi0; d1 = xa.y*ilN - xi1; v[0] = eta*__expf(-0.5f*(d0*d0+d1*d1));
            d0 = xa.z*ilZ - xi0; d1 = xa.w*ilN - xi1; v[1] = eta*__expf(-0.5f*(d0*d0+d1*d1));
            d0 = xb.x*ilZ - xi0; d1 = xb.y*ilN - xi1; v[2] = eta*__expf(-0.5f*(d0*d0+d1*d1));
            d0 = xb.z*ilZ - xi0; d1 = xb.w*ilN - xi1; v[3] = eta*__expf(-0.5f*(d0*d0+d1*d1));
            #pragma unroll
            for (int qq = 0; qq < 4; ++qq) if (jcol + qq == g) v[qq] += sigma2;
            const float4 ac = (rr == 0) ? acc0 : acc1;
            float* cp = C + rowoff(g) + jcol;
            float4 u;
            u.x = v[0] - ac.x; u.y = v[1] - ac.y; u.z = v[2] - ac.z; u.w = v[3] - ac.w;
            *(float4*)cp = u;
        }
    }
}

// ---------------- fused diag-factor + panel TRSM ----------------
__global__ __launch_bounds__(128)
void trsm_kernel(float* __restrict__ covb, float* __restrict__ bvec,
                 float* __restrict__ stats, int mbase, int p, int mc)
{
    int bid = blockIdx.x;
    int ml  = bid % mc;
    int bx  = bid / mc;
    int m  = mbase + ml;
    float* C = covb + (size_t)ml * SMPL;
    __shared__ __align__(16) float Tl[NB][68];
    __shared__ float rs_s[NB], sol_s[NB];
    int tid = threadIdx.x;
    int bofp = rowoff(p);
    int bsp  = 64*(p>>6) + 80;

    // preload solve rows (global loads in flight while wave 0 factors)
    int r0 = p + NB + bx * 128 + tid;
    bool have = (r0 < NN);
    float l[NB];
    int roff = have ? rowoff(r0) : 0;
    if (have) {
        const float* rowp = C + roff + p;
        #pragma unroll
        for (int q = 0; q < NB/4; ++q) {
            float4 v = *(const float4*)(rowp + 4*q);
            l[4*q] = v.x; l[4*q+1] = v.y; l[4*q+2] = v.z; l[4*q+3] = v.w;
        }
    }

    // ---- in-block diag factor (wave 0), verbatim diag arithmetic
    if (tid < 64) {
        int r = tid;
        float row[NB];
        const float* src = C + bofp + r * bsp + p;
        #pragma unroll
        for (int q = 0; q < NB/4; ++q) {
            float4 v = *(const float4*)(src + 4*q);
            row[4*q+0] = v.x; row[4*q+1] = v.y; row[4*q+2] = v.z; row[4*q+3] = v.w;
        }
        float b = bvec[(size_t)m * NN + p + r];
        float quad_add = 0.f, my_d = 1.f, my_rs = 0.f, my_sol = 0.f;
        #pragma unroll
        for (int j = 0; j < NB; ++j) {
            float dj = fmaxf(bcastf(row[j], j), 1e-30f);
            float rs = rsqrtf(dj);
            if (r == j) my_d = dj;
            row[j] *= rs;                       // row[j] = L[r][j] for r>=j
            float sj = bcastf(b, j) * rs;
            quad_add = fmaf(sj, sj, quad_add);
            b = fmaf(-row[j], sj, b);
            if (r == j) { my_rs = rs; my_sol = sj; }
            #pragma unroll
            for (int c = j + 1; c < NB; ++c) {
                float s = bcastf(row[j], c);    // = L[c][j]
                row[c] = fmaf(-row[j], s, row[c]);
            }
        }
        #pragma unroll
        for (int q = 0; q < NB/4; ++q) {
            float4 v; v.x = row[4*q]; v.y = row[4*q+1]; v.z = row[4*q+2]; v.w = row[4*q+3];
            *(float4*)&Tl[r][4*q] = v;
        }
        rs_s[r]  = my_rs;
        sol_s[r] = my_sol;
        if (bx == 0) {
            float ldv = logf(my_d);
            #pragma unroll
            for (int off = 32; off > 0; off >>= 1) ldv += __shfl_down(ldv, off);
            if (r == 0) {
                stats[2*m]   += quad_add;
                stats[2*m+1] += ldv;
            }
        }
    }
    __syncthreads();

    if (!have) return;
    float* rowp = C + roff + p;
    #pragma unroll
    for (int j = 0; j < NB; ++j) {
        float s0 = l[j], s1 = 0.f, s2 = 0.f, s3 = 0.f;
        int c = 0;
        #pragma unroll
        for (; c + 4 <= j; c += 4) {
            float4 t = *(const float4*)&Tl[j][c];
            s0 = fmaf(-l[c],   t.x, s0);
            s1 = fmaf(-l[c+1], t.y, s1);
            s2 = fmaf(-l[c+2], t.z, s2);
            s3 = fmaf(-l[c+3], t.w, s3);
        }
        #pragma unroll
        for (; c < j; ++c) s0 = fmaf(-l[c], Tl[j][c], s0);
        l[j] = ((s0 + s1) + (s2 + s3)) * rs_s[j];
    }
    #pragma unroll
    for (int q = 0; q < NB/4; ++q) {
        float4 v; v.x = l[4*q]; v.y = l[4*q+1]; v.z = l[4*q+2]; v.w = l[4*q+3];
        *(float4*)(rowp + 4*q) = v;
    }
    float b0 = 0.f, b1 = 0.f, b2 = 0.f, b3 = 0.f;
    #pragma unroll
    for (int j = 0; j < NB; j += 4) {
        b0 = fmaf(l[j],   sol_s[j],   b0);
        b1 = fmaf(l[j+1], sol_s[j+1], b1);
        b2 = fmaf(l[j+2], sol_s[j+2], b2);
        b3 = fmaf(l[j+3], sol_s[j+3], b3);
    }
    bvec[(size_t)m * NN + r0] -= ((b0 + b1) + (b2 + b3));
}

// ---------------- tail SYRK, split-K partials -> psq ----------------
__global__ __launch_bounds__(256)
void tailsyrk_kernel(const float* __restrict__ covb, float* __restrict__ psq)
{
    int ml = blockIdx.y;
    const float* C = covb + (size_t)ml * SMPL;
    float* P = psq + (size_t)ml * PSQN;
    int z  = blockIdx.x;
    int k0 = z * (CROSS / 4);            // 224 per segment

    __shared__ __align__(16) float As[32][132];
    int tid = threadIdx.x;
    int tx = tid & 15, ty = tid >> 4;
    int c0 = tx * 8, r0 = ty * 8;

    float4 acc[8][2];
    #pragma unroll
    for (int r = 0; r < 8; ++r) { acc[r][0] = make_float4(0,0,0,0); acc[r][1] = make_float4(0,0,0,0); }

    for (int ks = k0; ks < k0 + CROSS/4; ks += 32) {
        for (int idx = tid; idx < 128 * 8; idx += 256) {
            int ii = idx >> 3;
            int c4 = (idx & 7) << 2;
            float4 v = *(const float4*)(C + rowoff(CROSS + ii) + ks + c4);
            As[c4+0][ii] = v.x; As[c4+1][ii] = v.y;
            As[c4+2][ii] = v.z; As[c4+3][ii] = v.w;
        }
        __syncthreads();
        #pragma unroll
        for (int k = 0; k < 32; ++k) {
            float4 b0 = *(const float4*)&As[k][c0];
            float4 b1 = *(const float4*)&As[k][c0 + 4];
            float4 a0 = *(const float4*)&As[k][r0];
            float4 a1 = *(const float4*)&As[k][r0 + 4];
            float ar[8] = {a0.x, a0.y, a0.z, a0.w, a1.x, a1.y, a1.z, a1.w};
            #pragma unroll
            for (int r = 0; r < 8; ++r) {
                fma4(acc[r][0], ar[r], b0);
                fma4(acc[r][1], ar[r], b1);
            }
        }
        __syncthreads();
    }

    #pragma unroll
    for (int r = 0; r < 8; ++r) {
        float* cp = P + (r0 + r) * 512 + z * 128 + c0;
        *(float4*)cp = acc[r][0];
        *((float4*)cp + 1) = acc[r][1];
    }
}

// ---------------- fused tailreduce + per-sample finish ----------------
__global__ __launch_bounds__(512)
void finish_kernel(const float* __restrict__ tsq, const float* __restrict__ psq,
                   const float* __restrict__ bvec,
                   const float* __restrict__ stats, float* __restrict__ out,
                   const float* __restrict__ scal, int mbase)
{
    int ml = blockIdx.x;
    int m  = mbase + ml;
    const float* T = tsq + (size_t)ml * TSQN;
    const float* P = psq + (size_t)ml * PSQN;
    __shared__ __align__(16) float A11[NB][68];   // tail 11; after TRSM: k-major L21 (Ps)
    __shared__ __align__(16) float A21[NB][68];   // tail rows 64..127, cols 0..63
    __shared__ __align__(16) float A22[NB][68];
    __shared__ float rs_s[NB], sol_s[NB];
    __shared__ float bt[TB];
    __shared__ float s_quad, s_ld;
    int tid = threadIdx.x;

    if (tid < TB) bt[tid] = bvec[(size_t)m * NN + CROSS + tid];
    if (tid == 0) { s_quad = 0.f; s_ld = 0.f; }

    // ---- fused tail reduce: A = tsq - sum_z psq partials ----
    float4 tv[6], p0[6], p1[6], p2[6], p3[6];
    const float* pbase[6];
    #pragma unroll
    for (int u = 0; u < 6; ++u) {
        int f   = tid + u * 512;
        int i   = (f & 1023) >> 4;
        int c4  = (f & 15) << 2;
        int blk = f >> 10;
        int ti  = (blk == 0) ? i : (64 + i);         // tail-local row
        int tc  = (blk == 2) ? (64 + c4) : c4;       // tail-local col
        pbase[u] = P + ti * 512 + tc;
        tv[u] = *(const float4*)(T + ti * TB + tc);
    }
    #pragma unroll
    for (int u = 0; u < 6; ++u) p0[u] = *(const float4*)(pbase[u]);
    #pragma unroll
    for (int u = 0; u < 6; ++u) p1[u] = *(const float4*)(pbase[u] + 128);
    #pragma unroll
    for (int u = 0; u < 6; ++u) p2[u] = *(const float4*)(pbase[u] + 256);
    #pragma unroll
    for (int u = 0; u < 6; ++u) p3[u] = *(const float4*)(pbase[u] + 384);
    #pragma unroll
    for (int u = 0; u < 6; ++u) {
        int f   = tid + u * 512;
        int i   = (f & 1023) >> 4;
        int c4  = (f & 15) << 2;
        int blk = f >> 10;
        float4 s;
        s.x = ((p0[u].x + p1[u].x) + p2[u].x) + p3[u].x;
        s.y = ((p0[u].y + p1[u].y) + p2[u].y) + p3[u].y;
        s.z = ((p0[u].z + p1[u].z) + p2[u].z) + p3[u].z;
        s.w = ((p0[u].w + p1[u].w) + p2[u].w) + p3[u].w;
        float4 t = tv[u];
        t.x -= s.x; t.y -= s.y; t.z -= s.z; t.w -= s.w;
        float* dst = (blk == 0) ? &A11[i][c4] : ((blk == 1) ? &A21[i][c4] : &A22[i][c4]);
        *(float4*)dst = t;
    }
    __syncthreads();

    // ---- factor A11 (64x64), scaled rows back into A11 ----
    if (tid < 64) {
        int r = tid;
        float row[NB];
        #pragma unroll
        for (int q = 0; q < NB/4; ++q) {
            float4 v = *(const float4*)&A11[r][4*q];
            row[4*q+0] = v.x; row[4*q+1] = v.y; row[4*q+2] = v.z; row[4*q+3] = v.w;
        }
        float b = bt[r];
        float quad_add = 0.f, my_d = 1.f;
        #pragma unroll
        for (int j = 0; j < NB; ++j) {
            float dj = fmaxf(bcastf(row[j], j), 1e-30f);
            float rs = rsqrtf(dj);
            if (r == j) my_d = dj;
            row[j] *= rs;
            float sj = bcastf(b, j) * rs;
            quad_add = fmaf(sj, sj, quad_add);
            b = fmaf(-row[j], sj, b);
            if (r == j) { rs_s[j] = rs; sol_s[j] = sj; }
            #pragma unroll
            for (int c = j + 1; c < NB; ++c) {
                float s = bcastf(row[j], c);
                row[c] = fmaf(-row[j], s, row[c]);
            }
        }
        #pragma unroll
        for (int q = 0; q < NB/4; ++q) {
            float4 v; v.x = row[4*q]; v.y = row[4*q+1]; v.z = row[4*q+2]; v.w = row[4*q+3];
            *(float4*)&A11[r][4*q] = v;
        }
        float ldv = logf(my_d);
        #pragma unroll
        for (int off = 32; off > 0; off >>= 1) ldv += __shfl_down(ldv, off);
        if (r == 0) { s_quad += quad_add; s_ld += ldv; }
    }
    __syncthreads();

    // ---- TRSM: rows of A21 (wave 1); result transposed into A11 (k-major Ps) ----
    if (tid >= 64 && tid < 128) {
        int rr = tid - 64;
        float l[NB];
        #pragma unroll
        for (int q = 0; q < NB/4; ++q) {
            float4 v = *(const float4*)&A21[rr][4*q];
            l[4*q] = v.x; l[4*q+1] = v.y; l[4*q+2] = v.z; l[4*q+3] = v.w;
        }
        #pragma unroll
        for (int j = 0; j < NB; ++j) {
            float s0 = l[j], s1 = 0.f, s2 = 0.f, s3 = 0.f;
            int c = 0;
            #pragma unroll
            for (; c + 4 <= j; c += 4) {
                float4 t = *(const float4*)&A11[j][c];
                s0 = fmaf(-l[c],   t.x, s0);
                s1 = fmaf(-l[c+1], t.y, s1);
                s2 = fmaf(-l[c+2], t.z, s2);
                s3 = fmaf(-l[c+3], t.w, s3);
            }
            #pragma unroll
            for (; c < j; ++c) s0 = fmaf(-l[c], A11[j][c], s0);
            l[j] = ((s0 + s1) + (s2 + s3)) * rs_s[j];
        }
        // A11 is dead now; single-wave program order makes this race-free.
        #pragma unroll
        for (int k = 0; k < NB; ++k) A11[k][rr] = l[k];   // Ps[k][rr]
        float bacc = 0.f;
        #pragma unroll
        for (int j = 0; j < NB; ++j) bacc = fmaf(l[j], sol_s[j], bacc);
        bt[64 + rr] -= bacc;
    }
    __syncthreads();

    // ---- SYRK: A22 -= L21 * L21^T, k-major Ps (= A11), conflict-free ----
    for (int idx = tid; idx < 64 * 16; idx += 512) {
        int i  = idx >> 4;
        int j4 = (idx & 15) << 2;
        if (j4 > i) continue;
        float4 a = make_float4(0,0,0,0);
        #pragma unroll 8
        for (int k = 0; k < NB; ++k) {
            float4 pj = *(const float4*)&A11[k][j4];
            fma4(a, A11[k][i], pj);
        }
        float* cp = &A22[i][j4];
        float4 uu = *(float4*)cp;
        uu.x -= a.x; uu.y -= a.y; uu.z -= a.z; uu.w -= a.w;
        *(float4*)cp = uu;
    }
    __syncthreads();

    // ---- factor A22 (64x64); only logdet + quad needed ----
    if (tid < 64) {
        int r = tid;
        float row[NB];
        #pragma unroll
        for (int q = 0; q < NB/4; ++q) {
            float4 v = *(const float4*)&A22[r][4*q];
            row[4*q+0] = v.x; row[4*q+1] = v.y; row[4*q+2] = v.z; row[4*q+3] = v.w;
        }
        float b = bt[64 + r];
        float quad_add = 0.f, my_d = 1.f;
        #pragma unroll
        for (int j = 0; j < NB; ++j) {
            float dj = fmaxf(bcastf(row[j], j), 1e-30f);
            float rs = rsqrtf(dj);
            if (r == j) my_d = dj;
            row[j] *= rs;
            float sj = bcastf(b, j) * rs;
            quad_add = fmaf(sj, sj, quad_add);
            b = fmaf(-row[j], sj, b);
            #pragma unroll
            for (int c = j + 1; c < NB; ++c) {
                float s = bcastf(row[j], c);
                row[c] = fmaf(-row[j], s, row[c]);
            }
        }
        float ldv = logf(my_d);
        #pragma unroll
        for (int off = 32; off > 0; off >>= 1) ldv += __shfl_down(ldv, off);
        if (r == 0) { s_quad += quad_add; s_ld += ldv; }
    }
    __syncthreads();

    if (tid == 0) {
        float qt = stats[2*m]   + s_quad;
        float lt = stats[2*m+1] + s_ld;
        out[m] = -0.5f * (qt + lt + (float)NN * LOG2PI) + scal[5*NSAMP + m];
    }
}

extern "C" void kernel_launch(void* const* d_in, const int* in_sizes, int n_in,
                              void* d_out, int out_size, void* d_ws, size_t ws_size,
                              hipStream_t stream)
{
    const float* x   = (const float*)d_in[0];
    const float* y   = (const float*)d_in[1];
    const float* z   = (const float*)d_in[2];
    const float* qbm = (const float*)d_in[3];
    const float* qbs = (const float*)d_in[4];
    const float* qsm = (const float*)d_in[5];
    const float* qss = (const float*)d_in[6];
    const float* qem = (const float*)d_in[7];
    const float* qes = (const float*)d_in[8];
    const float* qzm = (const float*)d_in[9];
    const float* qzs = (const float*)d_in[10];
    const float* qnm = (const float*)d_in[11];
    const float* qns = (const float*)d_in[12];
    float* out  = (float*)d_out;
    float* ws   = (float*)d_ws;

    // workspace layout (floats)
    float* scal   = ws;                                   // 384 used
    float* bvec   = ws + 1024;                            // 64*1024
    float* stats  = ws + 1024 + NSAMP*NN;                 // 128 used, 512 res
    float* tsq    = ws + 1024 + NSAMP*NN + 512;           // 64 * 128*128 (4MB)
    float* psq    = tsq + (size_t)NSAMP * TSQN;           // 64 * 128*512 (16MB)
    float* cov    = psq + (size_t)NSAMP * PSQN;           // 64 * SMPL (147MB banded)
    size_t headF  = 1024 + (size_t)NSAMP*NN + 512;

    scal_kernel<<<1, 64, 0, stream>>>(z, qbm, qbs, qsm, qss, qem, qes, qzm, qzs, qnm, qns, scal);

    size_t availF = ws_size / 4;
    size_t perM   = (size_t)SMPL + TSQN + PSQN;   // per-sample footprint
    int mc_max = NSAMP;
    if (availF < headF + (size_t)NSAMP * perM) {
        size_t rem = (availF > headF) ? (availF - headF) : 0;
        mc_max = (int)(rem / perM);
        if (mc_max < 1) mc_max = 1;
        if (mc_max > NSAMP) mc_max = NSAMP;
    }

    for (int mb = 0; mb < NSAMP; mb += mc_max) {
        int mc = NSAMP - mb; if (mc > mc_max) mc = mc_max;
        covslim_kernel<<<dim3(80, mc), 256, 0, stream>>>(cov, tsq, scal, x, y, bvec, stats, mb);
        for (int q = 0; q < CROSS / NB; ++q) {   // panels p = 0..832
            int p = q * NB;
            if (q > 0) {
                int rows = NN - p;
                int rt128 = (rows + 127) / 128;
                if (rt128 * mc >= 448) {
                    update_kernel<<<dim3(rt128 * mc), 256, 0, stream>>>(cov, scal, x, mb, p, mc);
                } else {
                    int rt64 = (rows + 63) / 64;
                    update_small_kernel<<<dim3(rt64 * mc * 2), 256, 0, stream>>>(cov, scal, x, mb, p, mc, rt64);
                }
            }
            int rb = NN - p - NB;
            int rtiles = (rb + 127) / 128;
            trsm_kernel<<<dim3(rtiles * mc), 128, 0, stream>>>(cov, bvec, stats, mb, p, mc);
        }
        tailsyrk_kernel<<<dim3(4, mc), 256, 0, stream>>>(cov, psq);
        finish_kernel<<<mc, 512, 0, stream>>>(tsq, psq, bvec, stats, out, scal, mb);
    }
}